// Round 1
// baseline (542.411 us; speedup 1.0000x reference)
//
#include <hip/hip_runtime.h>
#include <math.h>

#define B_    2
#define LSEQ  1024
#define DM    512
#define DI    1024
#define NS    64
#define NPROJ (DI + 2*NS)   // 1152
#define TC    64
#define NC    (LSEQ/TC)     // 16

__device__ __forceinline__ float sp_f(float x)   { return fmaxf(x, 0.f) + log1pf(expf(-fabsf(x))); }
__device__ __forceinline__ float silu_f(float x) { return x / (1.f + expf(-x)); }

// ---------------------------------------------------------------------------
// Generic f32 GEMM: C[M,N] = A[M,K] * B[N,K]^T   (both row-major, K mult of 16,
// M,N mult of 64). Block 256 threads, 64x64 tile, 4x4 per thread.
// ---------------------------------------------------------------------------
__global__ __launch_bounds__(256) void gemm_abt(
    const float* __restrict__ A, const float* __restrict__ B,
    float* __restrict__ C, int M, int N, int K)
{
    __shared__ float As[16][64];
    __shared__ float Bs[16][64];
    const int bm = blockIdx.y * 64;
    const int bn = blockIdx.x * 64;
    const int tid = threadIdx.x;
    const int tr = tid / 16, tc = tid % 16;
    const int la_m = tid / 4;
    const int la_k = (tid % 4) * 4;

    float acc[4][4] = {};
    for (int k0 = 0; k0 < K; k0 += 16) {
        __syncthreads();
        float4 av = *(const float4*)&A[(size_t)(bm + la_m) * K + k0 + la_k];
        float4 bv = *(const float4*)&B[(size_t)(bn + la_m) * K + k0 + la_k];
        As[la_k + 0][la_m] = av.x; As[la_k + 1][la_m] = av.y;
        As[la_k + 2][la_m] = av.z; As[la_k + 3][la_m] = av.w;
        Bs[la_k + 0][la_m] = bv.x; Bs[la_k + 1][la_m] = bv.y;
        Bs[la_k + 2][la_m] = bv.z; Bs[la_k + 3][la_m] = bv.w;
        __syncthreads();
#pragma unroll
        for (int kk = 0; kk < 16; kk++) {
            float4 a = *(const float4*)&As[kk][tr * 4];
            float4 b = *(const float4*)&Bs[kk][tc * 4];
            acc[0][0] = fmaf(a.x, b.x, acc[0][0]); acc[0][1] = fmaf(a.x, b.y, acc[0][1]);
            acc[0][2] = fmaf(a.x, b.z, acc[0][2]); acc[0][3] = fmaf(a.x, b.w, acc[0][3]);
            acc[1][0] = fmaf(a.y, b.x, acc[1][0]); acc[1][1] = fmaf(a.y, b.y, acc[1][1]);
            acc[1][2] = fmaf(a.y, b.z, acc[1][2]); acc[1][3] = fmaf(a.y, b.w, acc[1][3]);
            acc[2][0] = fmaf(a.z, b.x, acc[2][0]); acc[2][1] = fmaf(a.z, b.y, acc[2][1]);
            acc[2][2] = fmaf(a.z, b.z, acc[2][2]); acc[2][3] = fmaf(a.z, b.w, acc[2][3]);
            acc[3][0] = fmaf(a.w, b.x, acc[3][0]); acc[3][1] = fmaf(a.w, b.y, acc[3][1]);
            acc[3][2] = fmaf(a.w, b.z, acc[3][2]); acc[3][3] = fmaf(a.w, b.w, acc[3][3]);
        }
    }
#pragma unroll
    for (int i = 0; i < 4; i++)
#pragma unroll
        for (int j = 0; j < 4; j++)
            C[(size_t)(bm + tr * 4 + i) * N + bn + tc * 4 + j] = acc[i][j];
}

// ---------------------------------------------------------------------------
// Depthwise causal conv (fwd) + anti-causal conv (bwd) + SiLU.
// xc = first DI columns of xz rows. uc2 layout: [dir][b][L][DI]
// ---------------------------------------------------------------------------
__global__ __launch_bounds__(256) void convk(
    const float* __restrict__ xz, const float* __restrict__ cw,
    const float* __restrict__ cb, float* __restrict__ uc2)
{
    int idx = blockIdx.x * 256 + threadIdx.x;          // (b, tau, d)
    int b   = idx >> 20;                               // / (1024*1024)
    int rem = idx & ((LSEQ * DI) - 1);
    int tau = rem >> 10;
    int d   = rem & (DI - 1);

    const float* xc = xz + (size_t)b * LSEQ * (2 * DI);
    float w0 = cw[d * 4 + 0], w1 = cw[d * 4 + 1], w2 = cw[d * 4 + 2], w3 = cw[d * 4 + 3];
    float bias = cb[d];
    float accf = bias, accb = bias;
    // fwd: sum_j w[j] * xc[tau-3+j];  bwd: sum_j w[j] * xc[tau+3-j]
    {
        int t0 = tau - 3, t1 = tau - 2, t2 = tau - 1;
        if (t0 >= 0) accf = fmaf(w0, xc[(size_t)t0 * 2048 + d], accf);
        if (t1 >= 0) accf = fmaf(w1, xc[(size_t)t1 * 2048 + d], accf);
        if (t2 >= 0) accf = fmaf(w2, xc[(size_t)t2 * 2048 + d], accf);
        accf = fmaf(w3, xc[(size_t)tau * 2048 + d], accf);
    }
    {
        int t0 = tau + 3, t1 = tau + 2, t2 = tau + 1;
        if (t0 < LSEQ) accb = fmaf(w0, xc[(size_t)t0 * 2048 + d], accb);
        if (t1 < LSEQ) accb = fmaf(w1, xc[(size_t)t1 * 2048 + d], accb);
        if (t2 < LSEQ) accb = fmaf(w2, xc[(size_t)t2 * 2048 + d], accb);
        accb = fmaf(w3, xc[(size_t)tau * 2048 + d], accb);
    }
    uc2[((size_t)b * LSEQ + tau) * DI + d]                    = silu_f(accf);
    uc2[((size_t)(2 + b) * LSEQ + tau) * DI + d]              = silu_f(accb);
}

// ---------------------------------------------------------------------------
// Pass A: per-(dir,b,chunk,d) local scan from zero state.
// Writes sEnd[dirb][c][n][d] and P[dirb][c][d] = exp(A_d * sum(delta)).
// ---------------------------------------------------------------------------
__global__ __launch_bounds__(256) void passA(
    const float* __restrict__ proj2, const float* __restrict__ uc2,
    const float* __restrict__ A_log, float* __restrict__ sEnd,
    float* __restrict__ Pbuf)
{
    const int d    = blockIdx.x * 256 + threadIdx.x;
    const int c    = blockIdx.y;
    const int dirb = blockIdx.z;                 // dir*2 + b
    const int dir  = dirb >> 1;

    __shared__ float Bs[TC][NS];
    const float* projbase = proj2 + (size_t)dirb * LSEQ * NPROJ;
    const float* ucb      = uc2   + (size_t)dirb * LSEQ * DI;

    for (int i = threadIdx.x; i < TC * NS; i += 256) {
        int tl = i >> 6, n = i & 63;
        int t = c * TC + tl;
        int tau = dir ? (LSEQ - 1 - t) : t;
        Bs[tl][n] = projbase[(size_t)tau * NPROJ + DI + n];
    }
    __syncthreads();

    float Ad = -expf(A_log[d]);
    float s[NS];
#pragma unroll
    for (int n = 0; n < NS; n++) s[n] = 0.f;
    float sumdelta = 0.f;

    for (int tl = 0; tl < TC; tl++) {
        int t = c * TC + tl;
        int tau = dir ? (LSEQ - 1 - t) : t;
        float delta = sp_f(projbase[(size_t)tau * NPROJ + d]);
        float u     = ucb[(size_t)tau * DI + d];
        float dA    = expf(delta * Ad);
        float du    = delta * u;
        sumdelta += delta;
        const float4* brow = (const float4*)&Bs[tl][0];
#pragma unroll
        for (int q = 0; q < 16; q++) {
            float4 bv = brow[q];
            s[4*q+0] = fmaf(du, bv.x, dA * s[4*q+0]);
            s[4*q+1] = fmaf(du, bv.y, dA * s[4*q+1]);
            s[4*q+2] = fmaf(du, bv.z, dA * s[4*q+2]);
            s[4*q+3] = fmaf(du, bv.w, dA * s[4*q+3]);
        }
    }
    size_t base = (((size_t)dirb * NC + c) * NS) * DI;
#pragma unroll
    for (int n = 0; n < NS; n++) sEnd[base + (size_t)n * DI + d] = s[n];
    Pbuf[((size_t)dirb * NC + c) * DI + d] = expf(sumdelta * Ad);
}

// ---------------------------------------------------------------------------
// Pass B: sequential combine across chunks (in place: sEnd -> sInit).
// ---------------------------------------------------------------------------
__global__ __launch_bounds__(256) void passB(
    float* __restrict__ sEnd, const float* __restrict__ Pbuf)
{
    const int d    = blockIdx.x * 256 + threadIdx.x;
    const int n    = blockIdx.y;
    const int dirb = blockIdx.z;
    float run = 0.f;
    for (int c = 0; c < NC; c++) {
        size_t idx = (((size_t)dirb * NC + c) * NS + n) * DI + d;
        float tmp = sEnd[idx];
        sEnd[idx] = run;
        float P = Pbuf[((size_t)dirb * NC + c) * DI + d];
        run = fmaf(P, run, tmp);
    }
}

// ---------------------------------------------------------------------------
// Pass C: re-run local scan seeded with sInit, emit y fused with silu(z)*0.5.
// dir0 stores, dir1 accumulates.
// ---------------------------------------------------------------------------
__global__ __launch_bounds__(256) void passC(
    const float* __restrict__ proj2, const float* __restrict__ uc2,
    const float* __restrict__ xz, const float* __restrict__ sInit,
    const float* __restrict__ A_log, const float* __restrict__ Dvec,
    float* __restrict__ ycomb, int dir)
{
    const int d  = blockIdx.x * 256 + threadIdx.x;
    const int c  = blockIdx.y;
    const int b  = blockIdx.z;
    const int dirb = dir * 2 + b;

    __shared__ float Bs[TC][NS];
    __shared__ float Cs[TC][NS];
    const float* projbase = proj2 + (size_t)dirb * LSEQ * NPROJ;
    const float* ucb      = uc2   + (size_t)dirb * LSEQ * DI;

    for (int i = threadIdx.x; i < TC * NS; i += 256) {
        int tl = i >> 6, n = i & 63;
        int t = c * TC + tl;
        int tau = dir ? (LSEQ - 1 - t) : t;
        Bs[tl][n] = projbase[(size_t)tau * NPROJ + DI + n];
        Cs[tl][n] = projbase[(size_t)tau * NPROJ + DI + NS + n];
    }
    __syncthreads();

    float Ad = -expf(A_log[d]);
    float Dd = Dvec[d];
    float s[NS];
    size_t sbase = (((size_t)dirb * NC + c) * NS) * DI;
#pragma unroll
    for (int n = 0; n < NS; n++) s[n] = sInit[sbase + (size_t)n * DI + d];

    for (int tl = 0; tl < TC; tl++) {
        int t = c * TC + tl;
        int tau = dir ? (LSEQ - 1 - t) : t;
        float delta = sp_f(projbase[(size_t)tau * NPROJ + d]);
        float u     = ucb[(size_t)tau * DI + d];
        float dA    = expf(delta * Ad);
        float du    = delta * u;
        float y = 0.f;
        const float4* brow = (const float4*)&Bs[tl][0];
        const float4* crow = (const float4*)&Cs[tl][0];
#pragma unroll
        for (int q = 0; q < 16; q++) {
            float4 bv = brow[q];
            float4 cv = crow[q];
            float s0 = fmaf(du, bv.x, dA * s[4*q+0]); s[4*q+0] = s0; y = fmaf(cv.x, s0, y);
            float s1 = fmaf(du, bv.y, dA * s[4*q+1]); s[4*q+1] = s1; y = fmaf(cv.y, s1, y);
            float s2 = fmaf(du, bv.z, dA * s[4*q+2]); s[4*q+2] = s2; y = fmaf(cv.z, s2, y);
            float s3 = fmaf(du, bv.w, dA * s[4*q+3]); s[4*q+3] = s3; y = fmaf(cv.w, s3, y);
        }
        y = fmaf(Dd, u, y);
        float z = xz[((size_t)b * LSEQ + tau) * (2 * DI) + DI + d];
        float g = 0.5f * y * silu_f(z);
        size_t oidx = ((size_t)b * LSEQ + tau) * DI + d;
        if (dir == 0) ycomb[oidx] = g;
        else          ycomb[oidx] += g;
    }
}

// ---------------------------------------------------------------------------
extern "C" void kernel_launch(void* const* d_in, const int* in_sizes, int n_in,
                              void* d_out, int out_size, void* d_ws, size_t ws_size,
                              hipStream_t stream)
{
    const float* x      = (const float*)d_in[0];
    const float* W_in   = (const float*)d_in[1];
    const float* conv_w = (const float*)d_in[2];
    const float* conv_b = (const float*)d_in[3];
    const float* W_xprj = (const float*)d_in[4];
    const float* A_log  = (const float*)d_in[5];
    const float* Dvec   = (const float*)d_in[6];
    const float* W_out  = (const float*)d_in[7];
    float* out = (float*)d_out;

    float* ws = (float*)d_ws;
    float* xz    = ws;                               // [B_][L][2*DI]      16 MB
    float* uc2   = xz    + (size_t)B_ * LSEQ * 2 * DI;   // [2][B_][L][DI] 16 MB
    float* proj2 = uc2   + (size_t)4 * LSEQ * DI;        // [2][B_][L][NPROJ] 18 MB
    float* sEnd  = proj2 + (size_t)4 * LSEQ * NPROJ;     // [4][NC][NS][DI]  16 MB
    float* Pbuf  = sEnd  + (size_t)4 * NC * NS * DI;     // [4][NC][DI]     .25 MB
    float* ycomb = Pbuf  + (size_t)4 * NC * DI;          // [B_][L][DI]      8 MB

    // 1) xz = x @ W_in^T   (M=2048, N=2048, K=512)
    gemm_abt<<<dim3(2 * DI / 64, B_ * LSEQ / 64), 256, 0, stream>>>(
        x, W_in, xz, B_ * LSEQ, 2 * DI, DM);

    // 2) conv both directions + SiLU
    convk<<<(B_ * LSEQ * DI) / 256, 256, 0, stream>>>(xz, conv_w, conv_b, uc2);

    // 3) proj2 = uc2 @ W_xproj^T  (M=4096, N=1152, K=1024)
    gemm_abt<<<dim3(NPROJ / 64, 4 * LSEQ / 64), 256, 0, stream>>>(
        uc2, W_xprj, proj2, 4 * LSEQ, NPROJ, DI);

    // 4) pass A: local chunk scans
    passA<<<dim3(DI / 256, NC, 4), 256, 0, stream>>>(proj2, uc2, A_log, sEnd, Pbuf);

    // 5) pass B: chunk-state combine (sEnd -> sInit in place)
    passB<<<dim3(DI / 256, NS, 4), 256, 0, stream>>>(sEnd, Pbuf);

    // 6/7) pass C: final scan + y*silu(z)*0.5, fwd then bwd accumulate
    passC<<<dim3(DI / 256, NC, B_), 256, 0, stream>>>(proj2, uc2, xz, sEnd, A_log, Dvec, ycomb, 0);
    passC<<<dim3(DI / 256, NC, B_), 256, 0, stream>>>(proj2, uc2, xz, sEnd, A_log, Dvec, ycomb, 1);

    // 8) out = ycomb @ W_out^T  (M=2048, N=512, K=1024)
    gemm_abt<<<dim3(DM / 64, B_ * LSEQ / 64), 256, 0, stream>>>(
        ycomb, W_out, out, B_ * LSEQ, DM, DI);
}

// Round 2
// 454.243 us; speedup vs baseline: 1.1941x; 1.1941x over previous
//
#include <hip/hip_runtime.h>
#include <math.h>

#define B_    2
#define LSEQ  1024
#define DM    512
#define DI    1024
#define NS    64
#define NPROJ (DI + 2*NS)   // 1152
#define TC    64
#define NC    (LSEQ/TC)     // 16

typedef __bf16 bf16x8 __attribute__((ext_vector_type(8)));
typedef float  f32x4  __attribute__((ext_vector_type(4)));

__device__ __forceinline__ float sp_f(float x)   { return fmaxf(x, 0.f) + log1pf(expf(-fabsf(x))); }
__device__ __forceinline__ float silu_f(float x) { return x / (1.f + expf(-x)); }
__device__ __forceinline__ unsigned short f2bf(float f) {
    unsigned int u = __float_as_uint(f);
    u += 0x7FFF + ((u >> 16) & 1);          // RNE
    return (unsigned short)(u >> 16);
}
__device__ __forceinline__ float bf2f(unsigned short h) {
    return __uint_as_float(((unsigned int)h) << 16);
}

// ---------------------------------------------------------------------------
// f32 -> bf16 cast, 4 elements/thread
// ---------------------------------------------------------------------------
__global__ __launch_bounds__(256) void cast4(
    const float* __restrict__ s, unsigned short* __restrict__ d, int n)
{
    int i = (blockIdx.x * 256 + threadIdx.x) * 4;
    if (i >= n) return;
    float4 v = *(const float4*)(s + i);
    ushort4 o;
    o.x = f2bf(v.x); o.y = f2bf(v.y); o.z = f2bf(v.z); o.w = f2bf(v.w);
    *(ushort4*)(d + i) = o;
}

// ---------------------------------------------------------------------------
// bf16 MFMA GEMM: C[M,N] = A[M,K] * B[N,K]^T, f32 out.
// 128x128 tile, BK=64, 256 threads (4 waves, 2x2), each wave 64x64.
// ---------------------------------------------------------------------------
__global__ __launch_bounds__(256) void gemm_bf16(
    const unsigned short* __restrict__ A, const unsigned short* __restrict__ B,
    float* __restrict__ C, int M, int N, int K)
{
    __shared__ short As[128 * 64];
    __shared__ short Bs[128 * 64];
    const int tid  = threadIdx.x;
    const int lane = tid & 63, wid = tid >> 6;
    const int bm = blockIdx.y * 128, bn = blockIdx.x * 128;
    const int wm = (wid >> 1) * 64,  wn = (wid & 1) * 64;
    const int fr = lane & 15, fk = (lane >> 4) * 8;

    f32x4 acc[4][4];
#pragma unroll
    for (int i = 0; i < 4; i++)
#pragma unroll
        for (int j = 0; j < 4; j++) acc[i][j] = (f32x4)0.f;

    uint4 ra[4], rb[4];
#pragma unroll
    for (int r = 0; r < 4; r++) {                   // prefetch k0 = 0
        int o = tid * 16 + r * 4096;                // byte offset in 16KB tile
        int row = o >> 7, colb = o & 127;
        ra[r] = *(const uint4*)((const char*)A + ((size_t)(bm + row) * K) * 2 + colb);
        rb[r] = *(const uint4*)((const char*)B + ((size_t)(bn + row) * K) * 2 + colb);
    }

    for (int k0 = 0; k0 < K; k0 += 64) {
        __syncthreads();
#pragma unroll
        for (int r = 0; r < 4; r++) {
            *(uint4*)((char*)As + tid * 16 + r * 4096) = ra[r];
            *(uint4*)((char*)Bs + tid * 16 + r * 4096) = rb[r];
        }
        __syncthreads();
        if (k0 + 64 < K) {
#pragma unroll
            for (int r = 0; r < 4; r++) {
                int o = tid * 16 + r * 4096;
                int row = o >> 7, colb = o & 127;
                ra[r] = *(const uint4*)((const char*)A + ((size_t)(bm + row) * K + k0 + 64) * 2 + colb);
                rb[r] = *(const uint4*)((const char*)B + ((size_t)(bn + row) * K + k0 + 64) * 2 + colb);
            }
        }
#pragma unroll
        for (int kk = 0; kk < 2; kk++) {
            bf16x8 af[4], bfr[4];
#pragma unroll
            for (int i = 0; i < 4; i++)
                af[i] = *reinterpret_cast<const bf16x8*>(&As[(wm + i * 16 + fr) * 64 + kk * 32 + fk]);
#pragma unroll
            for (int j = 0; j < 4; j++)
                bfr[j] = *reinterpret_cast<const bf16x8*>(&Bs[(wn + j * 16 + fr) * 64 + kk * 32 + fk]);
#pragma unroll
            for (int i = 0; i < 4; i++)
#pragma unroll
                for (int j = 0; j < 4; j++)
                    acc[i][j] = __builtin_amdgcn_mfma_f32_16x16x32_bf16(af[i], bfr[j], acc[i][j], 0, 0, 0);
        }
    }

    const int crow = (lane >> 4) * 4;
#pragma unroll
    for (int i = 0; i < 4; i++)
#pragma unroll
        for (int j = 0; j < 4; j++)
#pragma unroll
            for (int r = 0; r < 4; r++)
                C[(size_t)(bm + wm + i * 16 + crow + r) * N + (bn + wn + j * 16 + fr)] = acc[i][j][r];
}

// ---------------------------------------------------------------------------
// Depthwise causal conv (fwd) + anti-causal conv (bwd) + SiLU -> bf16
// uc2b layout: [dir][b][L][DI] at ORIGINAL tau positions
// ---------------------------------------------------------------------------
__global__ __launch_bounds__(256) void convk(
    const float* __restrict__ xz, const float* __restrict__ cw,
    const float* __restrict__ cb, unsigned short* __restrict__ uc2b)
{
    int idx = blockIdx.x * 256 + threadIdx.x;          // (b, tau, d)
    int b   = idx >> 20;
    int rem = idx & ((LSEQ * DI) - 1);
    int tau = rem >> 10;
    int d   = rem & (DI - 1);

    const float* xc = xz + (size_t)b * LSEQ * (2 * DI);
    float w0 = cw[d * 4 + 0], w1 = cw[d * 4 + 1], w2 = cw[d * 4 + 2], w3 = cw[d * 4 + 3];
    float bias = cb[d];
    float accf = bias, accb = bias;
    {
        int t0 = tau - 3, t1 = tau - 2, t2 = tau - 1;
        if (t0 >= 0) accf = fmaf(w0, xc[(size_t)t0 * 2048 + d], accf);
        if (t1 >= 0) accf = fmaf(w1, xc[(size_t)t1 * 2048 + d], accf);
        if (t2 >= 0) accf = fmaf(w2, xc[(size_t)t2 * 2048 + d], accf);
        accf = fmaf(w3, xc[(size_t)tau * 2048 + d], accf);
    }
    {
        int t0 = tau + 3, t1 = tau + 2, t2 = tau + 1;
        if (t0 < LSEQ) accb = fmaf(w0, xc[(size_t)t0 * 2048 + d], accb);
        if (t1 < LSEQ) accb = fmaf(w1, xc[(size_t)t1 * 2048 + d], accb);
        if (t2 < LSEQ) accb = fmaf(w2, xc[(size_t)t2 * 2048 + d], accb);
        accb = fmaf(w3, xc[(size_t)tau * 2048 + d], accb);
    }
    uc2b[((size_t)b * LSEQ + tau) * DI + d]       = f2bf(silu_f(accf));
    uc2b[((size_t)(2 + b) * LSEQ + tau) * DI + d] = f2bf(silu_f(accb));
}

// ---------------------------------------------------------------------------
// Pass A: per-(dir,b,chunk,d) local scan from zero state.
// ---------------------------------------------------------------------------
__global__ __launch_bounds__(256) void passA(
    const float* __restrict__ proj2, const unsigned short* __restrict__ uc2b,
    const float* __restrict__ A_log, float* __restrict__ sEnd,
    float* __restrict__ Pbuf)
{
    const int d    = blockIdx.x * 256 + threadIdx.x;
    const int c    = blockIdx.y;
    const int dirb = blockIdx.z;                 // dir*2 + b
    const int dir  = dirb >> 1;

    __shared__ float Bsh[TC][NS];
    const float* projbase = proj2 + (size_t)dirb * LSEQ * NPROJ;
    const unsigned short* ucb = uc2b + (size_t)dirb * LSEQ * DI;

    for (int i = threadIdx.x; i < TC * NS; i += 256) {
        int tl = i >> 6, n = i & 63;
        int t = c * TC + tl;
        int tau = dir ? (LSEQ - 1 - t) : t;
        Bsh[tl][n] = projbase[(size_t)tau * NPROJ + DI + n];
    }
    __syncthreads();

    float Ad = -expf(A_log[d]);
    float s[NS];
#pragma unroll
    for (int n = 0; n < NS; n++) s[n] = 0.f;
    float sumdelta = 0.f;

    for (int tl = 0; tl < TC; tl++) {
        int t = c * TC + tl;
        int tau = dir ? (LSEQ - 1 - t) : t;
        float delta = sp_f(projbase[(size_t)tau * NPROJ + d]);
        float u     = bf2f(ucb[(size_t)tau * DI + d]);
        float dA    = expf(delta * Ad);
        float du    = delta * u;
        sumdelta += delta;
        const float4* brow = (const float4*)&Bsh[tl][0];
#pragma unroll
        for (int q = 0; q < 16; q++) {
            float4 bv = brow[q];
            s[4*q+0] = fmaf(du, bv.x, dA * s[4*q+0]);
            s[4*q+1] = fmaf(du, bv.y, dA * s[4*q+1]);
            s[4*q+2] = fmaf(du, bv.z, dA * s[4*q+2]);
            s[4*q+3] = fmaf(du, bv.w, dA * s[4*q+3]);
        }
    }
    size_t base = (((size_t)dirb * NC + c) * NS) * DI;
#pragma unroll
    for (int n = 0; n < NS; n++) sEnd[base + (size_t)n * DI + d] = s[n];
    Pbuf[((size_t)dirb * NC + c) * DI + d] = expf(sumdelta * Ad);
}

// ---------------------------------------------------------------------------
// Pass B: sequential combine across chunks (in place: sEnd -> sInit).
// ---------------------------------------------------------------------------
__global__ __launch_bounds__(256) void passB(
    float* __restrict__ sEnd, const float* __restrict__ Pbuf)
{
    const int d    = blockIdx.x * 256 + threadIdx.x;
    const int n    = blockIdx.y;
    const int dirb = blockIdx.z;
    float run = 0.f;
    for (int c = 0; c < NC; c++) {
        size_t idx = (((size_t)dirb * NC + c) * NS + n) * DI + d;
        float tmp = sEnd[idx];
        sEnd[idx] = run;
        float P = Pbuf[((size_t)dirb * NC + c) * DI + d];
        run = fmaf(P, run, tmp);
    }
}

// ---------------------------------------------------------------------------
// Pass C: re-run local scan seeded with sInit, emit y fused with silu(z)*0.5.
// dir0 stores f32; dir1 adds and stores bf16 for the output GEMM.
// ---------------------------------------------------------------------------
__global__ __launch_bounds__(256) void passC(
    const float* __restrict__ proj2, const unsigned short* __restrict__ uc2b,
    const float* __restrict__ xz, const float* __restrict__ sInit,
    const float* __restrict__ A_log, const float* __restrict__ Dvec,
    float* __restrict__ ycomb, unsigned short* __restrict__ ycombb, int dir)
{
    const int d  = blockIdx.x * 256 + threadIdx.x;
    const int c  = blockIdx.y;
    const int b  = blockIdx.z;
    const int dirb = dir * 2 + b;

    __shared__ float Bsh[TC][NS];
    __shared__ float Csh[TC][NS];
    const float* projbase = proj2 + (size_t)dirb * LSEQ * NPROJ;
    const unsigned short* ucb = uc2b + (size_t)dirb * LSEQ * DI;

    for (int i = threadIdx.x; i < TC * NS; i += 256) {
        int tl = i >> 6, n = i & 63;
        int t = c * TC + tl;
        int tau = dir ? (LSEQ - 1 - t) : t;
        Bsh[tl][n] = projbase[(size_t)tau * NPROJ + DI + n];
        Csh[tl][n] = projbase[(size_t)tau * NPROJ + DI + NS + n];
    }
    __syncthreads();

    float Ad = -expf(A_log[d]);
    float Dd = Dvec[d];
    float s[NS];
    size_t sbase = (((size_t)dirb * NC + c) * NS) * DI;
#pragma unroll
    for (int n = 0; n < NS; n++) s[n] = sInit[sbase + (size_t)n * DI + d];

    for (int tl = 0; tl < TC; tl++) {
        int t = c * TC + tl;
        int tau = dir ? (LSEQ - 1 - t) : t;
        float delta = sp_f(projbase[(size_t)tau * NPROJ + d]);
        float u     = bf2f(ucb[(size_t)tau * DI + d]);
        float dA    = expf(delta * Ad);
        float du    = delta * u;
        float y = 0.f;
        const float4* brow = (const float4*)&Bsh[tl][0];
        const float4* crow = (const float4*)&Csh[tl][0];
#pragma unroll
        for (int q = 0; q < 16; q++) {
            float4 bv = brow[q];
            float4 cv = crow[q];
            float s0 = fmaf(du, bv.x, dA * s[4*q+0]); s[4*q+0] = s0; y = fmaf(cv.x, s0, y);
            float s1 = fmaf(du, bv.y, dA * s[4*q+1]); s[4*q+1] = s1; y = fmaf(cv.y, s1, y);
            float s2 = fmaf(du, bv.z, dA * s[4*q+2]); s[4*q+2] = s2; y = fmaf(cv.z, s2, y);
            float s3 = fmaf(du, bv.w, dA * s[4*q+3]); s[4*q+3] = s3; y = fmaf(cv.w, s3, y);
        }
        y = fmaf(Dd, u, y);
        float z = xz[((size_t)b * LSEQ + tau) * (2 * DI) + DI + d];
        float g = 0.5f * y * silu_f(z);
        size_t oidx = ((size_t)b * LSEQ + tau) * DI + d;
        if (dir == 0) ycomb[oidx] = g;
        else          ycombb[oidx] = f2bf(ycomb[oidx] + g);
    }
}

// ---------------------------------------------------------------------------
extern "C" void kernel_launch(void* const* d_in, const int* in_sizes, int n_in,
                              void* d_out, int out_size, void* d_ws, size_t ws_size,
                              hipStream_t stream)
{
    const float* x      = (const float*)d_in[0];
    const float* W_in   = (const float*)d_in[1];
    const float* conv_w = (const float*)d_in[2];
    const float* conv_b = (const float*)d_in[3];
    const float* W_xprj = (const float*)d_in[4];
    const float* A_log  = (const float*)d_in[5];
    const float* Dvec   = (const float*)d_in[6];
    const float* W_out  = (const float*)d_in[7];
    float* out = (float*)d_out;

    // workspace layout (74.7 MB total; aliased regions are dead-before-overwrite)
    float* ws    = (float*)d_ws;
    float* xz    = ws;                              // 4.19M f  [B][L][2*DI]
    float* proj2 = xz    + 4194304;                 // 4.72M f  [4][L][NPROJ]
    float* sEnd  = proj2 + 4718592;                 // 4.19M f  [4][NC][NS][DI]
    float* Pbuf  = sEnd  + 4194304;                 // 65536 f
    float* ycomb = Pbuf  + 65536;                   // 2.10M f  [B][L][DI]
    unsigned short* uc2b   = (unsigned short*)(ycomb + 2097152);  // 4.19M bf16
    unsigned short* ycombb = uc2b + 4194304;        // 2.10M bf16
    unsigned short* wob    = ycombb + 2097152;      // 0.52M bf16
    // aliases: written at step 1, consumed before their host region is written
    unsigned short* xb   = (unsigned short*)sEnd;               // dead after gemm1; sEnd written in passA
    unsigned short* winb = (unsigned short*)sEnd + 1048576;
    unsigned short* wxb  = (unsigned short*)ycomb;              // dead after gemm3; ycomb written in passC0

    // 1) bf16 casts
    cast4<<<1024, 256, 0, stream>>>(x, xb, LSEQ * B_ * DM);
    cast4<<<1024, 256, 0, stream>>>(W_in, winb, 2 * DI * DM);
    cast4<<<1152, 256, 0, stream>>>(W_xprj, wxb, NPROJ * DI);
    cast4<<<512, 256, 0, stream>>>(W_out, wob, DM * DI);

    // 2) xz = x @ W_in^T (M=2048, N=2048, K=512)
    gemm_bf16<<<dim3(16, 16), 256, 0, stream>>>(xb, winb, xz, B_ * LSEQ, 2 * DI, DM);

    // 3) conv both directions + SiLU -> bf16
    convk<<<(B_ * LSEQ * DI) / 256, 256, 0, stream>>>(xz, conv_w, conv_b, uc2b);

    // 4) proj2 = uc2 @ W_xproj^T (M=4096, N=1152, K=1024)
    gemm_bf16<<<dim3(9, 32), 256, 0, stream>>>(uc2b, wxb, proj2, 4 * LSEQ, NPROJ, DI);

    // 5) pass A: local chunk scans
    passA<<<dim3(DI / 256, NC, 4), 256, 0, stream>>>(proj2, uc2b, A_log, sEnd, Pbuf);

    // 6) pass B: chunk-state combine
    passB<<<dim3(DI / 256, NS, 4), 256, 0, stream>>>(sEnd, Pbuf);

    // 7) pass C: final scan + y*silu(z)*0.5, fwd then bwd(+combine -> bf16)
    passC<<<dim3(DI / 256, NC, B_), 256, 0, stream>>>(proj2, uc2b, xz, sEnd, A_log, Dvec, ycomb, ycombb, 0);
    passC<<<dim3(DI / 256, NC, B_), 256, 0, stream>>>(proj2, uc2b, xz, sEnd, A_log, Dvec, ycomb, ycombb, 1);

    // 8) out = ycomb @ W_out^T (M=2048, N=512, K=1024)
    gemm_bf16<<<dim3(4, 16), 256, 0, stream>>>(ycombb, wob, out, B_ * LSEQ, DM, DI);
}

// Round 3
// 375.878 us; speedup vs baseline: 1.4430x; 1.2085x over previous
//
#include <hip/hip_runtime.h>
#include <math.h>

#define B_    2
#define LSEQ  1024
#define DM    512
#define DI    1024
#define NS    64
#define NPROJ (DI + 2*NS)   // 1152
#define TC    64
#define NC    (LSEQ/TC)     // 16

typedef __bf16 bf16x8 __attribute__((ext_vector_type(8)));
typedef float  f32x4  __attribute__((ext_vector_type(4)));

__device__ __forceinline__ float sp_f(float x)   { return fmaxf(x, 0.f) + log1pf(expf(-fabsf(x))); }
__device__ __forceinline__ float silu_f(float x) { return x / (1.f + expf(-x)); }
__device__ __forceinline__ unsigned short f2bf(float f) {
    unsigned int u = __float_as_uint(f);
    u += 0x7FFF + ((u >> 16) & 1);          // RNE
    return (unsigned short)(u >> 16);
}
__device__ __forceinline__ float bf2f(unsigned short h) {
    return __uint_as_float(((unsigned int)h) << 16);
}
// add two packs of 8 bf16 in f32, repack RNE
__device__ __forceinline__ uint4 bfadd8(uint4 a, uint4 b) {
    uint4 r;
    unsigned* pa = (unsigned*)&a; unsigned* pb = (unsigned*)&b; unsigned* pr = (unsigned*)&r;
#pragma unroll
    for (int i = 0; i < 4; i++) {
        unsigned wa = pa[i], wb = pb[i];
        float lo = __uint_as_float(wa << 16) + __uint_as_float(wb << 16);
        float hi = __uint_as_float(wa & 0xffff0000u) + __uint_as_float(wb & 0xffff0000u);
        pr[i] = ((unsigned)f2bf(lo)) | (((unsigned)f2bf(hi)) << 16);
    }
    return r;
}

// ---------------------------------------------------------------------------
// f32 -> bf16 cast, 4 elements/thread
// ---------------------------------------------------------------------------
__global__ __launch_bounds__(256) void cast4(
    const float* __restrict__ s, unsigned short* __restrict__ d, int n)
{
    int i = (blockIdx.x * 256 + threadIdx.x) * 4;
    if (i >= n) return;
    float4 v = *(const float4*)(s + i);
    ushort4 o;
    o.x = f2bf(v.x); o.y = f2bf(v.y); o.z = f2bf(v.z); o.w = f2bf(v.w);
    *(ushort4*)(d + i) = o;
}

// ---------------------------------------------------------------------------
// bf16 MFMA GEMM: C[M,N] = (A [+ A2]) [M,K] * B[N,K]^T, f32 out.
// 128x128 tile, BK=64, 256 threads (4 waves, 2x2), each wave 64x64.
// A2 (optional, may be null): second bf16 matrix summed into A during staging.
// ---------------------------------------------------------------------------
__global__ __launch_bounds__(256) void gemm_bf16(
    const unsigned short* __restrict__ A, const unsigned short* __restrict__ A2,
    const unsigned short* __restrict__ B,
    float* __restrict__ C, int M, int N, int K)
{
    __shared__ short As[128 * 64];
    __shared__ short Bs[128 * 64];
    const int tid  = threadIdx.x;
    const int lane = tid & 63, wid = tid >> 6;
    const int bm = blockIdx.y * 128, bn = blockIdx.x * 128;
    const int wm = (wid >> 1) * 64,  wn = (wid & 1) * 64;
    const int fr = lane & 15, fk = (lane >> 4) * 8;

    f32x4 acc[4][4];
#pragma unroll
    for (int i = 0; i < 4; i++)
#pragma unroll
        for (int j = 0; j < 4; j++) acc[i][j] = (f32x4)0.f;

    uint4 ra[4], rb[4];
#pragma unroll
    for (int r = 0; r < 4; r++) {                   // prefetch k0 = 0
        int o = tid * 16 + r * 4096;                // byte offset in 16KB tile
        int row = o >> 7, colb = o & 127;
        ra[r] = *(const uint4*)((const char*)A + ((size_t)(bm + row) * K) * 2 + colb);
        if (A2) ra[r] = bfadd8(ra[r], *(const uint4*)((const char*)A2 + ((size_t)(bm + row) * K) * 2 + colb));
        rb[r] = *(const uint4*)((const char*)B + ((size_t)(bn + row) * K) * 2 + colb);
    }

    for (int k0 = 0; k0 < K; k0 += 64) {
        __syncthreads();
#pragma unroll
        for (int r = 0; r < 4; r++) {
            *(uint4*)((char*)As + tid * 16 + r * 4096) = ra[r];
            *(uint4*)((char*)Bs + tid * 16 + r * 4096) = rb[r];
        }
        __syncthreads();
        if (k0 + 64 < K) {
#pragma unroll
            for (int r = 0; r < 4; r++) {
                int o = tid * 16 + r * 4096;
                int row = o >> 7, colb = o & 127;
                ra[r] = *(const uint4*)((const char*)A + ((size_t)(bm + row) * K + k0 + 64) * 2 + colb);
                if (A2) ra[r] = bfadd8(ra[r], *(const uint4*)((const char*)A2 + ((size_t)(bm + row) * K + k0 + 64) * 2 + colb));
                rb[r] = *(const uint4*)((const char*)B + ((size_t)(bn + row) * K + k0 + 64) * 2 + colb);
            }
        }
#pragma unroll
        for (int kk = 0; kk < 2; kk++) {
            bf16x8 af[4], bfr[4];
#pragma unroll
            for (int i = 0; i < 4; i++)
                af[i] = *reinterpret_cast<const bf16x8*>(&As[(wm + i * 16 + fr) * 64 + kk * 32 + fk]);
#pragma unroll
            for (int j = 0; j < 4; j++)
                bfr[j] = *reinterpret_cast<const bf16x8*>(&Bs[(wn + j * 16 + fr) * 64 + kk * 32 + fk]);
#pragma unroll
            for (int i = 0; i < 4; i++)
#pragma unroll
                for (int j = 0; j < 4; j++)
                    acc[i][j] = __builtin_amdgcn_mfma_f32_16x16x32_bf16(af[i], bfr[j], acc[i][j], 0, 0, 0);
        }
    }

    const int crow = (lane >> 4) * 4;
#pragma unroll
    for (int i = 0; i < 4; i++)
#pragma unroll
        for (int j = 0; j < 4; j++)
#pragma unroll
            for (int r = 0; r < 4; r++)
                C[(size_t)(bm + wm + i * 16 + crow + r) * N + (bn + wn + j * 16 + fr)] = acc[i][j][r];
}

// ---------------------------------------------------------------------------
// Depthwise causal conv (fwd) + anti-causal conv (bwd) + SiLU -> bf16
// uc2b layout: [dir][b][L][DI] at ORIGINAL tau positions
// ---------------------------------------------------------------------------
__global__ __launch_bounds__(256) void convk(
    const float* __restrict__ xz, const float* __restrict__ cw,
    const float* __restrict__ cb, unsigned short* __restrict__ uc2b)
{
    int idx = blockIdx.x * 256 + threadIdx.x;          // (b, tau, d)
    int b   = idx >> 20;
    int rem = idx & ((LSEQ * DI) - 1);
    int tau = rem >> 10;
    int d   = rem & (DI - 1);

    const float* xc = xz + (size_t)b * LSEQ * (2 * DI);
    float w0 = cw[d * 4 + 0], w1 = cw[d * 4 + 1], w2 = cw[d * 4 + 2], w3 = cw[d * 4 + 3];
    float bias = cb[d];
    float accf = bias, accb = bias;
    {
        int t0 = tau - 3, t1 = tau - 2, t2 = tau - 1;
        if (t0 >= 0) accf = fmaf(w0, xc[(size_t)t0 * 2048 + d], accf);
        if (t1 >= 0) accf = fmaf(w1, xc[(size_t)t1 * 2048 + d], accf);
        if (t2 >= 0) accf = fmaf(w2, xc[(size_t)t2 * 2048 + d], accf);
        accf = fmaf(w3, xc[(size_t)tau * 2048 + d], accf);
    }
    {
        int t0 = tau + 3, t1 = tau + 2, t2 = tau + 1;
        if (t0 < LSEQ) accb = fmaf(w0, xc[(size_t)t0 * 2048 + d], accb);
        if (t1 < LSEQ) accb = fmaf(w1, xc[(size_t)t1 * 2048 + d], accb);
        if (t2 < LSEQ) accb = fmaf(w2, xc[(size_t)t2 * 2048 + d], accb);
        accb = fmaf(w3, xc[(size_t)tau * 2048 + d], accb);
    }
    uc2b[((size_t)b * LSEQ + tau) * DI + d]       = f2bf(silu_f(accf));
    uc2b[((size_t)(2 + b) * LSEQ + tau) * DI + d] = f2bf(silu_f(accb));
}

// ---------------------------------------------------------------------------
// Pass A: local chunk scans, 4 threads per channel (16 states each).
// sEnd layout: [dirb][c][d][n]
// ---------------------------------------------------------------------------
__global__ __launch_bounds__(256) void passA(
    const float* __restrict__ proj2, const unsigned short* __restrict__ uc2b,
    const float* __restrict__ A_log, float* __restrict__ sEnd,
    float* __restrict__ Pbuf)
{
    const int dl   = threadIdx.x >> 2;
    const int nq   = threadIdx.x & 3;
    const int d    = blockIdx.x * 64 + dl;
    const int c    = blockIdx.y;
    const int dirb = blockIdx.z;
    const int dir  = dirb >> 1;

    __shared__ float Bsh[TC][NS];
    const float* projbase = proj2 + (size_t)dirb * LSEQ * NPROJ;
    const unsigned short* ucb = uc2b + (size_t)dirb * LSEQ * DI;

    for (int i = threadIdx.x * 4; i < TC * NS; i += 1024) {
        int tl = i >> 6, n = i & 63;
        int t = c * TC + tl;
        int tau = dir ? (LSEQ - 1 - t) : t;
        *(float4*)&Bsh[tl][n] = *(const float4*)&projbase[(size_t)tau * NPROJ + DI + n];
    }
    __syncthreads();

    float Ad = -expf(A_log[d]);
    float s[16];
#pragma unroll
    for (int i = 0; i < 16; i++) s[i] = 0.f;
    float sumdelta = 0.f;

    for (int tl = 0; tl < TC; tl++) {
        int t = c * TC + tl;
        int tau = dir ? (LSEQ - 1 - t) : t;
        float delta = sp_f(projbase[(size_t)tau * NPROJ + d]);
        float u     = bf2f(ucb[(size_t)tau * DI + d]);
        float dA    = expf(delta * Ad);
        float du    = delta * u;
        sumdelta += delta;
        const float4* brow = (const float4*)&Bsh[tl][nq * 16];
#pragma unroll
        for (int q = 0; q < 4; q++) {
            float4 bv = brow[q];
            s[4*q+0] = fmaf(du, bv.x, dA * s[4*q+0]);
            s[4*q+1] = fmaf(du, bv.y, dA * s[4*q+1]);
            s[4*q+2] = fmaf(du, bv.z, dA * s[4*q+2]);
            s[4*q+3] = fmaf(du, bv.w, dA * s[4*q+3]);
        }
    }
    size_t base = (((size_t)dirb * NC + c) * DI + d) * NS + nq * 16;
#pragma unroll
    for (int q = 0; q < 4; q++)
        *(float4*)&sEnd[base + q * 4] = make_float4(s[4*q], s[4*q+1], s[4*q+2], s[4*q+3]);
    if (nq == 0) Pbuf[((size_t)dirb * NC + c) * DI + d] = expf(sumdelta * Ad);
}

// ---------------------------------------------------------------------------
// Pass B: sequential combine across chunks (in place: sEnd -> sInit).
// ---------------------------------------------------------------------------
__global__ __launch_bounds__(256) void passB(
    float* __restrict__ sEnd, const float* __restrict__ Pbuf)
{
    const int fl   = blockIdx.x * 256 + threadIdx.x;   // d*64 + n
    const int dirb = blockIdx.y;
    const int d    = fl >> 6;
    float run = 0.f;
    for (int c = 0; c < NC; c++) {
        size_t idx = ((size_t)(dirb * NC + c)) * (DI * NS) + fl;
        float tmp = sEnd[idx];
        sEnd[idx] = run;
        float P = Pbuf[((size_t)dirb * NC + c) * DI + d];
        run = fmaf(P, run, tmp);
    }
}

// ---------------------------------------------------------------------------
// Pass C: seeded local scan, all 4 dirb in one launch, y fused with
// silu(z)*0.5 -> bf16 per-dir buffers ygb[dirb][L][DI].
// ---------------------------------------------------------------------------
__global__ __launch_bounds__(256) void passC(
    const float* __restrict__ proj2, const unsigned short* __restrict__ uc2b,
    const float* __restrict__ xz, const float* __restrict__ sInit,
    const float* __restrict__ A_log, const float* __restrict__ Dvec,
    unsigned short* __restrict__ ygb)
{
    const int dl   = threadIdx.x >> 2;
    const int nq   = threadIdx.x & 3;
    const int d0   = blockIdx.x * 64;
    const int d    = d0 + dl;
    const int c    = blockIdx.y;
    const int dirb = blockIdx.z;
    const int dir  = dirb >> 1;
    const int b    = dirb & 1;

    __shared__ float Bsh[TC][NS];
    __shared__ float Csh[TC][NS];
    __shared__ unsigned short gsh[TC][64];
    const float* projbase = proj2 + (size_t)dirb * LSEQ * NPROJ;
    const unsigned short* ucb = uc2b + (size_t)dirb * LSEQ * DI;

    for (int i = threadIdx.x * 4; i < TC * NS; i += 1024) {
        int tl = i >> 6, n = i & 63;
        int t = c * TC + tl;
        int tau = dir ? (LSEQ - 1 - t) : t;
        *(float4*)&Bsh[tl][n] = *(const float4*)&projbase[(size_t)tau * NPROJ + DI + n];
        *(float4*)&Csh[tl][n] = *(const float4*)&projbase[(size_t)tau * NPROJ + DI + NS + n];
    }
    __syncthreads();

    float Ad = -expf(A_log[d]);
    float Dd = Dvec[d];
    float s[16];
    size_t sbase = (((size_t)dirb * NC + c) * DI + d) * NS + nq * 16;
#pragma unroll
    for (int q = 0; q < 4; q++) {
        float4 v = *(const float4*)&sInit[sbase + q * 4];
        s[4*q] = v.x; s[4*q+1] = v.y; s[4*q+2] = v.z; s[4*q+3] = v.w;
    }

    for (int tl = 0; tl < TC; tl++) {
        int t = c * TC + tl;
        int tau = dir ? (LSEQ - 1 - t) : t;
        float delta = sp_f(projbase[(size_t)tau * NPROJ + d]);
        float u     = bf2f(ucb[(size_t)tau * DI + d]);
        float dA    = expf(delta * Ad);
        float du    = delta * u;
        float yp = 0.f;
        const float4* brow = (const float4*)&Bsh[tl][nq * 16];
        const float4* crow = (const float4*)&Csh[tl][nq * 16];
#pragma unroll
        for (int q = 0; q < 4; q++) {
            float4 bv = brow[q];
            float4 cv = crow[q];
            float s0 = fmaf(du, bv.x, dA * s[4*q+0]); s[4*q+0] = s0; yp = fmaf(cv.x, s0, yp);
            float s1 = fmaf(du, bv.y, dA * s[4*q+1]); s[4*q+1] = s1; yp = fmaf(cv.y, s1, yp);
            float s2 = fmaf(du, bv.z, dA * s[4*q+2]); s[4*q+2] = s2; yp = fmaf(cv.z, s2, yp);
            float s3 = fmaf(du, bv.w, dA * s[4*q+3]); s[4*q+3] = s3; yp = fmaf(cv.w, s3, yp);
        }
        yp += __shfl_xor(yp, 1);
        yp += __shfl_xor(yp, 2);
        float y = fmaf(Dd, u, yp);
        float z = xz[((size_t)b * LSEQ + tau) * (2 * DI) + DI + d];
        if (nq == 0) gsh[tl][dl] = f2bf(0.5f * y * silu_f(z));
    }
    __syncthreads();
    // coalesced write-out of the chunk's 64x64 g tile
    for (int i = threadIdx.x * 4; i < TC * 64; i += 1024) {
        int tl = i >> 6, col = i & 63;
        int t = c * TC + tl;
        int tau = dir ? (LSEQ - 1 - t) : t;
        *(ushort4*)&ygb[((size_t)dirb * LSEQ + tau) * DI + d0 + col] = *(const ushort4*)&gsh[tl][col];
    }
}

// ---------------------------------------------------------------------------
extern "C" void kernel_launch(void* const* d_in, const int* in_sizes, int n_in,
                              void* d_out, int out_size, void* d_ws, size_t ws_size,
                              hipStream_t stream)
{
    const float* x      = (const float*)d_in[0];
    const float* W_in   = (const float*)d_in[1];
    const float* conv_w = (const float*)d_in[2];
    const float* conv_b = (const float*)d_in[3];
    const float* W_xprj = (const float*)d_in[4];
    const float* A_log  = (const float*)d_in[5];
    const float* Dvec   = (const float*)d_in[6];
    const float* W_out  = (const float*)d_in[7];
    float* out = (float*)d_out;

    // workspace (~70.5 MB; aliased regions are dead-before-overwrite)
    float* ws    = (float*)d_ws;
    float* xz    = ws;                              // 4.19M f  [B][L][2*DI]
    float* proj2 = xz    + 4194304;                 // 4.72M f  [4][L][NPROJ]
    float* sEnd  = proj2 + 4718592;                 // 4.19M f  [4][NC][DI][NS]
    float* Pbuf  = sEnd  + 4194304;                 // 65536 f
    unsigned short* uc2b = (unsigned short*)(Pbuf + 65536);  // 4.19M sh
    unsigned short* ygb  = uc2b + 4194304;          // 4.19M sh [4][L][DI]
    unsigned short* wob  = ygb  + 4194304;          // 0.52M sh
    // aliases: consumed before their host region is written
    unsigned short* xb   = (unsigned short*)sEnd;   // dead after gemm1; sEnd written in passA
    unsigned short* winb = xb + 1048576;
    unsigned short* wxb  = (unsigned short*)ygb;    // dead after gemm2; ygb written in passC

    // 1) bf16 casts
    cast4<<<1024, 256, 0, stream>>>(x, xb, LSEQ * B_ * DM);
    cast4<<<1024, 256, 0, stream>>>(W_in, winb, 2 * DI * DM);
    cast4<<<1152, 256, 0, stream>>>(W_xprj, wxb, NPROJ * DI);
    cast4<<<512, 256, 0, stream>>>(W_out, wob, DM * DI);

    // 2) xz = x @ W_in^T (M=2048, N=2048, K=512)
    gemm_bf16<<<dim3(16, 16), 256, 0, stream>>>(xb, nullptr, winb, xz, B_ * LSEQ, 2 * DI, DM);

    // 3) conv both directions + SiLU -> bf16
    convk<<<(B_ * LSEQ * DI) / 256, 256, 0, stream>>>(xz, conv_w, conv_b, uc2b);

    // 4) proj2 = uc2 @ W_xproj^T (M=4096, N=1152, K=1024)
    gemm_bf16<<<dim3(9, 32), 256, 0, stream>>>(uc2b, nullptr, wxb, proj2, 4 * LSEQ, NPROJ, DI);

    // 5) pass A: local chunk scans
    passA<<<dim3(16, NC, 4), 256, 0, stream>>>(proj2, uc2b, A_log, sEnd, Pbuf);

    // 6) pass B: chunk-state combine
    passB<<<dim3(256, 4), 256, 0, stream>>>(sEnd, Pbuf);

    // 7) pass C: seeded scan + y*silu(z)*0.5 -> per-dir bf16
    passC<<<dim3(16, NC, 4), 256, 0, stream>>>(proj2, uc2b, xz, sEnd, A_log, Dvec, ygb);

    // 8) out = (yf + yb) @ W_out^T (M=2048, N=512, K=1024)
    gemm_bf16<<<dim3(4, 16), 256, 0, stream>>>(ygb, ygb + (size_t)2 * LSEQ * DI, wob, out, B_ * LSEQ, DM, DI);
}

// Round 4
// 274.129 us; speedup vs baseline: 1.9787x; 1.3712x over previous
//
#include <hip/hip_runtime.h>
#include <math.h>

#define B_    2
#define LSEQ  1024
#define DM    512
#define DI    1024
#define NS    64
#define NPROJ (DI + 2*NS)   // 1152
#define TC    64
#define NC    (LSEQ/TC)     // 16

typedef __bf16 bf16x8 __attribute__((ext_vector_type(8)));
typedef float  f32x4  __attribute__((ext_vector_type(4)));

__device__ __forceinline__ float sp_f(float x)   { return fmaxf(x, 0.f) + log1pf(expf(-fabsf(x))); }
__device__ __forceinline__ float silu_f(float x) { return x / (1.f + expf(-x)); }
__device__ __forceinline__ unsigned short f2bf(float f) {
    unsigned int u = __float_as_uint(f);
    u += 0x7FFF + ((u >> 16) & 1);          // RNE
    return (unsigned short)(u >> 16);
}
__device__ __forceinline__ float bf2f(unsigned short h) {
    return __uint_as_float(((unsigned int)h) << 16);
}
// add two packs of 8 bf16 in f32, repack RNE
__device__ __forceinline__ uint4 bfadd8(uint4 a, uint4 b) {
    uint4 r;
    unsigned* pa = (unsigned*)&a; unsigned* pb = (unsigned*)&b; unsigned* pr = (unsigned*)&r;
#pragma unroll
    for (int i = 0; i < 4; i++) {
        unsigned wa = pa[i], wb = pb[i];
        float lo = __uint_as_float(wa << 16) + __uint_as_float(wb << 16);
        float hi = __uint_as_float(wa & 0xffff0000u) + __uint_as_float(wb & 0xffff0000u);
        pr[i] = ((unsigned)f2bf(lo)) | (((unsigned)f2bf(hi)) << 16);
    }
    return r;
}

// ---------------------------------------------------------------------------
// All 4 f32->bf16 weight/input casts in one launch. Totals: 1048576 + 1048576
// + 1179648 + 524288 = 3801088 elems, 4/thread -> 3712 blocks exactly.
// ---------------------------------------------------------------------------
__global__ __launch_bounds__(256) void castall(
    const float* __restrict__ x, const float* __restrict__ W_in,
    const float* __restrict__ W_xproj, const float* __restrict__ W_out,
    unsigned short* __restrict__ xb, unsigned short* __restrict__ winb,
    unsigned short* __restrict__ wxb, unsigned short* __restrict__ wob)
{
    int i = (blockIdx.x * 256 + threadIdx.x) * 4;
    const float* s; unsigned short* dst; int off;
    if (i < 1048576)      { s = x;       dst = xb;   off = i; }
    else if (i < 2097152) { s = W_in;    dst = winb; off = i - 1048576; }
    else if (i < 3276800) { s = W_xproj; dst = wxb;  off = i - 2097152; }
    else                  { s = W_out;   dst = wob;  off = i - 3276800; }
    float4 v = *(const float4*)(s + off);
    ushort4 o;
    o.x = f2bf(v.x); o.y = f2bf(v.y); o.z = f2bf(v.z); o.w = f2bf(v.w);
    *(ushort4*)(dst + off) = o;
}

// ---------------------------------------------------------------------------
// bf16 MFMA GEMM: C[M,N] = (A [+ A2]) [M,K] * B[N,K]^T, f32 out.
// 128x128 tile, BK=64, 256 threads (4 waves, 2x2), each wave 64x64.
// ---------------------------------------------------------------------------
__global__ __launch_bounds__(256) void gemm_bf16(
    const unsigned short* __restrict__ A, const unsigned short* __restrict__ A2,
    const unsigned short* __restrict__ B,
    float* __restrict__ C, int M, int N, int K)
{
    __shared__ short As[128 * 64];
    __shared__ short Bs[128 * 64];
    const int tid  = threadIdx.x;
    const int lane = tid & 63, wid = tid >> 6;
    const int bm = blockIdx.y * 128, bn = blockIdx.x * 128;
    const int wm = (wid >> 1) * 64,  wn = (wid & 1) * 64;
    const int fr = lane & 15, fk = (lane >> 4) * 8;

    f32x4 acc[4][4];
#pragma unroll
    for (int i = 0; i < 4; i++)
#pragma unroll
        for (int j = 0; j < 4; j++) acc[i][j] = (f32x4)0.f;

    uint4 ra[4], rb[4];
#pragma unroll
    for (int r = 0; r < 4; r++) {                   // prefetch k0 = 0
        int o = tid * 16 + r * 4096;                // byte offset in 16KB tile
        int row = o >> 7, colb = o & 127;
        ra[r] = *(const uint4*)((const char*)A + ((size_t)(bm + row) * K) * 2 + colb);
        if (A2) ra[r] = bfadd8(ra[r], *(const uint4*)((const char*)A2 + ((size_t)(bm + row) * K) * 2 + colb));
        rb[r] = *(const uint4*)((const char*)B + ((size_t)(bn + row) * K) * 2 + colb);
    }

    for (int k0 = 0; k0 < K; k0 += 64) {
        __syncthreads();
#pragma unroll
        for (int r = 0; r < 4; r++) {
            *(uint4*)((char*)As + tid * 16 + r * 4096) = ra[r];
            *(uint4*)((char*)Bs + tid * 16 + r * 4096) = rb[r];
        }
        __syncthreads();
        if (k0 + 64 < K) {
#pragma unroll
            for (int r = 0; r < 4; r++) {
                int o = tid * 16 + r * 4096;
                int row = o >> 7, colb = o & 127;
                ra[r] = *(const uint4*)((const char*)A + ((size_t)(bm + row) * K + k0 + 64) * 2 + colb);
                if (A2) ra[r] = bfadd8(ra[r], *(const uint4*)((const char*)A2 + ((size_t)(bm + row) * K + k0 + 64) * 2 + colb));
                rb[r] = *(const uint4*)((const char*)B + ((size_t)(bn + row) * K + k0 + 64) * 2 + colb);
            }
        }
#pragma unroll
        for (int kk = 0; kk < 2; kk++) {
            bf16x8 af[4], bfr[4];
#pragma unroll
            for (int i = 0; i < 4; i++)
                af[i] = *reinterpret_cast<const bf16x8*>(&As[(wm + i * 16 + fr) * 64 + kk * 32 + fk]);
#pragma unroll
            for (int j = 0; j < 4; j++)
                bfr[j] = *reinterpret_cast<const bf16x8*>(&Bs[(wn + j * 16 + fr) * 64 + kk * 32 + fk]);
#pragma unroll
            for (int i = 0; i < 4; i++)
#pragma unroll
                for (int j = 0; j < 4; j++)
                    acc[i][j] = __builtin_amdgcn_mfma_f32_16x16x32_bf16(af[i], bfr[j], acc[i][j], 0, 0, 0);
        }
    }

    const int crow = (lane >> 4) * 4;
#pragma unroll
    for (int i = 0; i < 4; i++)
#pragma unroll
        for (int j = 0; j < 4; j++)
#pragma unroll
            for (int r = 0; r < 4; r++)
                C[(size_t)(bm + wm + i * 16 + crow + r) * N + (bn + wn + j * 16 + fr)] = acc[i][j][r];
}

// ---------------------------------------------------------------------------
// Depthwise causal conv (fwd) + anti-causal conv (bwd) + SiLU -> bf16
// uc2b layout: [dir][b][L][DI] at ORIGINAL tau positions
// ---------------------------------------------------------------------------
__global__ __launch_bounds__(256) void convk(
    const float* __restrict__ xz, const float* __restrict__ cw,
    const float* __restrict__ cb, unsigned short* __restrict__ uc2b)
{
    int idx = blockIdx.x * 256 + threadIdx.x;          // (b, tau, d)
    int b   = idx >> 20;
    int rem = idx & ((LSEQ * DI) - 1);
    int tau = rem >> 10;
    int d   = rem & (DI - 1);

    const float* xc = xz + (size_t)b * LSEQ * (2 * DI);
    float w0 = cw[d * 4 + 0], w1 = cw[d * 4 + 1], w2 = cw[d * 4 + 2], w3 = cw[d * 4 + 3];
    float bias = cb[d];
    float accf = bias, accb = bias;
    {
        int t0 = tau - 3, t1 = tau - 2, t2 = tau - 1;
        if (t0 >= 0) accf = fmaf(w0, xc[(size_t)t0 * 2048 + d], accf);
        if (t1 >= 0) accf = fmaf(w1, xc[(size_t)t1 * 2048 + d], accf);
        if (t2 >= 0) accf = fmaf(w2, xc[(size_t)t2 * 2048 + d], accf);
        accf = fmaf(w3, xc[(size_t)tau * 2048 + d], accf);
    }
    {
        int t0 = tau + 3, t1 = tau + 2, t2 = tau + 1;
        if (t0 < LSEQ) accb = fmaf(w0, xc[(size_t)t0 * 2048 + d], accb);
        if (t1 < LSEQ) accb = fmaf(w1, xc[(size_t)t1 * 2048 + d], accb);
        if (t2 < LSEQ) accb = fmaf(w2, xc[(size_t)t2 * 2048 + d], accb);
        accb = fmaf(w3, xc[(size_t)tau * 2048 + d], accb);
    }
    uc2b[((size_t)b * LSEQ + tau) * DI + d]       = f2bf(silu_f(accf));
    uc2b[((size_t)(2 + b) * LSEQ + tau) * DI + d] = f2bf(silu_f(accb));
}

// ---------------------------------------------------------------------------
// Prep: hoist all transcendentals out of the scan. In place:
//   proj2 delta-col  ->  dA = exp(softplus(delta_raw) * A_d)   (f32)
//   uc2b  u          ->  du = softplus(delta_raw) * u          (bf16)
// New: Ebuf = 0.5*silu(z)*D*u (bf16), Fbuf = 0.5*silu(z) (bf16, dir0 only).
// ---------------------------------------------------------------------------
__global__ __launch_bounds__(256) void prep(
    float* __restrict__ proj2, unsigned short* __restrict__ uc2b,
    const float* __restrict__ xz, const float* __restrict__ A_log,
    const float* __restrict__ Dvec, unsigned short* __restrict__ Ebuf,
    unsigned short* __restrict__ Fbuf)
{
    int idx  = blockIdx.x * 256 + threadIdx.x;     // (dirb, tau, d)
    int dirb = idx >> 20;
    int rem  = idx & ((LSEQ * DI) - 1);
    int tau  = rem >> 10;
    int d    = rem & (DI - 1);
    int b    = dirb & 1;
    int dir  = dirb >> 1;

    size_t pidx = (size_t)dirb * LSEQ * NPROJ + (size_t)tau * NPROJ + d;
    float delta = sp_f(proj2[pidx]);
    float Ad    = -expf(A_log[d]);
    proj2[pidx] = expf(delta * Ad);

    size_t uidx = ((size_t)dirb * LSEQ + tau) * DI + d;
    float u = bf2f(uc2b[uidx]);
    uc2b[uidx] = f2bf(delta * u);

    float z = xz[((size_t)b * LSEQ + tau) * (2 * DI) + DI + d];
    float F = 0.5f * silu_f(z);
    Ebuf[uidx] = f2bf(F * Dvec[d] * u);
    if (dir == 0) Fbuf[((size_t)b * LSEQ + tau) * DI + d] = f2bf(F);
}

// ---------------------------------------------------------------------------
// Pass A: local chunk scans, 4 threads/channel (16 states each).
// Inner loop: 2 loads + 1 mul + 16 FMA. sEnd layout: [dirb][c][d][n]
// ---------------------------------------------------------------------------
__global__ __launch_bounds__(256) void passA(
    const float* __restrict__ proj2, const unsigned short* __restrict__ du2b,
    float* __restrict__ sEnd, float* __restrict__ Pbuf)
{
    const int dl   = threadIdx.x >> 2;
    const int nq   = threadIdx.x & 3;
    const int d    = blockIdx.x * 64 + dl;
    const int c    = blockIdx.y;
    const int dirb = blockIdx.z;
    const int dir  = dirb >> 1;

    __shared__ float Bsh[TC][NS];
    const float* projbase = proj2 + (size_t)dirb * LSEQ * NPROJ;
    const unsigned short* ducb = du2b + (size_t)dirb * LSEQ * DI;

    for (int i = threadIdx.x * 4; i < TC * NS; i += 1024) {
        int tl = i >> 6, n = i & 63;
        int t = c * TC + tl;
        int tau = dir ? (LSEQ - 1 - t) : t;
        *(float4*)&Bsh[tl][n] = *(const float4*)&projbase[(size_t)tau * NPROJ + DI + n];
    }
    __syncthreads();

    float s[16];
#pragma unroll
    for (int i = 0; i < 16; i++) s[i] = 0.f;
    float P = 1.f;

    int tau0 = dir ? (LSEQ - 1 - c * TC) : (c * TC);
    long stp = dir ? -1 : 1;
    const float* pDA = projbase + (size_t)tau0 * NPROJ + d;
    const unsigned short* pDU = ducb + (size_t)tau0 * DI + d;

    for (int tl = 0; tl < TC; tl++) {
        float dA = *pDA;
        float du = bf2f(*pDU);
        pDA += stp * NPROJ; pDU += stp * DI;
        P *= dA;
        const float4* brow = (const float4*)&Bsh[tl][nq * 16];
#pragma unroll
        for (int q = 0; q < 4; q++) {
            float4 bv = brow[q];
            s[4*q+0] = fmaf(du, bv.x, dA * s[4*q+0]);
            s[4*q+1] = fmaf(du, bv.y, dA * s[4*q+1]);
            s[4*q+2] = fmaf(du, bv.z, dA * s[4*q+2]);
            s[4*q+3] = fmaf(du, bv.w, dA * s[4*q+3]);
        }
    }
    size_t base = (((size_t)dirb * NC + c) * DI + d) * NS + nq * 16;
#pragma unroll
    for (int q = 0; q < 4; q++)
        *(float4*)&sEnd[base + q * 4] = make_float4(s[4*q], s[4*q+1], s[4*q+2], s[4*q+3]);
    if (nq == 0) Pbuf[((size_t)dirb * NC + c) * DI + d] = P;
}

// ---------------------------------------------------------------------------
// Pass B: sequential combine across chunks (in place: sEnd -> sInit).
// ---------------------------------------------------------------------------
__global__ __launch_bounds__(256) void passB(
    float* __restrict__ sEnd, const float* __restrict__ Pbuf)
{
    const int fl   = blockIdx.x * 256 + threadIdx.x;   // d*64 + n
    const int dirb = blockIdx.y;
    const int d    = fl >> 6;
    float run = 0.f;
    for (int c = 0; c < NC; c++) {
        size_t idx = ((size_t)(dirb * NC + c)) * (DI * NS) + fl;
        float tmp = sEnd[idx];
        sEnd[idx] = run;
        float P = Pbuf[((size_t)dirb * NC + c) * DI + d];
        run = fmaf(P, run, tmp);
    }
}

// ---------------------------------------------------------------------------
// Pass C: seeded local scan; inner loop: 4 loads + 32 FMA + 2 shfl; epilogue
// g = fma(F, y_scan, E) -> bf16 ygb[dirb][L][DI].
// ---------------------------------------------------------------------------
__global__ __launch_bounds__(256) void passC(
    const float* __restrict__ proj2, const unsigned short* __restrict__ du2b,
    const unsigned short* __restrict__ Ebuf, const unsigned short* __restrict__ Fbuf,
    const float* __restrict__ sInit, unsigned short* __restrict__ ygb)
{
    const int dl   = threadIdx.x >> 2;
    const int nq   = threadIdx.x & 3;
    const int d0   = blockIdx.x * 64;
    const int d    = d0 + dl;
    const int c    = blockIdx.y;
    const int dirb = blockIdx.z;
    const int dir  = dirb >> 1;
    const int b    = dirb & 1;

    __shared__ float Bsh[TC][NS];
    __shared__ float Csh[TC][NS];
    __shared__ unsigned short gsh[TC][64];
    const float* projbase = proj2 + (size_t)dirb * LSEQ * NPROJ;
    const unsigned short* ducb = du2b + (size_t)dirb * LSEQ * DI;

    for (int i = threadIdx.x * 4; i < TC * NS; i += 1024) {
        int tl = i >> 6, n = i & 63;
        int t = c * TC + tl;
        int tau = dir ? (LSEQ - 1 - t) : t;
        *(float4*)&Bsh[tl][n] = *(const float4*)&projbase[(size_t)tau * NPROJ + DI + n];
        *(float4*)&Csh[tl][n] = *(const float4*)&projbase[(size_t)tau * NPROJ + DI + NS + n];
    }
    __syncthreads();

    float s[16];
    size_t sbase = (((size_t)dirb * NC + c) * DI + d) * NS + nq * 16;
#pragma unroll
    for (int q = 0; q < 4; q++) {
        float4 v = *(const float4*)&sInit[sbase + q * 4];
        s[4*q] = v.x; s[4*q+1] = v.y; s[4*q+2] = v.z; s[4*q+3] = v.w;
    }

    int tau0 = dir ? (LSEQ - 1 - c * TC) : (c * TC);
    long stp = dir ? -1 : 1;
    const float* pDA = projbase + (size_t)tau0 * NPROJ + d;
    const unsigned short* pDU = ducb + (size_t)tau0 * DI + d;
    const unsigned short* pE  = Ebuf + ((size_t)dirb * LSEQ + tau0) * DI + d;
    const unsigned short* pF  = Fbuf + ((size_t)b * LSEQ + tau0) * DI + d;

    for (int tl = 0; tl < TC; tl++) {
        float dA = *pDA;
        float du = bf2f(*pDU);
        float E  = bf2f(*pE);
        float F  = bf2f(*pF);
        pDA += stp * NPROJ; pDU += stp * DI; pE += stp * DI; pF += stp * DI;
        float yp = 0.f;
        const float4* brow = (const float4*)&Bsh[tl][nq * 16];
        const float4* crow = (const float4*)&Csh[tl][nq * 16];
#pragma unroll
        for (int q = 0; q < 4; q++) {
            float4 bv = brow[q];
            float4 cv = crow[q];
            float s0 = fmaf(du, bv.x, dA * s[4*q+0]); s[4*q+0] = s0; yp = fmaf(cv.x, s0, yp);
            float s1 = fmaf(du, bv.y, dA * s[4*q+1]); s[4*q+1] = s1; yp = fmaf(cv.y, s1, yp);
            float s2 = fmaf(du, bv.z, dA * s[4*q+2]); s[4*q+2] = s2; yp = fmaf(cv.z, s2, yp);
            float s3 = fmaf(du, bv.w, dA * s[4*q+3]); s[4*q+3] = s3; yp = fmaf(cv.w, s3, yp);
        }
        yp += __shfl_xor(yp, 1);
        yp += __shfl_xor(yp, 2);
        if (nq == 0) gsh[tl][dl] = f2bf(fmaf(F, yp, E));
    }
    __syncthreads();
    // coalesced write-out of the chunk's 64x64 g tile
    for (int i = threadIdx.x * 4; i < TC * 64; i += 1024) {
        int tl = i >> 6, col = i & 63;
        int t = c * TC + tl;
        int tau = dir ? (LSEQ - 1 - t) : t;
        *(ushort4*)&ygb[((size_t)dirb * LSEQ + tau) * DI + d0 + col] = *(const ushort4*)&gsh[tl][col];
    }
}

// ---------------------------------------------------------------------------
extern "C" void kernel_launch(void* const* d_in, const int* in_sizes, int n_in,
                              void* d_out, int out_size, void* d_ws, size_t ws_size,
                              hipStream_t stream)
{
    const float* x      = (const float*)d_in[0];
    const float* W_in   = (const float*)d_in[1];
    const float* conv_w = (const float*)d_in[2];
    const float* conv_b = (const float*)d_in[3];
    const float* W_xprj = (const float*)d_in[4];
    const float* A_log  = (const float*)d_in[5];
    const float* Dvec   = (const float*)d_in[6];
    const float* W_out  = (const float*)d_in[7];
    float* out = (float*)d_out;

    // workspace (~66.3 MB; aliased regions are dead-before-overwrite)
    float* ws    = (float*)d_ws;
    float* proj2 = ws;                              // 4,718,592 f  [4][L][NPROJ] (delta-col -> dA after prep)
    unsigned short* uc2b = (unsigned short*)(proj2 + 4718592); // 4,194,304 sh (u -> du after prep)
    unsigned short* Ebuf = uc2b + 4194304;          // 4,194,304 sh [4][L][DI]
    unsigned short* Fbuf = Ebuf + 4194304;          // 2,097,152 sh [B][L][DI]
    float* xz    = (float*)(Fbuf + 2097152);        // 4,194,304 f  [B][L][2*DI]
    float* sEnd  = xz;                              // alias: xz dead after prep; sEnd written in passA
    float* Pbuf  = xz + 4194304;                    // 65,536 f
    unsigned short* ygb  = (unsigned short*)(Pbuf + 65536);    // 4,194,304 sh [4][L][DI]
    unsigned short* wob  = ygb + 4194304;           // 524,288 sh
    // cast aliases: consumed before their host region is written
    unsigned short* xb   = Ebuf;                    // dead after gemm1; Ebuf written in prep
    unsigned short* winb = Ebuf + 1048576;
    unsigned short* wxb  = ygb;                     // dead after gemm2; ygb written in passC

    // 1) all bf16 casts in one launch
    castall<<<3712, 256, 0, stream>>>(x, W_in, W_xprj, W_out, xb, winb, wxb, wob);

    // 2) xz = x @ W_in^T (M=2048, N=2048, K=512)
    gemm_bf16<<<dim3(16, 16), 256, 0, stream>>>(xb, nullptr, winb, xz, B_ * LSEQ, 2 * DI, DM);

    // 3) conv both directions + SiLU -> bf16 u
    convk<<<(B_ * LSEQ * DI) / 256, 256, 0, stream>>>(xz, conv_w, conv_b, uc2b);

    // 4) proj2 = uc2 @ W_xproj^T (M=4096, N=1152, K=1024)
    gemm_bf16<<<dim3(9, 32), 256, 0, stream>>>(uc2b, nullptr, wxb, proj2, 4 * LSEQ, NPROJ, DI);

    // 5) prep: delta->dA (in place), u->du (in place), E/F buffers
    prep<<<(4 * LSEQ * DI) / 256, 256, 0, stream>>>(proj2, uc2b, xz, A_log, Dvec, Ebuf, Fbuf);

    // 6) pass A: local chunk scans
    passA<<<dim3(16, NC, 4), 256, 0, stream>>>(proj2, uc2b, sEnd, Pbuf);

    // 7) pass B: chunk-state combine
    passB<<<dim3(256, 4), 256, 0, stream>>>(sEnd, Pbuf);

    // 8) pass C: seeded scan -> g (bf16 per dirb)
    passC<<<dim3(16, NC, 4), 256, 0, stream>>>(proj2, uc2b, Ebuf, Fbuf, sEnd, ygb);

    // 9) out = (yf + yb) @ W_out^T (M=2048, N=512, K=1024)
    gemm_bf16<<<dim3(4, 16), 256, 0, stream>>>(ygb, ygb + (size_t)2 * LSEQ * DI, wob, out, B_ * LSEQ, DM, DI);
}

// Round 5
// 232.888 us; speedup vs baseline: 2.3291x; 1.1771x over previous
//
#include <hip/hip_runtime.h>
#include <math.h>

#define B_    2
#define LSEQ  1024
#define DM    512
#define DI    1024
#define NS    64
#define NPROJ (DI + 2*NS)   // 1152
#define TC    64
#define NC    (LSEQ/TC)     // 16

typedef __bf16 bf16x8 __attribute__((ext_vector_type(8)));
typedef float  f32x4  __attribute__((ext_vector_type(4)));

__device__ __forceinline__ float sp_f(float x)   { return fmaxf(x, 0.f) + log1pf(expf(-fabsf(x))); }
__device__ __forceinline__ float silu_f(float x) { return x / (1.f + expf(-x)); }
__device__ __forceinline__ unsigned short f2bf(float f) {
    unsigned int u = __float_as_uint(f);
    u += 0x7FFF + ((u >> 16) & 1);          // RNE
    return (unsigned short)(u >> 16);
}
__device__ __forceinline__ float bf2f(unsigned short h) {
    return __uint_as_float(((unsigned int)h) << 16);
}
// add two packs of 8 bf16 in f32, repack RNE
__device__ __forceinline__ uint4 bfadd8(uint4 a, uint4 b) {
    uint4 r;
    unsigned* pa = (unsigned*)&a; unsigned* pb = (unsigned*)&b; unsigned* pr = (unsigned*)&r;
#pragma unroll
    for (int i = 0; i < 4; i++) {
        unsigned wa = pa[i], wb = pb[i];
        float lo = __uint_as_float(wa << 16) + __uint_as_float(wb << 16);
        float hi = __uint_as_float(wa & 0xffff0000u) + __uint_as_float(wb & 0xffff0000u);
        pr[i] = ((unsigned)f2bf(lo)) | (((unsigned)f2bf(hi)) << 16);
    }
    return r;
}

// ---------------------------------------------------------------------------
// All 4 f32->bf16 casts in one launch (3712 blocks exactly).
// ---------------------------------------------------------------------------
__global__ __launch_bounds__(256) void castall(
    const float* __restrict__ x, const float* __restrict__ W_in,
    const float* __restrict__ W_xproj, const float* __restrict__ W_out,
    unsigned short* __restrict__ xb, unsigned short* __restrict__ winb,
    unsigned short* __restrict__ wxb, unsigned short* __restrict__ wob)
{
    int i = (blockIdx.x * 256 + threadIdx.x) * 4;
    const float* s; unsigned short* dst; int off;
    if (i < 1048576)      { s = x;       dst = xb;   off = i; }
    else if (i < 2097152) { s = W_in;    dst = winb; off = i - 1048576; }
    else if (i < 3276800) { s = W_xproj; dst = wxb;  off = i - 2097152; }
    else                  { s = W_out;   dst = wob;  off = i - 3276800; }
    float4 v = *(const float4*)(s + off);
    ushort4 o;
    o.x = f2bf(v.x); o.y = f2bf(v.y); o.z = f2bf(v.z); o.w = f2bf(v.w);
    *(ushort4*)(dst + off) = o;
}

// ---------------------------------------------------------------------------
// bf16 MFMA GEMM, 64x64 tile, BK=64, 256 threads (4 waves, 2x2), wave = 32x32.
// C[kz][M,N] = (A [+ A2])[M, kslice] * B[N, kslice]^T ; ks = K-split count.
// Small tiles maximize grid size: these GEMMs are tiny, parallelism > reuse.
// ---------------------------------------------------------------------------
__global__ __launch_bounds__(256) void gemm64(
    const unsigned short* __restrict__ A, const unsigned short* __restrict__ A2,
    const unsigned short* __restrict__ B,
    float* __restrict__ C, int M, int N, int K, int ks)
{
    __shared__ short As[64 * 64];
    __shared__ short Bs[64 * 64];
    const int tid  = threadIdx.x;
    const int lane = tid & 63, wid = tid >> 6;
    const int bm = blockIdx.y * 64, bn = blockIdx.x * 64;
    const int wm = (wid >> 1) * 32, wn = (wid & 1) * 32;
    const int fr = lane & 15, fk = (lane >> 4) * 8;
    const int Kc = K / ks;
    const int k0beg = blockIdx.z * Kc;
    const int k0end = k0beg + Kc;
    float* Cz = C + (size_t)blockIdx.z * M * N;

    f32x4 acc[2][2];
#pragma unroll
    for (int i = 0; i < 2; i++)
#pragma unroll
        for (int j = 0; j < 2; j++) acc[i][j] = (f32x4)0.f;

    uint4 ra[2], rb[2];
#pragma unroll
    for (int r = 0; r < 2; r++) {                   // prefetch first K-step
        int o = tid * 16 + r * 4096;                // byte offset in 8KB tile
        int row = o >> 7, colb = o & 127;           // 64 cols * 2B = 128 B/row
        ra[r] = *(const uint4*)((const char*)A + ((size_t)(bm + row) * K + k0beg) * 2 + colb);
        if (A2) ra[r] = bfadd8(ra[r], *(const uint4*)((const char*)A2 + ((size_t)(bm + row) * K + k0beg) * 2 + colb));
        rb[r] = *(const uint4*)((const char*)B + ((size_t)(bn + row) * K + k0beg) * 2 + colb);
    }

    for (int k0 = k0beg; k0 < k0end; k0 += 64) {
        __syncthreads();
#pragma unroll
        for (int r = 0; r < 2; r++) {
            *(uint4*)((char*)As + tid * 16 + r * 4096) = ra[r];
            *(uint4*)((char*)Bs + tid * 16 + r * 4096) = rb[r];
        }
        __syncthreads();
        if (k0 + 64 < k0end) {
#pragma unroll
            for (int r = 0; r < 2; r++) {
                int o = tid * 16 + r * 4096;
                int row = o >> 7, colb = o & 127;
                ra[r] = *(const uint4*)((const char*)A + ((size_t)(bm + row) * K + k0 + 64) * 2 + colb);
                if (A2) ra[r] = bfadd8(ra[r], *(const uint4*)((const char*)A2 + ((size_t)(bm + row) * K + k0 + 64) * 2 + colb));
                rb[r] = *(const uint4*)((const char*)B + ((size_t)(bn + row) * K + k0 + 64) * 2 + colb);
            }
        }
#pragma unroll
        for (int kk = 0; kk < 2; kk++) {
            bf16x8 af[2], bfr[2];
#pragma unroll
            for (int i = 0; i < 2; i++)
                af[i] = *reinterpret_cast<const bf16x8*>(&As[(wm + i * 16 + fr) * 64 + kk * 32 + fk]);
#pragma unroll
            for (int j = 0; j < 2; j++)
                bfr[j] = *reinterpret_cast<const bf16x8*>(&Bs[(wn + j * 16 + fr) * 64 + kk * 32 + fk]);
#pragma unroll
            for (int i = 0; i < 2; i++)
#pragma unroll
                for (int j = 0; j < 2; j++)
                    acc[i][j] = __builtin_amdgcn_mfma_f32_16x16x32_bf16(af[i], bfr[j], acc[i][j], 0, 0, 0);
        }
    }

    const int crow = (lane >> 4) * 4;
#pragma unroll
    for (int i = 0; i < 2; i++)
#pragma unroll
        for (int j = 0; j < 2; j++)
#pragma unroll
            for (int r = 0; r < 2; r++) {
                // two consecutive rows share nothing; write scalar f32 (4 per i,j)
                Cz[(size_t)(bm + wm + i * 16 + crow + 2 * r) * N + (bn + wn + j * 16 + fr)]     = acc[i][j][2 * r];
                Cz[(size_t)(bm + wm + i * 16 + crow + 2 * r + 1) * N + (bn + wn + j * 16 + fr)] = acc[i][j][2 * r + 1];
            }
}

// ---------------------------------------------------------------------------
// Split-K reduce: out = p0+p1+p2+p3 (float4 per thread), n = M*N
// ---------------------------------------------------------------------------
__global__ __launch_bounds__(256) void reduce4(
    const float* __restrict__ p, float* __restrict__ out, int n)
{
    int i = (blockIdx.x * 256 + threadIdx.x) * 4;
    if (i >= n) return;
    float4 a = *(const float4*)(p + i);
    float4 b = *(const float4*)(p + n + i);
    float4 c = *(const float4*)(p + 2 * n + i);
    float4 d = *(const float4*)(p + 3 * n + i);
    float4 o;
    o.x = (a.x + b.x) + (c.x + d.x);
    o.y = (a.y + b.y) + (c.y + d.y);
    o.z = (a.z + b.z) + (c.z + d.z);
    o.w = (a.w + b.w) + (c.w + d.w);
    *(float4*)(out + i) = o;
}

// ---------------------------------------------------------------------------
// Depthwise causal conv (fwd) + anti-causal conv (bwd) + SiLU -> bf16
// ---------------------------------------------------------------------------
__global__ __launch_bounds__(256) void convk(
    const float* __restrict__ xz, const float* __restrict__ cw,
    const float* __restrict__ cb, unsigned short* __restrict__ uc2b)
{
    int idx = blockIdx.x * 256 + threadIdx.x;          // (b, tau, d)
    int b   = idx >> 20;
    int rem = idx & ((LSEQ * DI) - 1);
    int tau = rem >> 10;
    int d   = rem & (DI - 1);

    const float* xc = xz + (size_t)b * LSEQ * (2 * DI);
    float w0 = cw[d * 4 + 0], w1 = cw[d * 4 + 1], w2 = cw[d * 4 + 2], w3 = cw[d * 4 + 3];
    float bias = cb[d];
    float accf = bias, accb = bias;
    {
        int t0 = tau - 3, t1 = tau - 2, t2 = tau - 1;
        if (t0 >= 0) accf = fmaf(w0, xc[(size_t)t0 * 2048 + d], accf);
        if (t1 >= 0) accf = fmaf(w1, xc[(size_t)t1 * 2048 + d], accf);
        if (t2 >= 0) accf = fmaf(w2, xc[(size_t)t2 * 2048 + d], accf);
        accf = fmaf(w3, xc[(size_t)tau * 2048 + d], accf);
    }
    {
        int t0 = tau + 3, t1 = tau + 2, t2 = tau + 1;
        if (t0 < LSEQ) accb = fmaf(w0, xc[(size_t)t0 * 2048 + d], accb);
        if (t1 < LSEQ) accb = fmaf(w1, xc[(size_t)t1 * 2048 + d], accb);
        if (t2 < LSEQ) accb = fmaf(w2, xc[(size_t)t2 * 2048 + d], accb);
        accb = fmaf(w3, xc[(size_t)tau * 2048 + d], accb);
    }
    uc2b[((size_t)b * LSEQ + tau) * DI + d]       = f2bf(silu_f(accf));
    uc2b[((size_t)(2 + b) * LSEQ + tau) * DI + d] = f2bf(silu_f(accb));
}

// ---------------------------------------------------------------------------
// Prep: hoist all transcendentals out of the scan (see R4 notes).
// ---------------------------------------------------------------------------
__global__ __launch_bounds__(256) void prep(
    float* __restrict__ proj2, unsigned short* __restrict__ uc2b,
    const float* __restrict__ xz, const float* __restrict__ A_log,
    const float* __restrict__ Dvec, unsigned short* __restrict__ Ebuf,
    unsigned short* __restrict__ Fbuf)
{
    int idx  = blockIdx.x * 256 + threadIdx.x;     // (dirb, tau, d)
    int dirb = idx >> 20;
    int rem  = idx & ((LSEQ * DI) - 1);
    int tau  = rem >> 10;
    int d    = rem & (DI - 1);
    int b    = dirb & 1;
    int dir  = dirb >> 1;

    size_t pidx = (size_t)dirb * LSEQ * NPROJ + (size_t)tau * NPROJ + d;
    float delta = sp_f(proj2[pidx]);
    float Ad    = -expf(A_log[d]);
    proj2[pidx] = expf(delta * Ad);

    size_t uidx = ((size_t)dirb * LSEQ + tau) * DI + d;
    float u = bf2f(uc2b[uidx]);
    uc2b[uidx] = f2bf(delta * u);

    float z = xz[((size_t)b * LSEQ + tau) * (2 * DI) + DI + d];
    float F = 0.5f * silu_f(z);
    Ebuf[uidx] = f2bf(F * Dvec[d] * u);
    if (dir == 0) Fbuf[((size_t)b * LSEQ + tau) * DI + d] = f2bf(F);
}

// ---------------------------------------------------------------------------
// Pass A: local chunk scans, 4 threads/channel (16 states each).
// ---------------------------------------------------------------------------
__global__ __launch_bounds__(256) void passA(
    const float* __restrict__ proj2, const unsigned short* __restrict__ du2b,
    float* __restrict__ sEnd, float* __restrict__ Pbuf)
{
    const int dl   = threadIdx.x >> 2;
    const int nq   = threadIdx.x & 3;
    const int d    = blockIdx.x * 64 + dl;
    const int c    = blockIdx.y;
    const int dirb = blockIdx.z;
    const int dir  = dirb >> 1;

    __shared__ float Bsh[TC][NS];
    const float* projbase = proj2 + (size_t)dirb * LSEQ * NPROJ;
    const unsigned short* ducb = du2b + (size_t)dirb * LSEQ * DI;

    for (int i = threadIdx.x * 4; i < TC * NS; i += 1024) {
        int tl = i >> 6, n = i & 63;
        int t = c * TC + tl;
        int tau = dir ? (LSEQ - 1 - t) : t;
        *(float4*)&Bsh[tl][n] = *(const float4*)&projbase[(size_t)tau * NPROJ + DI + n];
    }
    __syncthreads();

    float s[16];
#pragma unroll
    for (int i = 0; i < 16; i++) s[i] = 0.f;
    float P = 1.f;

    int tau0 = dir ? (LSEQ - 1 - c * TC) : (c * TC);
    long stp = dir ? -1 : 1;
    const float* pDA = projbase + (size_t)tau0 * NPROJ + d;
    const unsigned short* pDU = ducb + (size_t)tau0 * DI + d;

    for (int tl = 0; tl < TC; tl++) {
        float dA = *pDA;
        float du = bf2f(*pDU);
        pDA += stp * NPROJ; pDU += stp * DI;
        P *= dA;
        const float4* brow = (const float4*)&Bsh[tl][nq * 16];
#pragma unroll
        for (int q = 0; q < 4; q++) {
            float4 bv = brow[q];
            s[4*q+0] = fmaf(du, bv.x, dA * s[4*q+0]);
            s[4*q+1] = fmaf(du, bv.y, dA * s[4*q+1]);
            s[4*q+2] = fmaf(du, bv.z, dA * s[4*q+2]);
            s[4*q+3] = fmaf(du, bv.w, dA * s[4*q+3]);
        }
    }
    size_t base = (((size_t)dirb * NC + c) * DI + d) * NS + nq * 16;
#pragma unroll
    for (int q = 0; q < 4; q++)
        *(float4*)&sEnd[base + q * 4] = make_float4(s[4*q], s[4*q+1], s[4*q+2], s[4*q+3]);
    if (nq == 0) Pbuf[((size_t)dirb * NC + c) * DI + d] = P;
}

// ---------------------------------------------------------------------------
// Pass B: sequential combine across chunks (in place: sEnd -> sInit).
// ---------------------------------------------------------------------------
__global__ __launch_bounds__(256) void passB(
    float* __restrict__ sEnd, const float* __restrict__ Pbuf)
{
    const int fl   = blockIdx.x * 256 + threadIdx.x;   // d*64 + n
    const int dirb = blockIdx.y;
    const int d    = fl >> 6;
    float run = 0.f;
    for (int c = 0; c < NC; c++) {
        size_t idx = ((size_t)(dirb * NC + c)) * (DI * NS) + fl;
        float tmp = sEnd[idx];
        sEnd[idx] = run;
        float P = Pbuf[((size_t)dirb * NC + c) * DI + d];
        run = fmaf(P, run, tmp);
    }
}

// ---------------------------------------------------------------------------
// Pass C: seeded local scan; epilogue g = fma(F, y_scan, E) -> bf16 ygb.
// ---------------------------------------------------------------------------
__global__ __launch_bounds__(256) void passC(
    const float* __restrict__ proj2, const unsigned short* __restrict__ du2b,
    const unsigned short* __restrict__ Ebuf, const unsigned short* __restrict__ Fbuf,
    const float* __restrict__ sInit, unsigned short* __restrict__ ygb)
{
    const int dl   = threadIdx.x >> 2;
    const int nq   = threadIdx.x & 3;
    const int d0   = blockIdx.x * 64;
    const int d    = d0 + dl;
    const int c    = blockIdx.y;
    const int dirb = blockIdx.z;
    const int dir  = dirb >> 1;
    const int b    = dirb & 1;

    __shared__ float Bsh[TC][NS];
    __shared__ float Csh[TC][NS];
    __shared__ unsigned short gsh[TC][64];
    const float* projbase = proj2 + (size_t)dirb * LSEQ * NPROJ;
    const unsigned short* ducb = du2b + (size_t)dirb * LSEQ * DI;

    for (int i = threadIdx.x * 4; i < TC * NS; i += 1024) {
        int tl = i >> 6, n = i & 63;
        int t = c * TC + tl;
        int tau = dir ? (LSEQ - 1 - t) : t;
        *(float4*)&Bsh[tl][n] = *(const float4*)&projbase[(size_t)tau * NPROJ + DI + n];
        *(float4*)&Csh[tl][n] = *(const float4*)&projbase[(size_t)tau * NPROJ + DI + NS + n];
    }
    __syncthreads();

    float s[16];
    size_t sbase = (((size_t)dirb * NC + c) * DI + d) * NS + nq * 16;
#pragma unroll
    for (int q = 0; q < 4; q++) {
        float4 v = *(const float4*)&sInit[sbase + q * 4];
        s[4*q] = v.x; s[4*q+1] = v.y; s[4*q+2] = v.z; s[4*q+3] = v.w;
    }

    int tau0 = dir ? (LSEQ - 1 - c * TC) : (c * TC);
    long stp = dir ? -1 : 1;
    const float* pDA = projbase + (size_t)tau0 * NPROJ + d;
    const unsigned short* pDU = ducb + (size_t)tau0 * DI + d;
    const unsigned short* pE  = Ebuf + ((size_t)dirb * LSEQ + tau0) * DI + d;
    const unsigned short* pF  = Fbuf + ((size_t)b * LSEQ + tau0) * DI + d;

    for (int tl = 0; tl < TC; tl++) {
        float dA = *pDA;
        float du = bf2f(*pDU);
        float E  = bf2f(*pE);
        float F  = bf2f(*pF);
        pDA += stp * NPROJ; pDU += stp * DI; pE += stp * DI; pF += stp * DI;
        float yp = 0.f;
        const float4* brow = (const float4*)&Bsh[tl][nq * 16];
        const float4* crow = (const float4*)&Csh[tl][nq * 16];
#pragma unroll
        for (int q = 0; q < 4; q++) {
            float4 bv = brow[q];
            float4 cv = crow[q];
            float s0 = fmaf(du, bv.x, dA * s[4*q+0]); s[4*q+0] = s0; yp = fmaf(cv.x, s0, yp);
            float s1 = fmaf(du, bv.y, dA * s[4*q+1]); s[4*q+1] = s1; yp = fmaf(cv.y, s1, yp);
            float s2 = fmaf(du, bv.z, dA * s[4*q+2]); s[4*q+2] = s2; yp = fmaf(cv.z, s2, yp);
            float s3 = fmaf(du, bv.w, dA * s[4*q+3]); s[4*q+3] = s3; yp = fmaf(cv.w, s3, yp);
        }
        yp += __shfl_xor(yp, 1);
        yp += __shfl_xor(yp, 2);
        if (nq == 0) gsh[tl][dl] = f2bf(fmaf(F, yp, E));
    }
    __syncthreads();
    // coalesced write-out of the chunk's 64x64 g tile
    for (int i = threadIdx.x * 4; i < TC * 64; i += 1024) {
        int tl = i >> 6, col = i & 63;
        int t = c * TC + tl;
        int tau = dir ? (LSEQ - 1 - t) : t;
        *(ushort4*)&ygb[((size_t)dirb * LSEQ + tau) * DI + d0 + col] = *(const ushort4*)&gsh[tl][col];
    }
}

// ---------------------------------------------------------------------------
extern "C" void kernel_launch(void* const* d_in, const int* in_sizes, int n_in,
                              void* d_out, int out_size, void* d_ws, size_t ws_size,
                              hipStream_t stream)
{
    const float* x      = (const float*)d_in[0];
    const float* W_in   = (const float*)d_in[1];
    const float* conv_w = (const float*)d_in[2];
    const float* conv_b = (const float*)d_in[3];
    const float* W_xprj = (const float*)d_in[4];
    const float* A_log  = (const float*)d_in[5];
    const float* Dvec   = (const float*)d_in[6];
    const float* W_out  = (const float*)d_in[7];
    float* out = (float*)d_out;

    // workspace (~66.3 MB; aliased regions are dead-before-overwrite)
    float* ws    = (float*)d_ws;
    float* proj2 = ws;                              // 4,718,592 f  [4][L][NPROJ] (delta-col -> dA after prep)
    unsigned short* uc2b = (unsigned short*)(proj2 + 4718592); // 4,194,304 sh (u -> du after prep)
    unsigned short* Ebuf = uc2b + 4194304;          // 4,194,304 sh [4][L][DI]
    unsigned short* Fbuf = Ebuf + 4194304;          // 2,097,152 sh [B][L][DI]
    float* xz    = (float*)(Fbuf + 2097152);        // 4,194,304 f  [B][L][2*DI]
    float* sEnd  = xz;                              // alias: xz dead after prep; sEnd written in passA
    float* Pbuf  = xz + 4194304;                    // 65,536 f
    unsigned short* ygb  = (unsigned short*)(Pbuf + 65536);    // 4,194,304 sh [4][L][DI]
    unsigned short* wob  = ygb + 4194304;           // 524,288 sh
    // aliases consumed before their host region is written:
    unsigned short* xb   = Ebuf;                    // dead after gemm1; Ebuf written in prep
    unsigned short* winb = Ebuf + 1048576;
    unsigned short* wxb  = ygb;                     // dead after gemm2; ygb written in passC
    float* gpart = proj2;                           // split-K partials [4][2048*512]; proj2 dead after passC

    // 1) all bf16 casts in one launch
    castall<<<3712, 256, 0, stream>>>(x, W_in, W_xprj, W_out, xb, winb, wxb, wob);

    // 2) xz = x @ W_in^T (M=2048, N=2048, K=512) — 1024 blocks
    gemm64<<<dim3(32, 32), 256, 0, stream>>>(xb, nullptr, winb, xz, B_ * LSEQ, 2 * DI, DM, 1);

    // 3) conv both directions + SiLU -> bf16 u
    convk<<<(B_ * LSEQ * DI) / 256, 256, 0, stream>>>(xz, conv_w, conv_b, uc2b);

    // 4) proj2 = uc2 @ W_xproj^T (M=4096, N=1152, K=1024) — 1152 blocks
    gemm64<<<dim3(18, 64), 256, 0, stream>>>(uc2b, nullptr, wxb, proj2, 4 * LSEQ, NPROJ, DI, 1);

    // 5) prep: delta->dA (in place), u->du (in place), E/F buffers
    prep<<<(4 * LSEQ * DI) / 256, 256, 0, stream>>>(proj2, uc2b, xz, A_log, Dvec, Ebuf, Fbuf);

    // 6) pass A: local chunk scans
    passA<<<dim3(16, NC, 4), 256, 0, stream>>>(proj2, uc2b, sEnd, Pbuf);

    // 7) pass B: chunk-state combine
    passB<<<dim3(256, 4), 256, 0, stream>>>(sEnd, Pbuf);

    // 8) pass C: seeded scan -> g (bf16 per dirb)
    passC<<<dim3(16, NC, 4), 256, 0, stream>>>(proj2, uc2b, Ebuf, Fbuf, sEnd, ygb);

    // 9) out = (yf + yb) @ W_out^T (M=2048, N=512, K=1024) — split-K=4, 1024 blocks
    gemm64<<<dim3(8, 32, 4), 256, 0, stream>>>(ygb, ygb + (size_t)2 * LSEQ * DI, wob, gpart, B_ * LSEQ, DM, DI, 4);
    reduce4<<<1024, 256, 0, stream>>>(gpart, out, B_ * LSEQ * DM);
}

// Round 6
// 208.581 us; speedup vs baseline: 2.6005x; 1.1165x over previous
//
#include <hip/hip_runtime.h>
#include <math.h>

#define B_    2
#define LSEQ  1024
#define DM    512
#define DI    1024
#define NS    64
#define NPROJ (DI + 2*NS)   // 1152
#define TC    64
#define NC    (LSEQ/TC)     // 16

typedef __bf16 bf16x8 __attribute__((ext_vector_type(8)));
typedef float  f32x4  __attribute__((ext_vector_type(4)));

__device__ __forceinline__ float sp_f(float x)   { return fmaxf(x, 0.f) + log1pf(expf(-fabsf(x))); }
__device__ __forceinline__ float silu_f(float x) { return x / (1.f + expf(-x)); }
__device__ __forceinline__ unsigned short f2bf(float f) {
    unsigned int u = __float_as_uint(f);
    u += 0x7FFF + ((u >> 16) & 1);          // RNE
    return (unsigned short)(u >> 16);
}
__device__ __forceinline__ float bf2f(unsigned short h) {
    return __uint_as_float(((unsigned int)h) << 16);
}
__device__ __forceinline__ uint4 bfadd8(uint4 a, uint4 b) {
    uint4 r;
    unsigned* pa = (unsigned*)&a; unsigned* pb = (unsigned*)&b; unsigned* pr = (unsigned*)&r;
#pragma unroll
    for (int i = 0; i < 4; i++) {
        unsigned wa = pa[i], wb = pb[i];
        float lo = __uint_as_float(wa << 16) + __uint_as_float(wb << 16);
        float hi = __uint_as_float(wa & 0xffff0000u) + __uint_as_float(wb & 0xffff0000u);
        pr[i] = ((unsigned)f2bf(lo)) | (((unsigned)f2bf(hi)) << 16);
    }
    return r;
}

// ---------------------------------------------------------------------------
// All 4 f32->bf16 casts in one launch (3712 blocks exactly).
// ---------------------------------------------------------------------------
__global__ __launch_bounds__(256) void castall(
    const float* __restrict__ x, const float* __restrict__ W_in,
    const float* __restrict__ W_xproj, const float* __restrict__ W_out,
    unsigned short* __restrict__ xb, unsigned short* __restrict__ winb,
    unsigned short* __restrict__ wxb, unsigned short* __restrict__ wob)
{
    int i = (blockIdx.x * 256 + threadIdx.x) * 4;
    const float* s; unsigned short* dst; int off;
    if (i < 1048576)      { s = x;       dst = xb;   off = i; }
    else if (i < 2097152) { s = W_in;    dst = winb; off = i - 1048576; }
    else if (i < 3276800) { s = W_xproj; dst = wxb;  off = i - 2097152; }
    else                  { s = W_out;   dst = wob;  off = i - 3276800; }
    float4 v = *(const float4*)(s + off);
    ushort4 o;
    o.x = f2bf(v.x); o.y = f2bf(v.y); o.z = f2bf(v.z); o.w = f2bf(v.w);
    *(ushort4*)(dst + off) = o;
}

// ---------------------------------------------------------------------------
// bf16 MFMA GEMM, 64x64 tile, BK=64, 4 waves (2x2), wave = 32x32.
// C[kz] = (A [+A2]) * B^T ; ks = K-split; outbf: bf16 output.
// ---------------------------------------------------------------------------
__global__ __launch_bounds__(256) void gemm64(
    const unsigned short* __restrict__ A, const unsigned short* __restrict__ A2,
    const unsigned short* __restrict__ B,
    float* __restrict__ C, int M, int N, int K, int ks, int outbf)
{
    __shared__ short As[64 * 64];
    __shared__ short Bs[64 * 64];
    const int tid  = threadIdx.x;
    const int lane = tid & 63, wid = tid >> 6;
    const int bm = blockIdx.y * 64, bn = blockIdx.x * 64;
    const int wm = (wid >> 1) * 32, wn = (wid & 1) * 32;
    const int fr = lane & 15, fk = (lane >> 4) * 8;
    const int Kc = K / ks;
    const int k0beg = blockIdx.z * Kc;
    const int k0end = k0beg + Kc;
    float* Cz = C + (size_t)blockIdx.z * M * N;
    unsigned short* Czb = (unsigned short*)C + (size_t)blockIdx.z * M * N;

    f32x4 acc[2][2];
#pragma unroll
    for (int i = 0; i < 2; i++)
#pragma unroll
        for (int j = 0; j < 2; j++) acc[i][j] = (f32x4)0.f;

    uint4 ra[2], rb[2];
#pragma unroll
    for (int r = 0; r < 2; r++) {
        int o = tid * 16 + r * 4096;
        int row = o >> 7, colb = o & 127;
        ra[r] = *(const uint4*)((const char*)A + ((size_t)(bm + row) * K + k0beg) * 2 + colb);
        if (A2) ra[r] = bfadd8(ra[r], *(const uint4*)((const char*)A2 + ((size_t)(bm + row) * K + k0beg) * 2 + colb));
        rb[r] = *(const uint4*)((const char*)B + ((size_t)(bn + row) * K + k0beg) * 2 + colb);
    }

    for (int k0 = k0beg; k0 < k0end; k0 += 64) {
        __syncthreads();
#pragma unroll
        for (int r = 0; r < 2; r++) {
            *(uint4*)((char*)As + tid * 16 + r * 4096) = ra[r];
            *(uint4*)((char*)Bs + tid * 16 + r * 4096) = rb[r];
        }
        __syncthreads();
        if (k0 + 64 < k0end) {
#pragma unroll
            for (int r = 0; r < 2; r++) {
                int o = tid * 16 + r * 4096;
                int row = o >> 7, colb = o & 127;
                ra[r] = *(const uint4*)((const char*)A + ((size_t)(bm + row) * K + k0 + 64) * 2 + colb);
                if (A2) ra[r] = bfadd8(ra[r], *(const uint4*)((const char*)A2 + ((size_t)(bm + row) * K + k0 + 64) * 2 + colb));
                rb[r] = *(const uint4*)((const char*)B + ((size_t)(bn + row) * K + k0 + 64) * 2 + colb);
            }
        }
#pragma unroll
        for (int kk = 0; kk < 2; kk++) {
            bf16x8 af[2], bfr[2];
#pragma unroll
            for (int i = 0; i < 2; i++)
                af[i] = *reinterpret_cast<const bf16x8*>(&As[(wm + i * 16 + fr) * 64 + kk * 32 + fk]);
#pragma unroll
            for (int j = 0; j < 2; j++)
                bfr[j] = *reinterpret_cast<const bf16x8*>(&Bs[(wn + j * 16 + fr) * 64 + kk * 32 + fk]);
#pragma unroll
            for (int i = 0; i < 2; i++)
#pragma unroll
                for (int j = 0; j < 2; j++)
                    acc[i][j] = __builtin_amdgcn_mfma_f32_16x16x32_bf16(af[i], bfr[j], acc[i][j], 0, 0, 0);
        }
    }

    const int crow = (lane >> 4) * 4;
#pragma unroll
    for (int i = 0; i < 2; i++)
#pragma unroll
        for (int j = 0; j < 2; j++)
#pragma unroll
            for (int r = 0; r < 4; r++) {
                size_t idx = (size_t)(bm + wm + i * 16 + crow + r) * N + (bn + wn + j * 16 + fr);
                if (outbf) Czb[idx] = f2bf(acc[i][j][r]);
                else       Cz[idx]  = acc[i][j][r];
            }
}

// ---------------------------------------------------------------------------
// Split-K reduce: out = p0+p1+p2+p3
// ---------------------------------------------------------------------------
__global__ __launch_bounds__(256) void reduce4(
    const float* __restrict__ p, float* __restrict__ out, int n)
{
    int i = (blockIdx.x * 256 + threadIdx.x) * 4;
    if (i >= n) return;
    float4 a = *(const float4*)(p + i);
    float4 b = *(const float4*)(p + n + i);
    float4 c = *(const float4*)(p + 2 * n + i);
    float4 d = *(const float4*)(p + 3 * n + i);
    float4 o;
    o.x = (a.x + b.x) + (c.x + d.x);
    o.y = (a.y + b.y) + (c.y + d.y);
    o.z = (a.z + b.z) + (c.z + d.z);
    o.w = (a.w + b.w) + (c.w + d.w);
    *(float4*)(out + i) = o;
}

// ---------------------------------------------------------------------------
// Depthwise causal conv (fwd) + anti-causal (bwd) + SiLU -> bf16 u. xzb bf16.
// ---------------------------------------------------------------------------
__global__ __launch_bounds__(256) void convk(
    const unsigned short* __restrict__ xzb, const float* __restrict__ cw,
    const float* __restrict__ cb, unsigned short* __restrict__ uc2b)
{
    int idx = blockIdx.x * 256 + threadIdx.x;
    int b   = idx >> 20;
    int rem = idx & ((LSEQ * DI) - 1);
    int tau = rem >> 10;
    int d   = rem & (DI - 1);

    const unsigned short* xc = xzb + (size_t)b * LSEQ * (2 * DI);
    float w0 = cw[d * 4 + 0], w1 = cw[d * 4 + 1], w2 = cw[d * 4 + 2], w3 = cw[d * 4 + 3];
    float bias = cb[d];
    float accf = bias, accb = bias;
    {
        int t0 = tau - 3, t1 = tau - 2, t2 = tau - 1;
        if (t0 >= 0) accf = fmaf(w0, bf2f(xc[(size_t)t0 * 2048 + d]), accf);
        if (t1 >= 0) accf = fmaf(w1, bf2f(xc[(size_t)t1 * 2048 + d]), accf);
        if (t2 >= 0) accf = fmaf(w2, bf2f(xc[(size_t)t2 * 2048 + d]), accf);
        accf = fmaf(w3, bf2f(xc[(size_t)tau * 2048 + d]), accf);
    }
    {
        int t0 = tau + 3, t1 = tau + 2, t2 = tau + 1;
        if (t0 < LSEQ) accb = fmaf(w0, bf2f(xc[(size_t)t0 * 2048 + d]), accb);
        if (t1 < LSEQ) accb = fmaf(w1, bf2f(xc[(size_t)t1 * 2048 + d]), accb);
        if (t2 < LSEQ) accb = fmaf(w2, bf2f(xc[(size_t)t2 * 2048 + d]), accb);
        accb = fmaf(w3, bf2f(xc[(size_t)tau * 2048 + d]), accb);
    }
    uc2b[((size_t)b * LSEQ + tau) * DI + d]       = f2bf(silu_f(accf));
    uc2b[((size_t)(2 + b) * LSEQ + tau) * DI + d] = f2bf(silu_f(accb));
}

// ---------------------------------------------------------------------------
// Prep: transcendental hoist + operand packing (see R6 notes).
// ---------------------------------------------------------------------------
__global__ __launch_bounds__(256) void prep(
    const float* __restrict__ proj2, unsigned short* __restrict__ uc2b,
    const unsigned short* __restrict__ xzb, const float* __restrict__ A_log,
    const float* __restrict__ Dvec, float* __restrict__ dAbuf,
    unsigned short* __restrict__ ygb, unsigned short* __restrict__ Fbuf,
    unsigned short* __restrict__ Bbf, unsigned short* __restrict__ Cbf)
{
    int idx  = blockIdx.x * 256 + threadIdx.x;     // (dirb, tau, d)
    int dirb = idx >> 20;
    int rem  = idx & ((LSEQ * DI) - 1);
    int tau  = rem >> 10;
    int d    = rem & (DI - 1);
    int b    = dirb & 1;
    int dir  = dirb >> 1;

    const float* prow = proj2 + (size_t)dirb * LSEQ * NPROJ + (size_t)tau * NPROJ;
    float delta = sp_f(prow[d]);
    float Ad    = -expf(A_log[d]);
    size_t uidx = ((size_t)dirb * LSEQ + tau) * DI + d;
    dAbuf[uidx] = expf(delta * Ad);

    float u = bf2f(uc2b[uidx]);
    uc2b[uidx] = f2bf(delta * u);
    ygb[uidx]  = f2bf(Dvec[d] * u);

    if (dir == 0) {
        float z = bf2f(xzb[((size_t)b * LSEQ + tau) * (2 * DI) + DI + d]);
        Fbuf[((size_t)b * LSEQ + tau) * DI + d] = f2bf(0.5f * silu_f(z));
    }
    if (d < 2 * NS) {
        unsigned short v = f2bf(prow[DI + d]);
        if (d < NS) Bbf[((size_t)dirb * LSEQ + tau) * NS + d]        = v;
        else        Cbf[((size_t)dirb * LSEQ + tau) * NS + (d - NS)] = v;
    }
}

// ---------------------------------------------------------------------------
// Pass A: local chunk scan from zero; emits yloc (+Du, RMW into ygb),
// g running product (bf16), chunk-end states (bf16), P.
// ---------------------------------------------------------------------------
__global__ __launch_bounds__(256) void passA(
    const float* __restrict__ dAbuf, const unsigned short* __restrict__ du2b,
    const unsigned short* __restrict__ Bbf, const unsigned short* __restrict__ Cbf,
    unsigned short* __restrict__ ygb, unsigned short* __restrict__ gbuf,
    unsigned short* __restrict__ sEnd, float* __restrict__ Pbuf)
{
    const int dl   = threadIdx.x >> 2;
    const int nq   = threadIdx.x & 3;
    const int d0   = blockIdx.x * 64;
    const int d    = d0 + dl;
    const int c    = blockIdx.y;
    const int dirb = blockIdx.z;
    const int dir  = dirb >> 1;

    __shared__ float Bsh[TC][NS];
    __shared__ float Csh[TC][NS];
    __shared__ unsigned short gshY[TC][64];
    __shared__ unsigned short gshG[TC][64];

    for (int i = threadIdx.x * 4; i < TC * NS; i += 1024) {
        int tl = i >> 6, n = i & 63;
        int tau = dir ? (LSEQ - 1 - (c * TC + tl)) : (c * TC + tl);
        ushort4 vb = *(const ushort4*)&Bbf[((size_t)dirb * LSEQ + tau) * NS + n];
        ushort4 vc = *(const ushort4*)&Cbf[((size_t)dirb * LSEQ + tau) * NS + n];
        Bsh[tl][n+0] = bf2f(vb.x); Bsh[tl][n+1] = bf2f(vb.y);
        Bsh[tl][n+2] = bf2f(vb.z); Bsh[tl][n+3] = bf2f(vb.w);
        Csh[tl][n+0] = bf2f(vc.x); Csh[tl][n+1] = bf2f(vc.y);
        Csh[tl][n+2] = bf2f(vc.z); Csh[tl][n+3] = bf2f(vc.w);
    }
    __syncthreads();

    float s[16];
#pragma unroll
    for (int i = 0; i < 16; i++) s[i] = 0.f;
    float g_run = 1.f;

    int tau0 = dir ? (LSEQ - 1 - c * TC) : (c * TC);
    long stp = (dir ? -1L : 1L) * (long)DI;
    const float* pDA = dAbuf + ((size_t)dirb * LSEQ + tau0) * DI + d;
    const unsigned short* pDU = du2b + ((size_t)dirb * LSEQ + tau0) * DI + d;
    const unsigned short* pY  = ygb  + ((size_t)dirb * LSEQ + tau0) * DI + d;

    float dA = *pDA, du = bf2f(*pDU), Du = bf2f(*pY);
    for (int tl = 0; tl < TC; tl++) {
        float dA_c = dA, du_c = du, Du_c = Du;
        if (tl + 1 < TC) {                        // 1-deep register prefetch
            pDA += stp; pDU += stp; pY += stp;
            dA = *pDA; du = bf2f(*pDU); Du = bf2f(*pY);
        }
        g_run *= dA_c;
        float ydot = 0.f;
        const float4* brow = (const float4*)&Bsh[tl][nq * 16];
        const float4* crow = (const float4*)&Csh[tl][nq * 16];
#pragma unroll
        for (int q = 0; q < 4; q++) {
            float4 bv = brow[q];
            float4 cv = crow[q];
            float s0 = fmaf(du_c, bv.x, dA_c * s[4*q+0]); s[4*q+0] = s0; ydot = fmaf(cv.x, s0, ydot);
            float s1 = fmaf(du_c, bv.y, dA_c * s[4*q+1]); s[4*q+1] = s1; ydot = fmaf(cv.y, s1, ydot);
            float s2 = fmaf(du_c, bv.z, dA_c * s[4*q+2]); s[4*q+2] = s2; ydot = fmaf(cv.z, s2, ydot);
            float s3 = fmaf(du_c, bv.w, dA_c * s[4*q+3]); s[4*q+3] = s3; ydot = fmaf(cv.w, s3, ydot);
        }
        ydot += __shfl_xor(ydot, 1);
        ydot += __shfl_xor(ydot, 2);
        if (nq == 0) {
            gshY[tl][dl] = f2bf(Du_c + ydot);
            gshG[tl][dl] = f2bf(g_run);
        }
    }
    __syncthreads();

    size_t base = (((size_t)dirb * NC + c) * DI + d) * NS + nq * 16;
#pragma unroll
    for (int q = 0; q < 4; q++) {
        ushort4 v;
        v.x = f2bf(s[4*q+0]); v.y = f2bf(s[4*q+1]);
        v.z = f2bf(s[4*q+2]); v.w = f2bf(s[4*q+3]);
        *(ushort4*)&sEnd[base + q * 4] = v;
    }
    if (nq == 0) Pbuf[((size_t)dirb * NC + c) * DI + d] = g_run;

    for (int i = threadIdx.x * 4; i < TC * 64; i += 1024) {
        int tl = i >> 6, col = i & 63;
        int tau = dir ? (LSEQ - 1 - (c * TC + tl)) : (c * TC + tl);
        *(ushort4*)&ygb[((size_t)dirb * LSEQ + tau) * DI + d0 + col]  = *(const ushort4*)&gshY[tl][col];
        *(ushort4*)&gbuf[((size_t)dirb * LSEQ + tau) * DI + d0 + col] = *(const ushort4*)&gshG[tl][col];
    }
}

// ---------------------------------------------------------------------------
// Pass B: combine chunk states; sEnd bf16 in, sInitB bf16 out (f32 running).
// ---------------------------------------------------------------------------
__global__ __launch_bounds__(256) void passB(
    const unsigned short* __restrict__ sEnd, const float* __restrict__ Pbuf,
    unsigned short* __restrict__ sInitB)
{
    const int fl   = blockIdx.x * 256 + threadIdx.x;   // d*64 + n
    const int dirb = blockIdx.y;
    const int d    = fl >> 6;
    float run = 0.f;
    for (int c = 0; c < NC; c++) {
        size_t idx = ((size_t)(dirb * NC + c)) * (DI * NS) + fl;
        float tmp = bf2f(sEnd[idx]);
        sInitB[idx] = f2bf(run);
        float P = Pbuf[((size_t)dirb * NC + c) * DI + d];
        run = fmaf(P, run, tmp);
    }
}

// ---------------------------------------------------------------------------
// corrK: per (dirb, chunk, 128-d group): corr = C_chunk[64,64] @ s_init[d,n]^T
// via MFMA, then out = F * (yloc + g*corr) -> ygb (in place).
// ---------------------------------------------------------------------------
__global__ __launch_bounds__(256) void corrK(
    const unsigned short* __restrict__ Cbf, const unsigned short* __restrict__ sInitB,
    const unsigned short* __restrict__ gbuf, const unsigned short* __restrict__ Fbuf,
    unsigned short* __restrict__ ygb)
{
    const int tid  = threadIdx.x;
    const int lane = tid & 63, wid = tid >> 6;
    const int d0   = blockIdx.x * 128;
    const int c    = blockIdx.y;
    const int dirb = blockIdx.z;
    const int dir  = dirb >> 1;
    const int b    = dirb & 1;
    const int fr = lane & 15, fk = (lane >> 4) * 8;
    const int wm = (wid >> 1) * 32, wn = (wid & 1) * 64;

    __shared__ short Cs[64 * 64];      // [t][n] bf16
    __shared__ short Ss[128 * 64];     // [d][n] bf16
    __shared__ float corrS[64 * 128];  // [t][d]

    for (int i = tid * 4; i < 64 * 64; i += 1024) {
        int tl = i >> 6, n = i & 63;
        int tau = dir ? (LSEQ - 1 - (c * TC + tl)) : (c * TC + tl);
        *(ushort4*)&Cs[tl * 64 + n] = *(const ushort4*)&Cbf[((size_t)dirb * LSEQ + tau) * NS + n];
    }
    for (int i = tid * 4; i < 128 * 64; i += 1024) {
        int r = i >> 6, n = i & 63;
        *(ushort4*)&Ss[r * 64 + n] =
            *(const ushort4*)&sInitB[(((size_t)dirb * NC + c) * DI + d0 + r) * NS + n];
    }
    __syncthreads();

    f32x4 acc[2][4];
#pragma unroll
    for (int i = 0; i < 2; i++)
#pragma unroll
        for (int j = 0; j < 4; j++) acc[i][j] = (f32x4)0.f;

#pragma unroll
    for (int kk = 0; kk < 2; kk++) {
        bf16x8 af[2], bfr[4];
#pragma unroll
        for (int i = 0; i < 2; i++)
            af[i] = *reinterpret_cast<const bf16x8*>(&Cs[(wm + i * 16 + fr) * 64 + kk * 32 + fk]);
#pragma unroll
        for (int j = 0; j < 4; j++)
            bfr[j] = *reinterpret_cast<const bf16x8*>(&Ss[(wn + j * 16 + fr) * 64 + kk * 32 + fk]);
#pragma unroll
        for (int i = 0; i < 2; i++)
#pragma unroll
            for (int j = 0; j < 4; j++)
                acc[i][j] = __builtin_amdgcn_mfma_f32_16x16x32_bf16(af[i], bfr[j], acc[i][j], 0, 0, 0);
    }

    const int crow = (lane >> 4) * 4;
#pragma unroll
    for (int i = 0; i < 2; i++)
#pragma unroll
        for (int j = 0; j < 4; j++)
#pragma unroll
            for (int r = 0; r < 4; r++)
                corrS[(wm + i * 16 + crow + r) * 128 + (wn + j * 16 + fr)] = acc[i][j][r];
    __syncthreads();

    // epilogue: out = F * (yloc + g*corr), coalesced rows of 128 d
    for (int i = tid * 4; i < 64 * 128; i += 1024) {
        int tl = i >> 7, col = i & 127;
        int tau = dir ? (LSEQ - 1 - (c * TC + tl)) : (c * TC + tl);
        size_t gi = ((size_t)dirb * LSEQ + tau) * DI + d0 + col;
        size_t fi = ((size_t)b    * LSEQ + tau) * DI + d0 + col;
        ushort4 g4 = *(const ushort4*)&gbuf[gi];
        ushort4 y4 = *(const ushort4*)&ygb[gi];
        ushort4 F4 = *(const ushort4*)&Fbuf[fi];
        const float* cr = &corrS[tl * 128 + col];
        ushort4 o;
        o.x = f2bf(bf2f(F4.x) * fmaf(bf2f(g4.x), cr[0], bf2f(y4.x)));
        o.y = f2bf(bf2f(F4.y) * fmaf(bf2f(g4.y), cr[1], bf2f(y4.y)));
        o.z = f2bf(bf2f(F4.z) * fmaf(bf2f(g4.z), cr[2], bf2f(y4.z)));
        o.w = f2bf(bf2f(F4.w) * fmaf(bf2f(g4.w), cr[3], bf2f(y4.w)));
        *(ushort4*)&ygb[gi] = o;
    }
}

// ---------------------------------------------------------------------------
extern "C" void kernel_launch(void* const* d_in, const int* in_sizes, int n_in,
                              void* d_out, int out_size, void* d_ws, size_t ws_size,
                              hipStream_t stream)
{
    const float* x      = (const float*)d_in[0];
    const float* W_in   = (const float*)d_in[1];
    const float* conv_w = (const float*)d_in[2];
    const float* conv_b = (const float*)d_in[3];
    const float* W_xprj = (const float*)d_in[4];
    const float* A_log  = (const float*)d_in[5];
    const float* Dvec   = (const float*)d_in[6];
    const float* W_out  = (const float*)d_in[7];
    float* out = (float*)d_out;

    // workspace layout, ~67.4 MB (all aliases dead-before-overwrite):
    float* ws = (float*)d_ws;
    float*          proj2 = ws;                                   // 4,718,592 f
    unsigned short* uc2b  = (unsigned short*)(ws + 4718592);      // 4,194,304 sh
    unsigned short* xzb   = uc2b + 4194304;                       // 4,194,304 sh
    float*          dAbuf = ws + 8912896;                         // 4,194,304 f
    unsigned short* Fbuf  = (unsigned short*)(ws + 13107200);     // 2,097,152 sh
    unsigned short* ygb   = Fbuf + 2097152;                       // 4,194,304 sh
    unsigned short* Bbf   = ygb + 4194304;                        //   262,144 sh
    unsigned short* Cbf   = Bbf + 262144;                         //   262,144 sh
    unsigned short* wob   = Cbf + 262144;                         //   524,288 sh
    float*          Pbuf  = (float*)(wob + 524288);               //    65,536 f
    // aliases:
    unsigned short* sInitB = (unsigned short*)proj2;              // passB out (proj2 dead after prep)
    unsigned short* gbuf   = (unsigned short*)(proj2 + 2097152);  // passA out
    unsigned short* sEnd   = xzb;                                 // passA out (xzb dead after prep)
    unsigned short* xb     = (unsigned short*)dAbuf;              // cast, dead after gemm1
    unsigned short* winb   = xb + 1048576;                        // cast, dead after gemm1
    unsigned short* wxb    = ygb;                                 // cast, dead after gemm2
    float*          gpart  = dAbuf;                               // split-K partials (dAbuf dead after passA)

    // 1) bf16 casts
    castall<<<3712, 256, 0, stream>>>(x, W_in, W_xprj, W_out, xb, winb, wxb, wob);

    // 2) xz = x @ W_in^T -> bf16 (M=2048, N=2048, K=512)
    gemm64<<<dim3(32, 32), 256, 0, stream>>>(xb, nullptr, winb, (float*)xzb, B_ * LSEQ, 2 * DI, DM, 1, 1);

    // 3) conv both dirs + SiLU -> bf16 u
    convk<<<(B_ * LSEQ * DI) / 256, 256, 0, stream>>>(xzb, conv_w, conv_b, uc2b);

    // 4) proj2 = uc2 @ W_xproj^T -> f32 (M=4096, N=1152, K=1024)
    gemm64<<<dim3(18, 64), 256, 0, stream>>>(uc2b, nullptr, wxb, proj2, 4 * LSEQ, NPROJ, DI, 1, 0);

    // 5) prep: dA/du/Du/F + packed B,C
    prep<<<(4 * LSEQ * DI) / 256, 256, 0, stream>>>(proj2, uc2b, xzb, A_log, Dvec,
                                                    dAbuf, ygb, Fbuf, Bbf, Cbf);

    // 6) pass A: local scans + yloc + g
    passA<<<dim3(16, NC, 4), 256, 0, stream>>>(dAbuf, uc2b, Bbf, Cbf, ygb, gbuf, sEnd, Pbuf);

    // 7) pass B: chunk-state combine -> bf16 s_init
    passB<<<dim3(256, 4), 256, 0, stream>>>(sEnd, Pbuf, sInitB);

    // 8) corrK: MFMA correction + epilogue -> final g values in ygb
    corrK<<<dim3(8, NC, 4), 256, 0, stream>>>(Cbf, sInitB, gbuf, Fbuf, ygb);

    // 9) out = (gf + gb) @ W_out^T, split-K=4 + reduce
    gemm64<<<dim3(8, 32, 4), 256, 0, stream>>>(ygb, ygb + (size_t)2 * LSEQ * DI, wob, gpart,
                                               B_ * LSEQ, DM, DI, 4, 0);
    reduce4<<<1024, 256, 0, stream>>>(gpart, out, B_ * LSEQ * DM);
}

// Round 7
// 206.471 us; speedup vs baseline: 2.6271x; 1.0102x over previous
//
#include <hip/hip_runtime.h>
#include <math.h>

#define B_    2
#define LSEQ  1024
#define DM    512
#define DI    1024
#define NS    64
#define NPROJ (DI + 2*NS)   // 1152
#define TC    64
#define NC    (LSEQ/TC)     // 16
#define LDP   72            // padded LDS row stride (shorts): 144 B -> conflict-free

typedef __bf16 bf16x8 __attribute__((ext_vector_type(8)));
typedef float  f32x4  __attribute__((ext_vector_type(4)));

__device__ __forceinline__ float sp_f(float x)   { return fmaxf(x, 0.f) + log1pf(expf(-fabsf(x))); }
__device__ __forceinline__ float silu_f(float x) { return x / (1.f + expf(-x)); }
__device__ __forceinline__ unsigned short f2bf(float f) {
    unsigned int u = __float_as_uint(f);
    u += 0x7FFF + ((u >> 16) & 1);          // RNE
    return (unsigned short)(u >> 16);
}
__device__ __forceinline__ float bf2f(unsigned short h) {
    return __uint_as_float(((unsigned int)h) << 16);
}
__device__ __forceinline__ uint4 bfadd8(uint4 a, uint4 b) {
    uint4 r;
    unsigned* pa = (unsigned*)&a; unsigned* pb = (unsigned*)&b; unsigned* pr = (unsigned*)&r;
#pragma unroll
    for (int i = 0; i < 4; i++) {
        unsigned wa = pa[i], wb = pb[i];
        float lo = __uint_as_float(wa << 16) + __uint_as_float(wb << 16);
        float hi = __uint_as_float(wa & 0xffff0000u) + __uint_as_float(wb & 0xffff0000u);
        pr[i] = ((unsigned)f2bf(lo)) | (((unsigned)f2bf(hi)) << 16);
    }
    return r;
}

// ---------------------------------------------------------------------------
// All 4 f32->bf16 casts in one launch (3712 blocks exactly).
// ---------------------------------------------------------------------------
__global__ __launch_bounds__(256) void castall(
    const float* __restrict__ x, const float* __restrict__ W_in,
    const float* __restrict__ W_xproj, const float* __restrict__ W_out,
    unsigned short* __restrict__ xb, unsigned short* __restrict__ winb,
    unsigned short* __restrict__ wxb, unsigned short* __restrict__ wob)
{
    int i = (blockIdx.x * 256 + threadIdx.x) * 4;
    const float* s; unsigned short* dst; int off;
    if (i < 1048576)      { s = x;       dst = xb;   off = i; }
    else if (i < 2097152) { s = W_in;    dst = winb; off = i - 1048576; }
    else if (i < 3276800) { s = W_xproj; dst = wxb;  off = i - 2097152; }
    else                  { s = W_out;   dst = wob;  off = i - 3276800; }
    float4 v = *(const float4*)(s + off);
    ushort4 o;
    o.x = f2bf(v.x); o.y = f2bf(v.y); o.z = f2bf(v.z); o.w = f2bf(v.w);
    *(ushort4*)(dst + off) = o;
}

// ---------------------------------------------------------------------------
// bf16 MFMA GEMM, 128x128 tile, BK=64, 4 waves (2x2), wave = 64x64.
// LDS rows padded to 72 shorts (144 B): consecutive rows shift 4 banks ->
// the 16-row x 4-group ds_read_b128 pattern hits each bank exactly 8x = 0
// excess conflicts (was 16-way at 128 B stride = 7.08M conflicts/dispatch).
// C[kz] = (A [+A2]) * B^T ; ks = K-split; outbf: bf16 output.
// ---------------------------------------------------------------------------
__global__ __launch_bounds__(256) void gemm128(
    const unsigned short* __restrict__ A, const unsigned short* __restrict__ A2,
    const unsigned short* __restrict__ B,
    float* __restrict__ C, int M, int N, int K, int ks, int outbf)
{
    __shared__ short As[128 * LDP];
    __shared__ short Bs[128 * LDP];
    const int tid  = threadIdx.x;
    const int lane = tid & 63, wid = tid >> 6;
    const int bm = blockIdx.y * 128, bn = blockIdx.x * 128;
    const int wm = (wid >> 1) * 64,  wn = (wid & 1) * 64;
    const int fr = lane & 15, fk = (lane >> 4) * 8;
    const int Kc = K / ks;
    const int k0beg = blockIdx.z * Kc;
    const int k0end = k0beg + Kc;
    float* Cz = C + (size_t)blockIdx.z * M * N;
    unsigned short* Czb = (unsigned short*)C + (size_t)blockIdx.z * M * N;

    f32x4 acc[4][4];
#pragma unroll
    for (int i = 0; i < 4; i++)
#pragma unroll
        for (int j = 0; j < 4; j++) acc[i][j] = (f32x4)0.f;

    uint4 ra[4], rb[4];
#pragma unroll
    for (int r = 0; r < 4; r++) {                   // prefetch first K-step
        int o = tid * 16 + r * 4096;                // byte offset in 16KB (unpadded) tile
        int row = o >> 7, colb = o & 127;
        ra[r] = *(const uint4*)((const char*)A + ((size_t)(bm + row) * K + k0beg) * 2 + colb);
        if (A2) ra[r] = bfadd8(ra[r], *(const uint4*)((const char*)A2 + ((size_t)(bm + row) * K + k0beg) * 2 + colb));
        rb[r] = *(const uint4*)((const char*)B + ((size_t)(bn + row) * K + k0beg) * 2 + colb);
    }

    for (int k0 = k0beg; k0 < k0end; k0 += 64) {
        __syncthreads();
#pragma unroll
        for (int r = 0; r < 4; r++) {
            int o = tid * 16 + r * 4096;
            int row = o >> 7, colb = o & 127;
            *(uint4*)((char*)As + row * (LDP * 2) + colb) = ra[r];
            *(uint4*)((char*)Bs + row * (LDP * 2) + colb) = rb[r];
        }
        __syncthreads();
        if (k0 + 64 < k0end) {
#pragma unroll
            for (int r = 0; r < 4; r++) {
                int o = tid * 16 + r * 4096;
                int row = o >> 7, colb = o & 127;
                ra[r] = *(const uint4*)((const char*)A + ((size_t)(bm + row) * K + k0 + 64) * 2 + colb);
                if (A2) ra[r] = bfadd8(ra[r], *(const uint4*)((const char*)A2 + ((size_t)(bm + row) * K + k0 + 64) * 2 + colb));
                rb[r] = *(const uint4*)((const char*)B + ((size_t)(bn + row) * K + k0 + 64) * 2 + colb);
            }
        }
#pragma unroll
        for (int kk = 0; kk < 2; kk++) {
            bf16x8 af[4], bfr[4];
#pragma unroll
            for (int i = 0; i < 4; i++)
                af[i] = *reinterpret_cast<const bf16x8*>(&As[(wm + i * 16 + fr) * LDP + kk * 32 + fk]);
#pragma unroll
            for (int j = 0; j < 4; j++)
                bfr[j] = *reinterpret_cast<const bf16x8*>(&Bs[(wn + j * 16 + fr) * LDP + kk * 32 + fk]);
#pragma unroll
            for (int i = 0; i < 4; i++)
#pragma unroll
                for (int j = 0; j < 4; j++)
                    acc[i][j] = __builtin_amdgcn_mfma_f32_16x16x32_bf16(af[i], bfr[j], acc[i][j], 0, 0, 0);
        }
    }

    const int crow = (lane >> 4) * 4;
#pragma unroll
    for (int i = 0; i < 4; i++)
#pragma unroll
        for (int j = 0; j < 4; j++)
#pragma unroll
            for (int r = 0; r < 4; r++) {
                size_t idx = (size_t)(bm + wm + i * 16 + crow + r) * N + (bn + wn + j * 16 + fr);
                if (outbf) Czb[idx] = f2bf(acc[i][j][r]);
                else       Cz[idx]  = acc[i][j][r];
            }
}

// ---------------------------------------------------------------------------
// Split-K reduce: out = p0+p1+p2+p3
// ---------------------------------------------------------------------------
__global__ __launch_bounds__(256) void reduce4(
    const float* __restrict__ p, float* __restrict__ out, int n)
{
    int i = (blockIdx.x * 256 + threadIdx.x) * 4;
    if (i >= n) return;
    float4 a = *(const float4*)(p + i);
    float4 b = *(const float4*)(p + n + i);
    float4 c = *(const float4*)(p + 2 * n + i);
    float4 d = *(const float4*)(p + 3 * n + i);
    float4 o;
    o.x = (a.x + b.x) + (c.x + d.x);
    o.y = (a.y + b.y) + (c.y + d.y);
    o.z = (a.z + b.z) + (c.z + d.z);
    o.w = (a.w + b.w) + (c.w + d.w);
    *(float4*)(out + i) = o;
}

// ---------------------------------------------------------------------------
// Depthwise causal conv (fwd) + anti-causal (bwd) + SiLU -> bf16 u. xzb bf16.
// ---------------------------------------------------------------------------
__global__ __launch_bounds__(256) void convk(
    const unsigned short* __restrict__ xzb, const float* __restrict__ cw,
    const float* __restrict__ cb, unsigned short* __restrict__ uc2b)
{
    int idx = blockIdx.x * 256 + threadIdx.x;
    int b   = idx >> 20;
    int rem = idx & ((LSEQ * DI) - 1);
    int tau = rem >> 10;
    int d   = rem & (DI - 1);

    const unsigned short* xc = xzb + (size_t)b * LSEQ * (2 * DI);
    float w0 = cw[d * 4 + 0], w1 = cw[d * 4 + 1], w2 = cw[d * 4 + 2], w3 = cw[d * 4 + 3];
    float bias = cb[d];
    float accf = bias, accb = bias;
    {
        int t0 = tau - 3, t1 = tau - 2, t2 = tau - 1;
        if (t0 >= 0) accf = fmaf(w0, bf2f(xc[(size_t)t0 * 2048 + d]), accf);
        if (t1 >= 0) accf = fmaf(w1, bf2f(xc[(size_t)t1 * 2048 + d]), accf);
        if (t2 >= 0) accf = fmaf(w2, bf2f(xc[(size_t)t2 * 2048 + d]), accf);
        accf = fmaf(w3, bf2f(xc[(size_t)tau * 2048 + d]), accf);
    }
    {
        int t0 = tau + 3, t1 = tau + 2, t2 = tau + 1;
        if (t0 < LSEQ) accb = fmaf(w0, bf2f(xc[(size_t)t0 * 2048 + d]), accb);
        if (t1 < LSEQ) accb = fmaf(w1, bf2f(xc[(size_t)t1 * 2048 + d]), accb);
        if (t2 < LSEQ) accb = fmaf(w2, bf2f(xc[(size_t)t2 * 2048 + d]), accb);
        accb = fmaf(w3, bf2f(xc[(size_t)tau * 2048 + d]), accb);
    }
    uc2b[((size_t)b * LSEQ + tau) * DI + d]       = f2bf(silu_f(accf));
    uc2b[((size_t)(2 + b) * LSEQ + tau) * DI + d] = f2bf(silu_f(accb));
}

// ---------------------------------------------------------------------------
// Prep: transcendental hoist + operand packing.
// ---------------------------------------------------------------------------
__global__ __launch_bounds__(256) void prep(
    const float* __restrict__ proj2, unsigned short* __restrict__ uc2b,
    const unsigned short* __restrict__ xzb, const float* __restrict__ A_log,
    const float* __restrict__ Dvec, float* __restrict__ dAbuf,
    unsigned short* __restrict__ ygb, unsigned short* __restrict__ Fbuf,
    unsigned short* __restrict__ Bbf, unsigned short* __restrict__ Cbf)
{
    int idx  = blockIdx.x * 256 + threadIdx.x;     // (dirb, tau, d)
    int dirb = idx >> 20;
    int rem  = idx & ((LSEQ * DI) - 1);
    int tau  = rem >> 10;
    int d    = rem & (DI - 1);
    int b    = dirb & 1;
    int dir  = dirb >> 1;

    const float* prow = proj2 + (size_t)dirb * LSEQ * NPROJ + (size_t)tau * NPROJ;
    float delta = sp_f(prow[d]);
    float Ad    = -expf(A_log[d]);
    size_t uidx = ((size_t)dirb * LSEQ + tau) * DI + d;
    dAbuf[uidx] = expf(delta * Ad);

    float u = bf2f(uc2b[uidx]);
    uc2b[uidx] = f2bf(delta * u);
    ygb[uidx]  = f2bf(Dvec[d] * u);

    if (dir == 0) {
        float z = bf2f(xzb[((size_t)b * LSEQ + tau) * (2 * DI) + DI + d]);
        Fbuf[((size_t)b * LSEQ + tau) * DI + d] = f2bf(0.5f * silu_f(z));
    }
    if (d < 2 * NS) {
        unsigned short v = f2bf(prow[DI + d]);
        if (d < NS) Bbf[((size_t)dirb * LSEQ + tau) * NS + d]        = v;
        else        Cbf[((size_t)dirb * LSEQ + tau) * NS + (d - NS)] = v;
    }
}

// ---------------------------------------------------------------------------
// Pass A: local chunk scan from zero; emits yloc (+Du, into ygb),
// g running product (bf16), chunk-end states (bf16), P.
// ---------------------------------------------------------------------------
__global__ __launch_bounds__(256) void passA(
    const float* __restrict__ dAbuf, const unsigned short* __restrict__ du2b,
    const unsigned short* __restrict__ Bbf, const unsigned short* __restrict__ Cbf,
    unsigned short* __restrict__ ygb, unsigned short* __restrict__ gbuf,
    unsigned short* __restrict__ sEnd, float* __restrict__ Pbuf)
{
    const int dl   = threadIdx.x >> 2;
    const int nq   = threadIdx.x & 3;
    const int d0   = blockIdx.x * 64;
    const int d    = d0 + dl;
    const int c    = blockIdx.y;
    const int dirb = blockIdx.z;
    const int dir  = dirb >> 1;

    __shared__ float Bsh[TC][NS];
    __shared__ float Csh[TC][NS];
    __shared__ unsigned short gshY[TC][64];
    __shared__ unsigned short gshG[TC][64];

    for (int i = threadIdx.x * 4; i < TC * NS; i += 1024) {
        int tl = i >> 6, n = i & 63;
        int tau = dir ? (LSEQ - 1 - (c * TC + tl)) : (c * TC + tl);
        ushort4 vb = *(const ushort4*)&Bbf[((size_t)dirb * LSEQ + tau) * NS + n];
        ushort4 vc = *(const ushort4*)&Cbf[((size_t)dirb * LSEQ + tau) * NS + n];
        Bsh[tl][n+0] = bf2f(vb.x); Bsh[tl][n+1] = bf2f(vb.y);
        Bsh[tl][n+2] = bf2f(vb.z); Bsh[tl][n+3] = bf2f(vb.w);
        Csh[tl][n+0] = bf2f(vc.x); Csh[tl][n+1] = bf2f(vc.y);
        Csh[tl][n+2] = bf2f(vc.z); Csh[tl][n+3] = bf2f(vc.w);
    }
    __syncthreads();

    float s[16];
#pragma unroll
    for (int i = 0; i < 16; i++) s[i] = 0.f;
    float g_run = 1.f;

    int tau0 = dir ? (LSEQ - 1 - c * TC) : (c * TC);
    long stp = (dir ? -1L : 1L) * (long)DI;
    const float* pDA = dAbuf + ((size_t)dirb * LSEQ + tau0) * DI + d;
    const unsigned short* pDU = du2b + ((size_t)dirb * LSEQ + tau0) * DI + d;
    const unsigned short* pY  = ygb  + ((size_t)dirb * LSEQ + tau0) * DI + d;

    float dA = *pDA, du = bf2f(*pDU), Du = bf2f(*pY);
    for (int tl = 0; tl < TC; tl++) {
        float dA_c = dA, du_c = du, Du_c = Du;
        if (tl + 1 < TC) {                        // 1-deep register prefetch
            pDA += stp; pDU += stp; pY += stp;
            dA = *pDA; du = bf2f(*pDU); Du = bf2f(*pY);
        }
        g_run *= dA_c;
        float ydot = 0.f;
        const float4* brow = (const float4*)&Bsh[tl][nq * 16];
        const float4* crow = (const float4*)&Csh[tl][nq * 16];
#pragma unroll
        for (int q = 0; q < 4; q++) {
            float4 bv = brow[q];
            float4 cv = crow[q];
            float s0 = fmaf(du_c, bv.x, dA_c * s[4*q+0]); s[4*q+0] = s0; ydot = fmaf(cv.x, s0, ydot);
            float s1 = fmaf(du_c, bv.y, dA_c * s[4*q+1]); s[4*q+1] = s1; ydot = fmaf(cv.y, s1, ydot);
            float s2 = fmaf(du_c, bv.z, dA_c * s[4*q+2]); s[4*q+2] = s2; ydot = fmaf(cv.z, s2, ydot);
            float s3 = fmaf(du_c, bv.w, dA_c * s[4*q+3]); s[4*q+3] = s3; ydot = fmaf(cv.w, s3, ydot);
        }
        ydot += __shfl_xor(ydot, 1);
        ydot += __shfl_xor(ydot, 2);
        if (nq == 0) {
            gshY[tl][dl] = f2bf(Du_c + ydot);
            gshG[tl][dl] = f2bf(g_run);
        }
    }
    __syncthreads();

    size_t base = (((size_t)dirb * NC + c) * DI + d) * NS + nq * 16;
#pragma unroll
    for (int q = 0; q < 4; q++) {
        ushort4 v;
        v.x = f2bf(s[4*q+0]); v.y = f2bf(s[4*q+1]);
        v.z = f2bf(s[4*q+2]); v.w = f2bf(s[4*q+3]);
        *(ushort4*)&sEnd[base + q * 4] = v;
    }
    if (nq == 0) Pbuf[((size_t)dirb * NC + c) * DI + d] = g_run;

    for (int i = threadIdx.x * 4; i < TC * 64; i += 1024) {
        int tl = i >> 6, col = i & 63;
        int tau = dir ? (LSEQ - 1 - (c * TC + tl)) : (c * TC + tl);
        *(ushort4*)&ygb[((size_t)dirb * LSEQ + tau) * DI + d0 + col]  = *(const ushort4*)&gshY[tl][col];
        *(ushort4*)&gbuf[((size_t)dirb * LSEQ + tau) * DI + d0 + col] = *(const ushort4*)&gshG[tl][col];
    }
}

// ---------------------------------------------------------------------------
// Pass B: combine chunk states; sEnd bf16 in, sInitB bf16 out (f32 running).
// ---------------------------------------------------------------------------
__global__ __launch_bounds__(256) void passB(
    const unsigned short* __restrict__ sEnd, const float* __restrict__ Pbuf,
    unsigned short* __restrict__ sInitB)
{
    const int fl   = blockIdx.x * 256 + threadIdx.x;   // d*64 + n
    const int dirb = blockIdx.y;
    const int d    = fl >> 6;
    float run = 0.f;
    for (int c = 0; c < NC; c++) {
        size_t idx = ((size_t)(dirb * NC + c)) * (DI * NS) + fl;
        float tmp = bf2f(sEnd[idx]);
        sInitB[idx] = f2bf(run);
        float P = Pbuf[((size_t)dirb * NC + c) * DI + d];
        run = fmaf(P, run, tmp);
    }
}

// ---------------------------------------------------------------------------
// corrK: per (dirb, chunk, 128-d group): corr = C_chunk[64,64] @ s_init[d,n]^T
// via MFMA (padded LDS, same conflict fix), then out = F*(yloc + g*corr).
// ---------------------------------------------------------------------------
__global__ __launch_bounds__(256) void corrK(
    const unsigned short* __restrict__ Cbf, const unsigned short* __restrict__ sInitB,
    const unsigned short* __restrict__ gbuf, const unsigned short* __restrict__ Fbuf,
    unsigned short* __restrict__ ygb)
{
    const int tid  = threadIdx.x;
    const int lane = tid & 63, wid = tid >> 6;
    const int d0   = blockIdx.x * 128;
    const int c    = blockIdx.y;
    const int dirb = blockIdx.z;
    const int dir  = dirb >> 1;
    const int b    = dirb & 1;
    const int fr = lane & 15, fk = (lane >> 4) * 8;
    const int wm = (wid >> 1) * 32, wn = (wid & 1) * 64;

    __shared__ short Cs[64 * LDP];     // [t][n] bf16, padded
    __shared__ short Ss[128 * LDP];    // [d][n] bf16, padded
    __shared__ float corrS[64 * 128];  // [t][d]

    for (int i = tid * 4; i < 64 * 64; i += 1024) {
        int tl = i >> 6, n = i & 63;
        int tau = dir ? (LSEQ - 1 - (c * TC + tl)) : (c * TC + tl);
        *(ushort4*)&Cs[tl * LDP + n] = *(const ushort4*)&Cbf[((size_t)dirb * LSEQ + tau) * NS + n];
    }
    for (int i = tid * 4; i < 128 * 64; i += 1024) {
        int r = i >> 6, n = i & 63;
        *(ushort4*)&Ss[r * LDP + n] =
            *(const ushort4*)&sInitB[(((size_t)dirb * NC + c) * DI + d0 + r) * NS + n];
    }
    __syncthreads();

    f32x4 acc[2][4];
#pragma unroll
    for (int i = 0; i < 2; i++)
#pragma unroll
        for (int j = 0; j < 4; j++) acc[i][j] = (f32x4)0.f;

#pragma unroll
    for (int kk = 0; kk < 2; kk++) {
        bf16x8 af[2], bfr[4];
#pragma unroll
        for (int i = 0; i < 2; i++)
            af[i] = *reinterpret_cast<const bf16x8*>(&Cs[(wm + i * 16 + fr) * LDP + kk * 32 + fk]);
#pragma unroll
        for (int j = 0; j < 4; j++)
            bfr[j] = *reinterpret_cast<const bf16x8*>(&Ss[(wn + j * 16 + fr) * LDP + kk * 32 + fk]);
#pragma unroll
        for (int i = 0; i < 2; i++)
#pragma unroll
            for (int j = 0; j < 4; j++)
                acc[i][j] = __builtin_amdgcn_mfma_f32_16x16x32_bf16(af[i], bfr[j], acc[i][j], 0, 0, 0);
    }

    const int crow = (lane >> 4) * 4;
#pragma unroll
    for (int i = 0; i < 2; i++)
#pragma unroll
        for (int j = 0; j < 4; j++)
#pragma unroll
            for (int r = 0; r < 4; r++)
                corrS[(wm + i * 16 + crow + r) * 128 + (wn + j * 16 + fr)] = acc[i][j][r];
    __syncthreads();

    // epilogue: out = F * (yloc + g*corr), coalesced rows of 128 d
    for (int i = tid * 4; i < 64 * 128; i += 1024) {
        int tl = i >> 7, col = i & 127;
        int tau = dir ? (LSEQ - 1 - (c * TC + tl)) : (c * TC + tl);
        size_t gi = ((size_t)dirb * LSEQ + tau) * DI + d0 + col;
        size_t fi = ((size_t)b    * LSEQ + tau) * DI + d0 + col;
        ushort4 g4 = *(const ushort4*)&gbuf[gi];
        ushort4 y4 = *(const ushort4*)&ygb[gi];
        ushort4 F4 = *(const ushort4*)&Fbuf[fi];
        const float* cr = &corrS[tl * 128 + col];
        ushort4 o;
        o.x = f2bf(bf2f(F4.x) * fmaf(bf2f(g4.x), cr[0], bf2f(y4.x)));
        o.y = f2bf(bf2f(F4.y) * fmaf(bf2f(g4.y), cr[1], bf2f(y4.y)));
        o.z = f2bf(bf2f(F4.z) * fmaf(bf2f(g4.z), cr[2], bf2f(y4.z)));
        o.w = f2bf(bf2f(F4.w) * fmaf(bf2f(g4.w), cr[3], bf2f(y4.w)));
        *(ushort4*)&ygb[gi] = o;
    }
}

// ---------------------------------------------------------------------------
extern "C" void kernel_launch(void* const* d_in, const int* in_sizes, int n_in,
                              void* d_out, int out_size, void* d_ws, size_t ws_size,
                              hipStream_t stream)
{
    const float* x      = (const float*)d_in[0];
    const float* W_in   = (const float*)d_in[1];
    const float* conv_w = (const float*)d_in[2];
    const float* conv_b = (const float*)d_in[3];
    const float* W_xprj = (const float*)d_in[4];
    const float* A_log  = (const float*)d_in[5];
    const float* Dvec   = (const float*)d_in[6];
    const float* W_out  = (const float*)d_in[7];
    float* out = (float*)d_out;

    // workspace layout, ~67.4 MB (all aliases dead-before-overwrite):
    float* ws = (float*)d_ws;
    float*          proj2 = ws;                                   // 4,718,592 f
    unsigned short* uc2b  = (unsigned short*)(ws + 4718592);      // 4,194,304 sh
    unsigned short* xzb   = uc2b + 4194304;                       // 4,194,304 sh
    float*          dAbuf = ws + 8912896;                         // 4,194,304 f
    unsigned short* Fbuf  = (unsigned short*)(ws + 13107200);     // 2,097,152 sh
    unsigned short* ygb   = Fbuf + 2097152;                       // 4,194,304 sh
    unsigned short* Bbf   = ygb + 4194304;                        //   262,144 sh
    unsigned short* Cbf   = Bbf + 262144;                         //   262,144 sh
    unsigned short* wob   = Cbf + 262144;                         //   524,288 sh
    float*          Pbuf  = (float*)(wob + 524288);               //    65,536 f
    // aliases:
    unsigned short* sInitB = (unsigned short*)proj2;              // passB out (proj2 dead after prep)
    unsigned short* gbuf   = (unsigned short*)(proj2 + 2097152);  // passA out
    unsigned short* sEnd   = xzb;                                 // passA out (xzb dead after prep)
    unsigned short* xb     = (unsigned short*)dAbuf;              // cast, dead after gemm1
    unsigned short* winb   = xb + 1048576;                        // cast, dead after gemm1
    unsigned short* wxb    = ygb;                                 // cast, dead after gemm2
    float*          gpart  = dAbuf;                               // split-K partials (dAbuf dead after passA)

    // 1) bf16 casts
    castall<<<3712, 256, 0, stream>>>(x, W_in, W_xprj, W_out, xb, winb, wxb, wob);

    // 2) xz = x @ W_in^T -> bf16 (M=2048, N=2048, K=512) — 256 blocks
    gemm128<<<dim3(16, 16), 256, 0, stream>>>(xb, nullptr, winb, (float*)xzb, B_ * LSEQ, 2 * DI, DM, 1, 1);

    // 3) conv both dirs + SiLU -> bf16 u
    convk<<<(B_ * LSEQ * DI) / 256, 256, 0, stream>>>(xzb, conv_w, conv_b, uc2b);

    // 4) proj2 = uc2 @ W_xproj^T -> f32 (M=4096, N=1152, K=1024) — 288 blocks
    gemm128<<<dim3(9, 32), 256, 0, stream>>>(uc2b, nullptr, wxb, proj2, 4 * LSEQ, NPROJ, DI, 1, 0);

    // 5) prep: dA/du/Du/F + packed B,C
    prep<<<(4 * LSEQ * DI) / 256, 256, 0, stream>>>(proj2, uc2b, xzb, A_log, Dvec,
                                                    dAbuf, ygb, Fbuf, Bbf, Cbf);

    // 6) pass A: local scans + yloc + g
    passA<<<dim3(16, NC, 4), 256, 0, stream>>>(dAbuf, uc2b, Bbf, Cbf, ygb, gbuf, sEnd, Pbuf);

    // 7) pass B: chunk-state combine -> bf16 s_init
    passB<<<dim3(256, 4), 256, 0, stream>>>(sEnd, Pbuf, sInitB);

    // 8) corrK: MFMA correction + epilogue -> final g values in ygb
    corrK<<<dim3(8, NC, 4), 256, 0, stream>>>(Cbf, sInitB, gbuf, Fbuf, ygb);

    // 9) out = (gf + gb) @ W_out^T, split-K=4 (256 blocks) + reduce
    gemm128<<<dim3(4, 16, 4), 256, 0, stream>>>(ygb, ygb + (size_t)2 * LSEQ * DI, wob, gpart,
                                                B_ * LSEQ, DM, DI, 4, 0);
    reduce4<<<1024, 256, 0, stream>>>(gpart, out, B_ * LSEQ * DM);
}

// Round 8
// 188.329 us; speedup vs baseline: 2.8801x; 1.0963x over previous
//
#include <hip/hip_runtime.h>
#include <math.h>

#define B_    2
#define LSEQ  1024
#define DM    512
#define DI    1024
#define NS    64
#define TC    64
#define NC    (LSEQ/TC)     // 16
#define LDP   72            // padded stride for corrK tiles only

typedef __bf16 bf16x8 __attribute__((ext_vector_type(8)));
typedef float  f32x4  __attribute__((ext_vector_type(4)));

__device__ __forceinline__ float sp_f(float x)   { return fmaxf(x, 0.f) + log1pf(expf(-fabsf(x))); }
__device__ __forceinline__ float silu_f(float x) { return x / (1.f + expf(-x)); }
__device__ __forceinline__ unsigned short f2bf(float f) {
    unsigned int u = __float_as_uint(f);
    u += 0x7FFF + ((u >> 16) & 1);          // RNE
    return (unsigned short)(u >> 16);
}
__device__ __forceinline__ float bf2f(unsigned short h) {
    return __uint_as_float(((unsigned int)h) << 16);
}
// async global->LDS, 16 B per lane; l must be wave-uniform (lane lands at l + lane*16)
__device__ __forceinline__ void gload16(const void* g, void* l) {
    __builtin_amdgcn_global_load_lds(
        (const __attribute__((address_space(1))) unsigned int*)g,
        (__attribute__((address_space(3))) unsigned int*)l, 16, 0, 0);
}

// ---------------------------------------------------------------------------
// All 4 f32->bf16 casts in one launch (3712 blocks exactly).
// ---------------------------------------------------------------------------
__global__ __launch_bounds__(256) void castall(
    const float* __restrict__ x, const float* __restrict__ W_in,
    const float* __restrict__ W_xproj, const float* __restrict__ W_out,
    unsigned short* __restrict__ xb, unsigned short* __restrict__ winb,
    unsigned short* __restrict__ wxb, unsigned short* __restrict__ wob)
{
    int i = (blockIdx.x * 256 + threadIdx.x) * 4;
    const float* s; unsigned short* dst; int off;
    if (i < 1048576)      { s = x;       dst = xb;   off = i; }
    else if (i < 2097152) { s = W_in;    dst = winb; off = i - 1048576; }
    else if (i < 3276800) { s = W_xproj; dst = wxb;  off = i - 2097152; }
    else                  { s = W_out;   dst = wob;  off = i - 3276800; }
    float4 v = *(const float4*)(s + off);
    ushort4 o;
    o.x = f2bf(v.x); o.y = f2bf(v.y); o.z = f2bf(v.z); o.w = f2bf(v.w);
    *(ushort4*)(dst + off) = o;
}

// ---------------------------------------------------------------------------
// bf16 MFMA GEMM, m97 structure: 128x128 tile, BK=64, 4 waves (2x2),
// wave = 64x64, LINEAR LDS + global_load_lds width-16 staging.
// K-concat: for k0 >= wrapK, A source switches Alo->Ahi (k-index rebased),
// B k-index wraps (row strides of A and B are wrapK elements in all uses).
// mode 0: f32 C. mode 1: bf16 C. mode 2: fused Mamba prep epilogue
//   (cols<1024: delta->dA f32 + du bf16; cols>=1024: pack B/C bf16).
// ---------------------------------------------------------------------------
__global__ __launch_bounds__(256) void gemm128(
    const unsigned short* __restrict__ Alo, const unsigned short* __restrict__ Ahi,
    const unsigned short* __restrict__ B, float* __restrict__ C,
    int M, int N, int K, int wrapK, int ks, int mode,
    const float* __restrict__ A_log, const unsigned short* __restrict__ u_in,
    float* __restrict__ dA_out, unsigned short* __restrict__ du_out,
    unsigned short* __restrict__ Bbf, unsigned short* __restrict__ Cbf)
{
    __shared__ short As[128 * 64];
    __shared__ short Bs[128 * 64];
    const int tid  = threadIdx.x;
    const int lane = tid & 63, wid = tid >> 6;
    const int bm = blockIdx.y * 128, bn = blockIdx.x * 128;
    const int wm = (wid >> 1) * 64,  wn = (wid & 1) * 64;
    const int fr = lane & 15, fk = (lane >> 4) * 8;
    const int Kc = K / ks;
    const int k0beg = blockIdx.z * Kc;
    const int k0end = k0beg + Kc;
    float* Cz = C + (size_t)blockIdx.z * M * N;
    unsigned short* Czb = (unsigned short*)C + (size_t)blockIdx.z * M * N;

    f32x4 acc[4][4];
#pragma unroll
    for (int i = 0; i < 4; i++)
#pragma unroll
        for (int j = 0; j < 4; j++) acc[i][j] = (f32x4)0.f;

    for (int k0 = k0beg; k0 < k0end; k0 += 64) {
        const unsigned short* Asrc = (k0 < wrapK) ? Alo : Ahi;
        const int ka = (k0 < wrapK) ? k0 : k0 - wrapK;   // A k-index (== B's)
        __syncthreads();                                 // LDS free (prev MFMA done)
#pragma unroll
        for (int r = 0; r < 4; r++) {
            int o   = tid * 16 + r * 4096;               // linear byte off in 16KB tile
            int row = o >> 7, colb = o & 127;
            int wb  = (tid >> 6) * 1024 + r * 4096;      // wave-uniform LDS byte base
            gload16((const char*)Asrc + ((size_t)(bm + row) * wrapK + ka) * 2 + colb,
                    (char*)As + wb);
            gload16((const char*)B    + ((size_t)(bn + row) * wrapK + ka) * 2 + colb,
                    (char*)Bs + wb);
        }
        __syncthreads();                                 // drains vmcnt -> LDS ready
#pragma unroll
        for (int kk = 0; kk < 2; kk++) {
            bf16x8 af[4], bfr[4];
#pragma unroll
            for (int i = 0; i < 4; i++)
                af[i] = *reinterpret_cast<const bf16x8*>(&As[(wm + i * 16 + fr) * 64 + kk * 32 + fk]);
#pragma unroll
            for (int j = 0; j < 4; j++)
                bfr[j] = *reinterpret_cast<const bf16x8*>(&Bs[(wn + j * 16 + fr) * 64 + kk * 32 + fk]);
#pragma unroll
            for (int i = 0; i < 4; i++)
#pragma unroll
                for (int j = 0; j < 4; j++)
                    acc[i][j] = __builtin_amdgcn_mfma_f32_16x16x32_bf16(af[i], bfr[j], acc[i][j], 0, 0, 0);
        }
    }

    const int crow = (lane >> 4) * 4;
    if (mode == 2) {
        if (bn < 1024) {                                 // delta region -> dA, du
#pragma unroll
            for (int j = 0; j < 4; j++) {
                int d = bn + wn + j * 16 + fr;
                float nAd = -expf(A_log[d]);
#pragma unroll
                for (int i = 0; i < 4; i++)
#pragma unroll
                    for (int r = 0; r < 4; r++) {
                        int m = bm + wm + i * 16 + crow + r;
                        float delta = sp_f(acc[i][j][r]);
                        size_t idx = (size_t)m * DI + d;
                        dA_out[idx] = expf(delta * nAd);
                        du_out[idx] = f2bf(delta * bf2f(u_in[idx]));
                    }
            }
        } else {                                         // B/C pack region
#pragma unroll
            for (int j = 0; j < 4; j++) {
                int cc = bn + wn + j * 16 + fr;
#pragma unroll
                for (int i = 0; i < 4; i++)
#pragma unroll
                    for (int r = 0; r < 4; r++) {
                        int m = bm + wm + i * 16 + crow + r;
                        unsigned short v16 = f2bf(acc[i][j][r]);
                        if (cc < 1024 + NS) Bbf[(size_t)m * NS + cc - 1024]      = v16;
                        else                Cbf[(size_t)m * NS + cc - 1024 - NS] = v16;
                    }
            }
        }
    } else {
#pragma unroll
        for (int i = 0; i < 4; i++)
#pragma unroll
            for (int j = 0; j < 4; j++)
#pragma unroll
                for (int r = 0; r < 4; r++) {
                    size_t idx = (size_t)(bm + wm + i * 16 + crow + r) * N + (bn + wn + j * 16 + fr);
                    if (mode == 1) Czb[idx] = f2bf(acc[i][j][r]);
                    else           Cz[idx]  = acc[i][j][r];
                }
    }
}

// ---------------------------------------------------------------------------
// Split-K reduce: out = p0+p1+p2+p3
// ---------------------------------------------------------------------------
__global__ __launch_bounds__(256) void reduce4(
    const float* __restrict__ p, float* __restrict__ out, int n)
{
    int i = (blockIdx.x * 256 + threadIdx.x) * 4;
    if (i >= n) return;
    float4 a = *(const float4*)(p + i);
    float4 b = *(const float4*)(p + n + i);
    float4 c = *(const float4*)(p + 2 * n + i);
    float4 d = *(const float4*)(p + 3 * n + i);
    float4 o;
    o.x = (a.x + b.x) + (c.x + d.x);
    o.y = (a.y + b.y) + (c.y + d.y);
    o.z = (a.z + b.z) + (c.z + d.z);
    o.w = (a.w + b.w) + (c.w + d.w);
    *(float4*)(out + i) = o;
}

// ---------------------------------------------------------------------------
// Conv (causal fwd + anti-causal bwd) + SiLU -> u; fused D*u and F=0.5*silu(z).
// ---------------------------------------------------------------------------
__global__ __launch_bounds__(256) void convk(
    const unsigned short* __restrict__ xzb, const float* __restrict__ cw,
    const float* __restrict__ cb, const float* __restrict__ Dvec,
    unsigned short* __restrict__ uc2b, unsigned short* __restrict__ ygb,
    unsigned short* __restrict__ Fbuf)
{
    int idx = blockIdx.x * 256 + threadIdx.x;
    int b   = idx >> 20;
    int rem = idx & ((LSEQ * DI) - 1);
    int tau = rem >> 10;
    int d   = rem & (DI - 1);

    const unsigned short* xc = xzb + (size_t)b * LSEQ * (2 * DI);
    float w0 = cw[d * 4 + 0], w1 = cw[d * 4 + 1], w2 = cw[d * 4 + 2], w3 = cw[d * 4 + 3];
    float bias = cb[d];
    float accf = bias, accb = bias;
    {
        int t0 = tau - 3, t1 = tau - 2, t2 = tau - 1;
        if (t0 >= 0) accf = fmaf(w0, bf2f(xc[(size_t)t0 * 2048 + d]), accf);
        if (t1 >= 0) accf = fmaf(w1, bf2f(xc[(size_t)t1 * 2048 + d]), accf);
        if (t2 >= 0) accf = fmaf(w2, bf2f(xc[(size_t)t2 * 2048 + d]), accf);
        accf = fmaf(w3, bf2f(xc[(size_t)tau * 2048 + d]), accf);
    }
    {
        int t0 = tau + 3, t1 = tau + 2, t2 = tau + 1;
        if (t0 < LSEQ) accb = fmaf(w0, bf2f(xc[(size_t)t0 * 2048 + d]), accb);
        if (t1 < LSEQ) accb = fmaf(w1, bf2f(xc[(size_t)t1 * 2048 + d]), accb);
        if (t2 < LSEQ) accb = fmaf(w2, bf2f(xc[(size_t)t2 * 2048 + d]), accb);
        accb = fmaf(w3, bf2f(xc[(size_t)tau * 2048 + d]), accb);
    }
    float uf = silu_f(accf), ub = silu_f(accb);
    size_t fi = ((size_t)b * LSEQ + tau) * DI + d;
    size_t bi = ((size_t)(2 + b) * LSEQ + tau) * DI + d;
    uc2b[fi] = f2bf(uf);
    uc2b[bi] = f2bf(ub);
    float Dd = Dvec[d];
    ygb[fi] = f2bf(Dd * uf);
    ygb[bi] = f2bf(Dd * ub);
    float z = bf2f(xc[(size_t)tau * 2048 + DI + d]);
    Fbuf[fi] = f2bf(0.5f * silu_f(z));
}

// ---------------------------------------------------------------------------
// Pass A: local chunk scan from zero; emits yloc (+Du, into ygb),
// g running product (bf16), chunk-end states (bf16), P.
// ---------------------------------------------------------------------------
__global__ __launch_bounds__(256) void passA(
    const float* __restrict__ dAbuf, const unsigned short* __restrict__ dub,
    const unsigned short* __restrict__ Bbf, const unsigned short* __restrict__ Cbf,
    unsigned short* __restrict__ ygb, unsigned short* __restrict__ gbuf,
    unsigned short* __restrict__ sEnd, float* __restrict__ Pbuf)
{
    const int dl   = threadIdx.x >> 2;
    const int nq   = threadIdx.x & 3;
    const int d0   = blockIdx.x * 64;
    const int d    = d0 + dl;
    const int c    = blockIdx.y;
    const int dirb = blockIdx.z;
    const int dir  = dirb >> 1;

    __shared__ float Bsh[TC][NS];
    __shared__ float Csh[TC][NS];
    __shared__ unsigned short gshY[TC][64];
    __shared__ unsigned short gshG[TC][64];

    for (int i = threadIdx.x * 4; i < TC * NS; i += 1024) {
        int tl = i >> 6, n = i & 63;
        int tau = dir ? (LSEQ - 1 - (c * TC + tl)) : (c * TC + tl);
        ushort4 vb = *(const ushort4*)&Bbf[((size_t)dirb * LSEQ + tau) * NS + n];
        ushort4 vc = *(const ushort4*)&Cbf[((size_t)dirb * LSEQ + tau) * NS + n];
        Bsh[tl][n+0] = bf2f(vb.x); Bsh[tl][n+1] = bf2f(vb.y);
        Bsh[tl][n+2] = bf2f(vb.z); Bsh[tl][n+3] = bf2f(vb.w);
        Csh[tl][n+0] = bf2f(vc.x); Csh[tl][n+1] = bf2f(vc.y);
        Csh[tl][n+2] = bf2f(vc.z); Csh[tl][n+3] = bf2f(vc.w);
    }
    __syncthreads();

    float s[16];
#pragma unroll
    for (int i = 0; i < 16; i++) s[i] = 0.f;
    float g_run = 1.f;

    int tau0 = dir ? (LSEQ - 1 - c * TC) : (c * TC);
    long stp = (dir ? -1L : 1L) * (long)DI;
    const float* pDA = dAbuf + ((size_t)dirb * LSEQ + tau0) * DI + d;
    const unsigned short* pDU = dub + ((size_t)dirb * LSEQ + tau0) * DI + d;
    const unsigned short* pY  = ygb + ((size_t)dirb * LSEQ + tau0) * DI + d;

    float dA = *pDA, du = bf2f(*pDU), Du = bf2f(*pY);
    for (int tl = 0; tl < TC; tl++) {
        float dA_c = dA, du_c = du, Du_c = Du;
        if (tl + 1 < TC) {                        // 1-deep register prefetch
            pDA += stp; pDU += stp; pY += stp;
            dA = *pDA; du = bf2f(*pDU); Du = bf2f(*pY);
        }
        g_run *= dA_c;
        float ydot = 0.f;
        const float4* brow = (const float4*)&Bsh[tl][nq * 16];
        const float4* crow = (const float4*)&Csh[tl][nq * 16];
#pragma unroll
        for (int q = 0; q < 4; q++) {
            float4 bv = brow[q];
            float4 cv = crow[q];
            float s0 = fmaf(du_c, bv.x, dA_c * s[4*q+0]); s[4*q+0] = s0; ydot = fmaf(cv.x, s0, ydot);
            float s1 = fmaf(du_c, bv.y, dA_c * s[4*q+1]); s[4*q+1] = s1; ydot = fmaf(cv.y, s1, ydot);
            float s2 = fmaf(du_c, bv.z, dA_c * s[4*q+2]); s[4*q+2] = s2; ydot = fmaf(cv.z, s2, ydot);
            float s3 = fmaf(du_c, bv.w, dA_c * s[4*q+3]); s[4*q+3] = s3; ydot = fmaf(cv.w, s3, ydot);
        }
        ydot += __shfl_xor(ydot, 1);
        ydot += __shfl_xor(ydot, 2);
        if (nq == 0) {
            gshY[tl][dl] = f2bf(Du_c + ydot);
            gshG[tl][dl] = f2bf(g_run);
        }
    }
    __syncthreads();

    size_t base = (((size_t)dirb * NC + c) * DI + d) * NS + nq * 16;
#pragma unroll
    for (int q = 0; q < 4; q++) {
        ushort4 v;
        v.x = f2bf(s[4*q+0]); v.y = f2bf(s[4*q+1]);
        v.z = f2bf(s[4*q+2]); v.w = f2bf(s[4*q+3]);
        *(ushort4*)&sEnd[base + q * 4] = v;
    }
    if (nq == 0) Pbuf[((size_t)dirb * NC + c) * DI + d] = g_run;

    for (int i = threadIdx.x * 4; i < TC * 64; i += 1024) {
        int tl = i >> 6, col = i & 63;
        int tau = dir ? (LSEQ - 1 - (c * TC + tl)) : (c * TC + tl);
        *(ushort4*)&ygb[((size_t)dirb * LSEQ + tau) * DI + d0 + col]  = *(const ushort4*)&gshY[tl][col];
        *(ushort4*)&gbuf[((size_t)dirb * LSEQ + tau) * DI + d0 + col] = *(const ushort4*)&gshG[tl][col];
    }
}

// ---------------------------------------------------------------------------
// Pass B: combine chunk states; sEnd bf16 in, sInitB bf16 out (f32 running).
// ---------------------------------------------------------------------------
__global__ __launch_bounds__(256) void passB(
    const unsigned short* __restrict__ sEnd, const float* __restrict__ Pbuf,
    unsigned short* __restrict__ sInitB)
{
    const int fl   = blockIdx.x * 256 + threadIdx.x;   // d*64 + n
    const int dirb = blockIdx.y;
    const int d    = fl >> 6;
    float run = 0.f;
    for (int c = 0; c < NC; c++) {
        size_t idx = ((size_t)(dirb * NC + c)) * (DI * NS) + fl;
        float tmp = bf2f(sEnd[idx]);
        sInitB[idx] = f2bf(run);
        float P = Pbuf[((size_t)dirb * NC + c) * DI + d];
        run = fmaf(P, run, tmp);
    }
}

// ---------------------------------------------------------------------------
// corrK: per (dirb, chunk, 128-d group): corr = C_chunk[64,64] @ s_init[d,n]^T
// via MFMA (padded LDS), then out = F*(yloc + g*corr) -> ygb in place.
// ---------------------------------------------------------------------------
__global__ __launch_bounds__(256) void corrK(
    const unsigned short* __restrict__ Cbf, const unsigned short* __restrict__ sInitB,
    const unsigned short* __restrict__ gbuf, const unsigned short* __restrict__ Fbuf,
    unsigned short* __restrict__ ygb)
{
    const int tid  = threadIdx.x;
    const int lane = tid & 63, wid = tid >> 6;
    const int d0   = blockIdx.x * 128;
    const int c    = blockIdx.y;
    const int dirb = blockIdx.z;
    const int dir  = dirb >> 1;
    const int b    = dirb & 1;
    const int fr = lane & 15, fk = (lane >> 4) * 8;
    const int wm = (wid >> 1) * 32, wn = (wid & 1) * 64;

    __shared__ short Cs[64 * LDP];
    __shared__ short Ss[128 * LDP];
    __shared__ float corrS[64 * 128];

    for (int i = tid * 4; i < 64 * 64; i += 1024) {
        int tl = i >> 6, n = i & 63;
        int tau = dir ? (LSEQ - 1 - (c * TC + tl)) : (c * TC + tl);
        *(ushort4*)&Cs[tl * LDP + n] = *(const ushort4*)&Cbf[((size_t)dirb * LSEQ + tau) * NS + n];
    }
    for (int i = tid * 4; i < 128 * 64; i += 1024) {
        int r = i >> 6, n = i & 63;
        *(ushort4*)&Ss[r * LDP + n] =
            *(const ushort4*)&sInitB[(((size_t)dirb * NC + c) * DI + d0 + r) * NS + n];
    }
    __syncthreads();

    f32x4 acc[2][4];
#pragma unroll
    for (int i = 0; i < 2; i++)
#pragma unroll
        for (int j = 0; j < 4; j++) acc[i][j] = (f32x4)0.f;

#pragma unroll
    for (int kk = 0; kk < 2; kk++) {
        bf16x8 af[2], bfr[4];
#pragma unroll
        for (int i = 0; i < 2; i++)
            af[i] = *reinterpret_cast<const bf16x8*>(&Cs[(wm + i * 16 + fr) * LDP + kk * 32 + fk]);
#pragma unroll
        for (int j = 0; j < 4; j++)
            bfr[j] = *reinterpret_cast<const bf16x8*>(&Ss[(wn + j * 16 + fr) * LDP + kk * 32 + fk]);
#pragma unroll
        for (int i = 0; i < 2; i++)
#pragma unroll
            for (int j = 0; j < 4; j++)
                acc[i][j] = __builtin_amdgcn_mfma_f32_16x16x32_bf16(af[i], bfr[j], acc[i][j], 0, 0, 0);
    }

    const int crow = (lane >> 4) * 4;
#pragma unroll
    for (int i = 0; i < 2; i++)
#pragma unroll
        for (int j = 0; j < 4; j++)
#pragma unroll
            for (int r = 0; r < 4; r++)
                corrS[(wm + i * 16 + crow + r) * 128 + (wn + j * 16 + fr)] = acc[i][j][r];
    __syncthreads();

    for (int i = tid * 4; i < 64 * 128; i += 1024) {
        int tl = i >> 7, col = i & 127;
        int tau = dir ? (LSEQ - 1 - (c * TC + tl)) : (c * TC + tl);
        size_t gi = ((size_t)dirb * LSEQ + tau) * DI + d0 + col;
        size_t fi = ((size_t)b    * LSEQ + tau) * DI + d0 + col;
        ushort4 g4 = *(const ushort4*)&gbuf[gi];
        ushort4 y4 = *(const ushort4*)&ygb[gi];
        ushort4 F4 = *(const ushort4*)&Fbuf[fi];
        const float* cr = &corrS[tl * 128 + col];
        ushort4 o;
        o.x = f2bf(bf2f(F4.x) * fmaf(bf2f(g4.x), cr[0], bf2f(y4.x)));
        o.y = f2bf(bf2f(F4.y) * fmaf(bf2f(g4.y), cr[1], bf2f(y4.y)));
        o.z = f2bf(bf2f(F4.z) * fmaf(bf2f(g4.z), cr[2], bf2f(y4.z)));
        o.w = f2bf(bf2f(F4.w) * fmaf(bf2f(g4.w), cr[3], bf2f(y4.w)));
        *(ushort4*)&ygb[gi] = o;
    }
}

// ---------------------------------------------------------------------------
extern "C" void kernel_launch(void* const* d_in, const int* in_sizes, int n_in,
                              void* d_out, int out_size, void* d_ws, size_t ws_size,
                              hipStream_t stream)
{
    const float* x      = (const float*)d_in[0];
    const float* W_in   = (const float*)d_in[1];
    const float* conv_w = (const float*)d_in[2];
    const float* conv_b = (const float*)d_in[3];
    const float* W_xprj = (const float*)d_in[4];
    const float* A_log  = (const float*)d_in[5];
    const float* Dvec   = (const float*)d_in[6];
    const float* W_out  = (const float*)d_in[7];
    float* out = (float*)d_out;

    // workspace ~65.3 MB; aliases are dead-before-overwrite (stream order):
    float* ws = (float*)d_ws;
    float*          dAbuf = ws;                                   // [4096][1024] f32, 16.8 MB
    unsigned short* uc2b  = (unsigned short*)(ws + 4194304);      // u, 8.4 MB
    unsigned short* xzb   = uc2b + 4194304;                       // 8.4 MB
    unsigned short* dub   = xzb  + 4194304;                       // du, 8.4 MB
    unsigned short* ygb   = dub  + 4194304;                       // Du->yloc->g, 8.4 MB
    unsigned short* gbuf  = ygb  + 4194304;                       // 8.4 MB
    unsigned short* Fbuf  = gbuf + 4194304;                       // 4.2 MB
    unsigned short* Bbf   = Fbuf + 2097152;                       // 0.5 MB
    unsigned short* Cbf   = Bbf  + 262144;                        // 0.5 MB
    unsigned short* wob   = Cbf  + 262144;                        // 1.0 MB
    float*          Pbuf  = (float*)(wob + 524288);               // 0.26 MB
    // aliases:
    unsigned short* xb     = (unsigned short*)dAbuf;              // dead after gemm1 (dAbuf written by gemm2)
    unsigned short* winb   = xb + 1048576;                        // dead after gemm1
    unsigned short* wxb    = gbuf;                                // dead after gemm2 (gbuf written in passA)
    unsigned short* sEnd   = xzb;                                 // xzb dead after convk
    unsigned short* sInitB = uc2b;                                // u dead after gemm2 epilogue
    float*          gpart  = dAbuf;                               // dAbuf dead after passA (== 4x2048x512 f32)

    // 1) bf16 casts
    castall<<<3712, 256, 0, stream>>>(x, W_in, W_xprj, W_out, xb, winb, wxb, wob);

    // 2) xz = x @ W_in^T -> bf16 (M=2048, N=2048, K=512)
    gemm128<<<dim3(16, 16), 256, 0, stream>>>(xb, nullptr, winb, (float*)xzb,
        B_ * LSEQ, 2 * DI, DM, DM, 1, 1, nullptr, nullptr, nullptr, nullptr, nullptr, nullptr);

    // 3) conv both dirs + SiLU -> u; fused D*u and F=0.5*silu(z)
    convk<<<(B_ * LSEQ * DI) / 256, 256, 0, stream>>>(xzb, conv_w, conv_b, Dvec, uc2b, ygb, Fbuf);

    // 4) proj GEMM with fused prep epilogue: dA/du + packed B,C
    gemm128<<<dim3(9, 32), 256, 0, stream>>>(uc2b, nullptr, wxb, nullptr,
        4 * LSEQ, DI + 2 * NS, DI, DI, 1, 2, A_log, uc2b, dAbuf, dub, Bbf, Cbf);

    // 5) pass A: local scans + yloc + g
    passA<<<dim3(16, NC, 4), 256, 0, stream>>>(dAbuf, dub, Bbf, Cbf, ygb, gbuf, sEnd, Pbuf);

    // 6) pass B: chunk-state combine -> bf16 s_init
    passB<<<dim3(256, 4), 256, 0, stream>>>(sEnd, Pbuf, sInitB);

    // 7) corrK: MFMA correction + epilogue -> final g values in ygb
    corrK<<<dim3(8, NC, 4), 256, 0, stream>>>(Cbf, sInitB, gbuf, Fbuf, ygb);

    // 8) out = [gf | gb] @ [W|W]^T via K-concat (K=2048, wrapK=1024), split-K=4
    gemm128<<<dim3(4, 16, 4), 256, 0, stream>>>(ygb, ygb + (size_t)2 * LSEQ * DI, wob, gpart,
        B_ * LSEQ, DM, 2 * DI, DI, 4, 0, nullptr, nullptr, nullptr, nullptr, nullptr, nullptr);
    reduce4<<<1024, 256, 0, stream>>>(gpart, out, B_ * LSEQ * DM);
}

// Round 9
// 160.850 us; speedup vs baseline: 3.3721x; 1.1708x over previous
//
#include <hip/hip_runtime.h>
#include <math.h>

#define B_    2
#define LSEQ  1024
#define DM    512
#define DI    1024
#define NS    64
#define TC    64
#define NC    (LSEQ/TC)     // 16
#define LDP   72            // padded stride for corrK tiles only

typedef __bf16 bf16x8 __attribute__((ext_vector_type(8)));
typedef float  f32x4  __attribute__((ext_vector_type(4)));

__device__ __forceinline__ float sp_f(float x)   { return fmaxf(x, 0.f) + log1pf(expf(-fabsf(x))); }
__device__ __forceinline__ float silu_f(float x) { return x / (1.f + expf(-x)); }
__device__ __forceinline__ unsigned short f2bf(float f) {
    unsigned int u = __float_as_uint(f);
    u += 0x7FFF + ((u >> 16) & 1);          // RNE
    return (unsigned short)(u >> 16);
}
__device__ __forceinline__ float bf2f(unsigned short h) {
    return __uint_as_float(((unsigned int)h) << 16);
}
// async global->LDS, 16 B per lane; LDS dest must be wave-uniform base + lane*16
__device__ __forceinline__ void gload16(const void* g, void* l) {
    __builtin_amdgcn_global_load_lds(
        (const __attribute__((address_space(1))) unsigned int*)g,
        (__attribute__((address_space(3))) unsigned int*)l, 16, 0, 0);
}

// ---------------------------------------------------------------------------
// All 4 f32->bf16 casts in one launch (3712 blocks exactly).
// ---------------------------------------------------------------------------
__global__ __launch_bounds__(256) void castall(
    const float* __restrict__ x, const float* __restrict__ W_in,
    const float* __restrict__ W_xproj, const float* __restrict__ W_out,
    unsigned short* __restrict__ xb, unsigned short* __restrict__ winb,
    unsigned short* __restrict__ wxb, unsigned short* __restrict__ wob)
{
    int i = (blockIdx.x * 256 + threadIdx.x) * 4;
    const float* s; unsigned short* dst; int off;
    if (i < 1048576)      { s = x;       dst = xb;   off = i; }
    else if (i < 2097152) { s = W_in;    dst = winb; off = i - 1048576; }
    else if (i < 3276800) { s = W_xproj; dst = wxb;  off = i - 2097152; }
    else                  { s = W_out;   dst = wob;  off = i - 3276800; }
    float4 v = *(const float4*)(s + off);
    ushort4 o;
    o.x = f2bf(v.x); o.y = f2bf(v.y); o.z = f2bf(v.z); o.w = f2bf(v.w);
    *(ushort4*)(dst + off) = o;
}

// ---------------------------------------------------------------------------
// bf16 MFMA GEMM: 128x64 tile (BM=128, BN=64), BK=64, 4 waves each 32x64.
// Halved BN doubles the grid vs 128x128 -> 2+ blocks/CU so cross-block waves
// hide the global_load_lds drain (the R8 profile showed 1 block/CU, MfmaUtil 3%).
// Linear LDS + global_load_lds width-16 staging (m97 structure).
// K-concat: for k0 >= wrapK, A source switches Alo->Ahi; k-index rebased.
// mode 0: f32 C. mode 1: bf16 C. mode 2: fused Mamba prep epilogue.
// ---------------------------------------------------------------------------
__global__ __launch_bounds__(256) void gemm128(
    const unsigned short* __restrict__ Alo, const unsigned short* __restrict__ Ahi,
    const unsigned short* __restrict__ B, float* __restrict__ C,
    int M, int N, int K, int wrapK, int ks, int mode,
    const float* __restrict__ A_log, const unsigned short* __restrict__ u_in,
    float* __restrict__ dA_out, unsigned short* __restrict__ du_out,
    unsigned short* __restrict__ Bbf, unsigned short* __restrict__ Cbf)
{
    __shared__ short As[128 * 64];
    __shared__ short Bs[64 * 64];
    const int tid  = threadIdx.x;
    const int lane = tid & 63, wid = tid >> 6;
    const int bm = blockIdx.y * 128, bn = blockIdx.x * 64;
    const int wm = wid * 32;
    const int fr = lane & 15, fk = (lane >> 4) * 8;
    const int Kc = K / ks;
    const int k0beg = blockIdx.z * Kc;
    const int k0end = k0beg + Kc;
    float* Cz = C + (size_t)blockIdx.z * M * N;
    unsigned short* Czb = (unsigned short*)C + (size_t)blockIdx.z * M * N;

    f32x4 acc[2][4];
#pragma unroll
    for (int i = 0; i < 2; i++)
#pragma unroll
        for (int j = 0; j < 4; j++) acc[i][j] = (f32x4)0.f;

    for (int k0 = k0beg; k0 < k0end; k0 += 64) {
        const unsigned short* Asrc = (k0 < wrapK) ? Alo : Ahi;
        const int ka = (k0 < wrapK) ? k0 : k0 - wrapK;
        __syncthreads();
#pragma unroll
        for (int r = 0; r < 4; r++) {                    // A tile: 16 KB
            int o   = tid * 16 + r * 4096;
            int row = o >> 7, colb = o & 127;
            int wb  = wid * 1024 + r * 4096;
            gload16((const char*)Asrc + ((size_t)(bm + row) * wrapK + ka) * 2 + colb,
                    (char*)As + wb);
        }
#pragma unroll
        for (int r = 0; r < 2; r++) {                    // B tile: 8 KB
            int o   = tid * 16 + r * 4096;
            int row = o >> 7, colb = o & 127;
            int wb  = wid * 1024 + r * 4096;
            gload16((const char*)B + ((size_t)(bn + row) * wrapK + ka) * 2 + colb,
                    (char*)Bs + wb);
        }
        __syncthreads();
#pragma unroll
        for (int kk = 0; kk < 2; kk++) {
            bf16x8 af[2], bfr[4];
#pragma unroll
            for (int i = 0; i < 2; i++)
                af[i] = *reinterpret_cast<const bf16x8*>(&As[(wm + i * 16 + fr) * 64 + kk * 32 + fk]);
#pragma unroll
            for (int j = 0; j < 4; j++)
                bfr[j] = *reinterpret_cast<const bf16x8*>(&Bs[(j * 16 + fr) * 64 + kk * 32 + fk]);
#pragma unroll
            for (int i = 0; i < 2; i++)
#pragma unroll
                for (int j = 0; j < 4; j++)
                    acc[i][j] = __builtin_amdgcn_mfma_f32_16x16x32_bf16(af[i], bfr[j], acc[i][j], 0, 0, 0);
        }
    }

    const int crow = (lane >> 4) * 4;
    if (mode == 2) {
        if (bn < 1024) {                                 // delta region -> dA, du
#pragma unroll
            for (int j = 0; j < 4; j++) {
                int d = bn + j * 16 + fr;
                float nAd = -expf(A_log[d]);
#pragma unroll
                for (int i = 0; i < 2; i++)
#pragma unroll
                    for (int r = 0; r < 4; r++) {
                        int m = bm + wm + i * 16 + crow + r;
                        float delta = sp_f(acc[i][j][r]);
                        size_t idx = (size_t)m * DI + d;
                        dA_out[idx] = expf(delta * nAd);
                        du_out[idx] = f2bf(delta * bf2f(u_in[idx]));
                    }
            }
        } else {                                         // B/C pack region
#pragma unroll
            for (int j = 0; j < 4; j++) {
                int cc = bn + j * 16 + fr;
#pragma unroll
                for (int i = 0; i < 2; i++)
#pragma unroll
                    for (int r = 0; r < 4; r++) {
                        int m = bm + wm + i * 16 + crow + r;
                        unsigned short v16 = f2bf(acc[i][j][r]);
                        if (cc < 1024 + NS) Bbf[(size_t)m * NS + cc - 1024]      = v16;
                        else                Cbf[(size_t)m * NS + cc - 1024 - NS] = v16;
                    }
            }
        }
    } else {
#pragma unroll
        for (int i = 0; i < 2; i++)
#pragma unroll
            for (int j = 0; j < 4; j++)
#pragma unroll
                for (int r = 0; r < 4; r++) {
                    size_t idx = (size_t)(bm + wm + i * 16 + crow + r) * N + (bn + j * 16 + fr);
                    if (mode == 1) Czb[idx] = f2bf(acc[i][j][r]);
                    else           Cz[idx]  = acc[i][j][r];
                }
    }
}

// ---------------------------------------------------------------------------
// Split-K reduce: out = p0+p1+p2+p3
// ---------------------------------------------------------------------------
__global__ __launch_bounds__(256) void reduce4(
    const float* __restrict__ p, float* __restrict__ out, int n)
{
    int i = (blockIdx.x * 256 + threadIdx.x) * 4;
    if (i >= n) return;
    float4 a = *(const float4*)(p + i);
    float4 b = *(const float4*)(p + n + i);
    float4 c = *(const float4*)(p + 2 * n + i);
    float4 d = *(const float4*)(p + 3 * n + i);
    float4 o;
    o.x = (a.x + b.x) + (c.x + d.x);
    o.y = (a.y + b.y) + (c.y + d.y);
    o.z = (a.z + b.z) + (c.z + d.z);
    o.w = (a.w + b.w) + (c.w + d.w);
    *(float4*)(out + i) = o;
}

// ---------------------------------------------------------------------------
// Conv (causal fwd + anti-causal bwd) + SiLU -> u; fused D*u and F=0.5*silu(z).
// ---------------------------------------------------------------------------
__global__ __launch_bounds__(256) void convk(
    const unsigned short* __restrict__ xzb, const float* __restrict__ cw,
    const float* __restrict__ cb, const float* __restrict__ Dvec,
    unsigned short* __restrict__ uc2b, unsigned short* __restrict__ ygb,
    unsigned short* __restrict__ Fbuf)
{
    int idx = blockIdx.x * 256 + threadIdx.x;
    int b   = idx >> 20;
    int rem = idx & ((LSEQ * DI) - 1);
    int tau = rem >> 10;
    int d   = rem & (DI - 1);

    const unsigned short* xc = xzb + (size_t)b * LSEQ * (2 * DI);
    float w0 = cw[d * 4 + 0], w1 = cw[d * 4 + 1], w2 = cw[d * 4 + 2], w3 = cw[d * 4 + 3];
    float bias = cb[d];
    float accf = bias, accb = bias;
    {
        int t0 = tau - 3, t1 = tau - 2, t2 = tau - 1;
        if (t0 >= 0) accf = fmaf(w0, bf2f(xc[(size_t)t0 * 2048 + d]), accf);
        if (t1 >= 0) accf = fmaf(w1, bf2f(xc[(size_t)t1 * 2048 + d]), accf);
        if (t2 >= 0) accf = fmaf(w2, bf2f(xc[(size_t)t2 * 2048 + d]), accf);
        accf = fmaf(w3, bf2f(xc[(size_t)tau * 2048 + d]), accf);
    }
    {
        int t0 = tau + 3, t1 = tau + 2, t2 = tau + 1;
        if (t0 < LSEQ) accb = fmaf(w0, bf2f(xc[(size_t)t0 * 2048 + d]), accb);
        if (t1 < LSEQ) accb = fmaf(w1, bf2f(xc[(size_t)t1 * 2048 + d]), accb);
        if (t2 < LSEQ) accb = fmaf(w2, bf2f(xc[(size_t)t2 * 2048 + d]), accb);
        accb = fmaf(w3, bf2f(xc[(size_t)tau * 2048 + d]), accb);
    }
    float uf = silu_f(accf), ub = silu_f(accb);
    size_t fi = ((size_t)b * LSEQ + tau) * DI + d;
    size_t bi = ((size_t)(2 + b) * LSEQ + tau) * DI + d;
    uc2b[fi] = f2bf(uf);
    uc2b[bi] = f2bf(ub);
    float Dd = Dvec[d];
    ygb[fi] = f2bf(Dd * uf);
    ygb[bi] = f2bf(Dd * ub);
    float z = bf2f(xc[(size_t)tau * 2048 + DI + d]);
    Fbuf[fi] = f2bf(0.5f * silu_f(z));
}

// ---------------------------------------------------------------------------
// Pass A: local chunk scan from zero; emits yloc (+Du, into ygb),
// g running product (bf16), chunk-end states (bf16), P.
// ---------------------------------------------------------------------------
__global__ __launch_bounds__(256) void passA(
    const float* __restrict__ dAbuf, const unsigned short* __restrict__ dub,
    const unsigned short* __restrict__ Bbf, const unsigned short* __restrict__ Cbf,
    unsigned short* __restrict__ ygb, unsigned short* __restrict__ gbuf,
    unsigned short* __restrict__ sEnd, float* __restrict__ Pbuf)
{
    const int dl   = threadIdx.x >> 2;
    const int nq   = threadIdx.x & 3;
    const int d0   = blockIdx.x * 64;
    const int d    = d0 + dl;
    const int c    = blockIdx.y;
    const int dirb = blockIdx.z;
    const int dir  = dirb >> 1;

    __shared__ float Bsh[TC][NS];
    __shared__ float Csh[TC][NS];
    __shared__ unsigned short gshY[TC][64];
    __shared__ unsigned short gshG[TC][64];

    for (int i = threadIdx.x * 4; i < TC * NS; i += 1024) {
        int tl = i >> 6, n = i & 63;
        int tau = dir ? (LSEQ - 1 - (c * TC + tl)) : (c * TC + tl);
        ushort4 vb = *(const ushort4*)&Bbf[((size_t)dirb * LSEQ + tau) * NS + n];
        ushort4 vc = *(const ushort4*)&Cbf[((size_t)dirb * LSEQ + tau) * NS + n];
        Bsh[tl][n+0] = bf2f(vb.x); Bsh[tl][n+1] = bf2f(vb.y);
        Bsh[tl][n+2] = bf2f(vb.z); Bsh[tl][n+3] = bf2f(vb.w);
        Csh[tl][n+0] = bf2f(vc.x); Csh[tl][n+1] = bf2f(vc.y);
        Csh[tl][n+2] = bf2f(vc.z); Csh[tl][n+3] = bf2f(vc.w);
    }
    __syncthreads();

    float s[16];
#pragma unroll
    for (int i = 0; i < 16; i++) s[i] = 0.f;
    float g_run = 1.f;

    int tau0 = dir ? (LSEQ - 1 - c * TC) : (c * TC);
    long stp = (dir ? -1L : 1L) * (long)DI;
    const float* pDA = dAbuf + ((size_t)dirb * LSEQ + tau0) * DI + d;
    const unsigned short* pDU = dub + ((size_t)dirb * LSEQ + tau0) * DI + d;
    const unsigned short* pY  = ygb + ((size_t)dirb * LSEQ + tau0) * DI + d;

    float dA = *pDA, du = bf2f(*pDU), Du = bf2f(*pY);
    for (int tl = 0; tl < TC; tl++) {
        float dA_c = dA, du_c = du, Du_c = Du;
        if (tl + 1 < TC) {                        // 1-deep register prefetch
            pDA += stp; pDU += stp; pY += stp;
            dA = *pDA; du = bf2f(*pDU); Du = bf2f(*pY);
        }
        g_run *= dA_c;
        float ydot = 0.f;
        const float4* brow = (const float4*)&Bsh[tl][nq * 16];
        const float4* crow = (const float4*)&Csh[tl][nq * 16];
#pragma unroll
        for (int q = 0; q < 4; q++) {
            float4 bv = brow[q];
            float4 cv = crow[q];
            float s0 = fmaf(du_c, bv.x, dA_c * s[4*q+0]); s[4*q+0] = s0; ydot = fmaf(cv.x, s0, ydot);
            float s1 = fmaf(du_c, bv.y, dA_c * s[4*q+1]); s[4*q+1] = s1; ydot = fmaf(cv.y, s1, ydot);
            float s2 = fmaf(du_c, bv.z, dA_c * s[4*q+2]); s[4*q+2] = s2; ydot = fmaf(cv.z, s2, ydot);
            float s3 = fmaf(du_c, bv.w, dA_c * s[4*q+3]); s[4*q+3] = s3; ydot = fmaf(cv.w, s3, ydot);
        }
        ydot += __shfl_xor(ydot, 1);
        ydot += __shfl_xor(ydot, 2);
        if (nq == 0) {
            gshY[tl][dl] = f2bf(Du_c + ydot);
            gshG[tl][dl] = f2bf(g_run);
        }
    }
    __syncthreads();

    size_t base = (((size_t)dirb * NC + c) * DI + d) * NS + nq * 16;
#pragma unroll
    for (int q = 0; q < 4; q++) {
        ushort4 v;
        v.x = f2bf(s[4*q+0]); v.y = f2bf(s[4*q+1]);
        v.z = f2bf(s[4*q+2]); v.w = f2bf(s[4*q+3]);
        *(ushort4*)&sEnd[base + q * 4] = v;
    }
    if (nq == 0) Pbuf[((size_t)dirb * NC + c) * DI + d] = g_run;

    for (int i = threadIdx.x * 4; i < TC * 64; i += 1024) {
        int tl = i >> 6, col = i & 63;
        int tau = dir ? (LSEQ - 1 - (c * TC + tl)) : (c * TC + tl);
        *(ushort4*)&ygb[((size_t)dirb * LSEQ + tau) * DI + d0 + col]  = *(const ushort4*)&gshY[tl][col];
        *(ushort4*)&gbuf[((size_t)dirb * LSEQ + tau) * DI + d0 + col] = *(const ushort4*)&gshG[tl][col];
    }
}

// ---------------------------------------------------------------------------
// Pass B: combine chunk states; sEnd bf16 in, sInitB bf16 out (f32 running).
// ---------------------------------------------------------------------------
__global__ __launch_bounds__(256) void passB(
    const unsigned short* __restrict__ sEnd, const float* __restrict__ Pbuf,
    unsigned short* __restrict__ sInitB)
{
    const int fl   = blockIdx.x * 256 + threadIdx.x;   // d*64 + n
    const int dirb = blockIdx.y;
    const int d    = fl >> 6;
    float run = 0.f;
    for (int c = 0; c < NC; c++) {
        size_t idx = ((size_t)(dirb * NC + c)) * (DI * NS) + fl;
        float tmp = bf2f(sEnd[idx]);
        sInitB[idx] = f2bf(run);
        float P = Pbuf[((size_t)dirb * NC + c) * DI + d];
        run = fmaf(P, run, tmp);
    }
}

// ---------------------------------------------------------------------------
// corrK: per (dirb, chunk, 128-d group): corr = C_chunk[64,64] @ s_init[d,n]^T
// via MFMA (padded LDS), then out = F*(yloc + g*corr) -> ygb in place.
// ---------------------------------------------------------------------------
__global__ __launch_bounds__(256) void corrK(
    const unsigned short* __restrict__ Cbf, const unsigned short* __restrict__ sInitB,
    const unsigned short* __restrict__ gbuf, const unsigned short* __restrict__ Fbuf,
    unsigned short* __restrict__ ygb)
{
    const int tid  = threadIdx.x;
    const int lane = tid & 63, wid = tid >> 6;
    const int d0   = blockIdx.x * 128;
    const int c    = blockIdx.y;
    const int dirb = blockIdx.z;
    const int dir  = dirb >> 1;
    const int b    = dirb & 1;
    const int fr = lane & 15, fk = (lane >> 4) * 8;
    const int wm = (wid >> 1) * 32, wn = (wid & 1) * 64;

    __shared__ short Cs[64 * LDP];
    __shared__ short Ss[128 * LDP];
    __shared__ float corrS[64 * 128];

    for (int i = tid * 4; i < 64 * 64; i += 1024) {
        int tl = i >> 6, n = i & 63;
        int tau = dir ? (LSEQ - 1 - (c * TC + tl)) : (c * TC + tl);
        *(ushort4*)&Cs[tl * LDP + n] = *(const ushort4*)&Cbf[((size_t)dirb * LSEQ + tau) * NS + n];
    }
    for (int i = tid * 4; i < 128 * 64; i += 1024) {
        int r = i >> 6, n = i & 63;
        *(ushort4*)&Ss[r * LDP + n] =
            *(const ushort4*)&sInitB[(((size_t)dirb * NC + c) * DI + d0 + r) * NS + n];
    }
    __syncthreads();

    f32x4 acc[2][4];
#pragma unroll
    for (int i = 0; i < 2; i++)
#pragma unroll
        for (int j = 0; j < 4; j++) acc[i][j] = (f32x4)0.f;

#pragma unroll
    for (int kk = 0; kk < 2; kk++) {
        bf16x8 af[2], bfr[4];
#pragma unroll
        for (int i = 0; i < 2; i++)
            af[i] = *reinterpret_cast<const bf16x8*>(&Cs[(wm + i * 16 + fr) * LDP + kk * 32 + fk]);
#pragma unroll
        for (int j = 0; j < 4; j++)
            bfr[j] = *reinterpret_cast<const bf16x8*>(&Ss[(wn + j * 16 + fr) * LDP + kk * 32 + fk]);
#pragma unroll
        for (int i = 0; i < 2; i++)
#pragma unroll
            for (int j = 0; j < 4; j++)
                acc[i][j] = __builtin_amdgcn_mfma_f32_16x16x32_bf16(af[i], bfr[j], acc[i][j], 0, 0, 0);
    }

    const int crow = (lane >> 4) * 4;
#pragma unroll
    for (int i = 0; i < 2; i++)
#pragma unroll
        for (int j = 0; j < 4; j++)
#pragma unroll
            for (int r = 0; r < 4; r++)
                corrS[(wm + i * 16 + crow + r) * 128 + (wn + j * 16 + fr)] = acc[i][j][r];
    __syncthreads();

    for (int i = tid * 4; i < 64 * 128; i += 1024) {
        int tl = i >> 7, col = i & 127;
        int tau = dir ? (LSEQ - 1 - (c * TC + tl)) : (c * TC + tl);
        size_t gi = ((size_t)dirb * LSEQ + tau) * DI + d0 + col;
        size_t fi = ((size_t)b    * LSEQ + tau) * DI + d0 + col;
        ushort4 g4 = *(const ushort4*)&gbuf[gi];
        ushort4 y4 = *(const ushort4*)&ygb[gi];
        ushort4 F4 = *(const ushort4*)&Fbuf[fi];
        const float* cr = &corrS[tl * 128 + col];
        ushort4 o;
        o.x = f2bf(bf2f(F4.x) * fmaf(bf2f(g4.x), cr[0], bf2f(y4.x)));
        o.y = f2bf(bf2f(F4.y) * fmaf(bf2f(g4.y), cr[1], bf2f(y4.y)));
        o.z = f2bf(bf2f(F4.z) * fmaf(bf2f(g4.z), cr[2], bf2f(y4.z)));
        o.w = f2bf(bf2f(F4.w) * fmaf(bf2f(g4.w), cr[3], bf2f(y4.w)));
        *(ushort4*)&ygb[gi] = o;
    }
}

// ---------------------------------------------------------------------------
extern "C" void kernel_launch(void* const* d_in, const int* in_sizes, int n_in,
                              void* d_out, int out_size, void* d_ws, size_t ws_size,
                              hipStream_t stream)
{
    const float* x      = (const float*)d_in[0];
    const float* W_in   = (const float*)d_in[1];
    const float* conv_w = (const float*)d_in[2];
    const float* conv_b = (const float*)d_in[3];
    const float* W_xprj = (const float*)d_in[4];
    const float* A_log  = (const float*)d_in[5];
    const float* Dvec   = (const float*)d_in[6];
    const float* W_out  = (const float*)d_in[7];
    float* out = (float*)d_out;

    // workspace ~65.3 MB; aliases are dead-before-overwrite (stream order):
    float* ws = (float*)d_ws;
    float*          dAbuf = ws;                                   // [4096][1024] f32, 16.8 MB
    unsigned short* uc2b  = (unsigned short*)(ws + 4194304);      // u, 8.4 MB
    unsigned short* xzb   = uc2b + 4194304;                       // 8.4 MB
    unsigned short* dub   = xzb  + 4194304;                       // du, 8.4 MB
    unsigned short* ygb   = dub  + 4194304;                       // Du->yloc->g, 8.4 MB
    unsigned short* gbuf  = ygb  + 4194304;                       // 8.4 MB
    unsigned short* Fbuf  = gbuf + 4194304;                       // 4.2 MB
    unsigned short* Bbf   = Fbuf + 2097152;                       // 0.5 MB
    unsigned short* Cbf   = Bbf  + 262144;                        // 0.5 MB
    unsigned short* wob   = Cbf  + 262144;                        // 1.0 MB
    float*          Pbuf  = (float*)(wob + 524288);               // 0.26 MB
    // aliases:
    unsigned short* xb     = (unsigned short*)dAbuf;              // dead after gemm1 (dAbuf written by gemm2)
    unsigned short* winb   = xb + 1048576;                        // dead after gemm1
    unsigned short* wxb    = gbuf;                                // dead after gemm2 (gbuf written in passA)
    unsigned short* sEnd   = xzb;                                 // xzb dead after convk
    unsigned short* sInitB = uc2b;                                // u dead after gemm2 epilogue
    float*          gpart  = dAbuf;                               // dAbuf dead after passA (== 4x2048x512 f32)

    // 1) bf16 casts
    castall<<<3712, 256, 0, stream>>>(x, W_in, W_xprj, W_out, xb, winb, wxb, wob);

    // 2) xz = x @ W_in^T -> bf16 (M=2048, N=2048, K=512) — 512 blocks
    gemm128<<<dim3(32, 16), 256, 0, stream>>>(xb, nullptr, winb, (float*)xzb,
        B_ * LSEQ, 2 * DI, DM, DM, 1, 1, nullptr, nullptr, nullptr, nullptr, nullptr, nullptr);

    // 3) conv both dirs + SiLU -> u; fused D*u and F=0.5*silu(z)
    convk<<<(B_ * LSEQ * DI) / 256, 256, 0, stream>>>(xzb, conv_w, conv_b, Dvec, uc2b, ygb, Fbuf);

    // 4) proj GEMM with fused prep epilogue: dA/du + packed B,C — 576 blocks
    gemm128<<<dim3(18, 32), 256, 0, stream>>>(uc2b, nullptr, wxb, nullptr,
        4 * LSEQ, DI + 2 * NS, DI, DI, 1, 2, A_log, uc2b, dAbuf, dub, Bbf, Cbf);

    // 5) pass A: local scans + yloc + g
    passA<<<dim3(16, NC, 4), 256, 0, stream>>>(dAbuf, dub, Bbf, Cbf, ygb, gbuf, sEnd, Pbuf);

    // 6) pass B: chunk-state combine -> bf16 s_init
    passB<<<dim3(256, 4), 256, 0, stream>>>(sEnd, Pbuf, sInitB);

    // 7) corrK: MFMA correction + epilogue -> final g values in ygb
    corrK<<<dim3(8, NC, 4), 256, 0, stream>>>(Cbf, sInitB, gbuf, Fbuf, ygb);

    // 8) out = [gf | gb] @ [W|W]^T via K-concat (K=2048, wrapK=1024), split-K=4 — 512 blocks
    gemm128<<<dim3(8, 16, 4), 256, 0, stream>>>(ygb, ygb + (size_t)2 * LSEQ * DI, wob, gpart,
        B_ * LSEQ, DM, 2 * DI, DI, 4, 0, nullptr, nullptr, nullptr, nullptr, nullptr, nullptr);
    reduce4<<<1024, 256, 0, stream>>>(gpart, out, B_ * LSEQ * DM);
}

// Round 10
// 153.578 us; speedup vs baseline: 3.5318x; 1.0474x over previous
//
#include <hip/hip_runtime.h>
#include <math.h>

#define B_    2
#define LSEQ  1024
#define DM    512
#define DI    1024
#define NS    64
#define TC    64
#define NC    (LSEQ/TC)     // 16
#define LDP   72            // padded stride for corrK tiles only

typedef __bf16 bf16x8 __attribute__((ext_vector_type(8)));
typedef float  f32x4  __attribute__((ext_vector_type(4)));

__device__ __forceinline__ float sp_f(float x)   { return fmaxf(x, 0.f) + log1pf(expf(-fabsf(x))); }
__device__ __forceinline__ float silu_f(float x) { return x / (1.f + expf(-x)); }
__device__ __forceinline__ unsigned short f2bf(float f) {
    unsigned int u = __float_as_uint(f);
    u += 0x7FFF + ((u >> 16) & 1);          // RNE
    return (unsigned short)(u >> 16);
}
__device__ __forceinline__ float bf2f(unsigned short h) {
    return __uint_as_float(((unsigned int)h) << 16);
}
// async global->LDS, 16 B per lane; LDS dest must be wave-uniform base + lane*16
__device__ __forceinline__ void gload16(const void* g, void* l) {
    __builtin_amdgcn_global_load_lds(
        (const __attribute__((address_space(1))) unsigned int*)g,
        (__attribute__((address_space(3))) unsigned int*)l, 16, 0, 0);
}

// ---------------------------------------------------------------------------
// All 4 f32->bf16 casts in one launch (3712 blocks exactly).
// ---------------------------------------------------------------------------
__global__ __launch_bounds__(256) void castall(
    const float* __restrict__ x, const float* __restrict__ W_in,
    const float* __restrict__ W_xproj, const float* __restrict__ W_out,
    unsigned short* __restrict__ xb, unsigned short* __restrict__ winb,
    unsigned short* __restrict__ wxb, unsigned short* __restrict__ wob)
{
    int i = (blockIdx.x * 256 + threadIdx.x) * 4;
    const float* s; unsigned short* dst; int off;
    if (i < 1048576)      { s = x;       dst = xb;   off = i; }
    else if (i < 2097152) { s = W_in;    dst = winb; off = i - 1048576; }
    else if (i < 3276800) { s = W_xproj; dst = wxb;  off = i - 2097152; }
    else                  { s = W_out;   dst = wob;  off = i - 3276800; }
    float4 v = *(const float4*)(s + off);
    ushort4 o;
    o.x = f2bf(v.x); o.y = f2bf(v.y); o.z = f2bf(v.z); o.w = f2bf(v.w);
    *(ushort4*)(dst + off) = o;
}

// ---------------------------------------------------------------------------
// bf16 MFMA GEMM: 128x64 tile, BK=64, 4 waves each 32x64.
// Linear LDS + global_load_lds, with BOTH-SIDES XOR swizzle (rule #21):
//   physical 16B chunk = logical chunk ^ (row & 7)
// - staging: LDS dest stays linear; per-lane GLOBAL column is pre-swizzled
//   (same 128-B row segments -> coalescing unchanged).
// - read: fragment chunk index XOR'd with (fr & 7) -> each ds_read_b128
//   spreads 64 lanes uniformly over all 8 chunks (8 lanes/chunk, optimal),
//   killing the 16-way row-alias conflict (was 5.3M conflicts/dispatch).
// K-concat: for k0 >= wrapK, A source switches Alo->Ahi; k-index rebased.
// mode 0: f32 C. mode 1: bf16 C. mode 2: fused Mamba prep epilogue.
// ---------------------------------------------------------------------------
__global__ __launch_bounds__(256) void gemm128(
    const unsigned short* __restrict__ Alo, const unsigned short* __restrict__ Ahi,
    const unsigned short* __restrict__ B, float* __restrict__ C,
    int M, int N, int K, int wrapK, int ks, int mode,
    const float* __restrict__ A_log, const unsigned short* __restrict__ u_in,
    float* __restrict__ dA_out, unsigned short* __restrict__ du_out,
    unsigned short* __restrict__ Bbf, unsigned short* __restrict__ Cbf)
{
    __shared__ short As[128 * 64];
    __shared__ short Bs[64 * 64];
    const int tid  = threadIdx.x;
    const int lane = tid & 63, wid = tid >> 6;
    const int bm = blockIdx.y * 128, bn = blockIdx.x * 64;
    const int wm = wid * 32;
    const int fr = lane & 15;
    const int h  = fr & 7;                 // row parity for read-side swizzle
    const int tq = lane >> 4;              // 0..3 chunk group
    const int Kc = K / ks;
    const int k0beg = blockIdx.z * Kc;
    const int k0end = k0beg + Kc;
    float* Cz = C + (size_t)blockIdx.z * M * N;
    unsigned short* Czb = (unsigned short*)C + (size_t)blockIdx.z * M * N;

    f32x4 acc[2][4];
#pragma unroll
    for (int i = 0; i < 2; i++)
#pragma unroll
        for (int j = 0; j < 4; j++) acc[i][j] = (f32x4)0.f;

    for (int k0 = k0beg; k0 < k0end; k0 += 64) {
        const unsigned short* Asrc = (k0 < wrapK) ? Alo : Ahi;
        const int ka = (k0 < wrapK) ? k0 : k0 - wrapK;
        __syncthreads();
#pragma unroll
        for (int r = 0; r < 4; r++) {                    // A tile: 16 KB
            int o    = tid * 16 + r * 4096;
            int row  = o >> 7;
            int colb = ((((o >> 4) & 7) ^ (row & 7)) << 4);   // pre-swizzled source col
            int wb   = wid * 1024 + r * 4096;
            gload16((const char*)Asrc + ((size_t)(bm + row) * wrapK + ka) * 2 + colb,
                    (char*)As + wb);
        }
#pragma unroll
        for (int r = 0; r < 2; r++) {                    // B tile: 8 KB
            int o    = tid * 16 + r * 4096;
            int row  = o >> 7;
            int colb = ((((o >> 4) & 7) ^ (row & 7)) << 4);
            int wb   = wid * 1024 + r * 4096;
            gload16((const char*)B + ((size_t)(bn + row) * wrapK + ka) * 2 + colb,
                    (char*)Bs + wb);
        }
        __syncthreads();
#pragma unroll
        for (int kk = 0; kk < 2; kk++) {
            const int sc = ((kk * 4 + tq) ^ h) << 3;     // swizzled chunk (shorts)
            bf16x8 af[2], bfr[4];
#pragma unroll
            for (int i = 0; i < 2; i++)
                af[i] = *reinterpret_cast<const bf16x8*>(&As[(wm + i * 16 + fr) * 64 + sc]);
#pragma unroll
            for (int j = 0; j < 4; j++)
                bfr[j] = *reinterpret_cast<const bf16x8*>(&Bs[(j * 16 + fr) * 64 + sc]);
#pragma unroll
            for (int i = 0; i < 2; i++)
#pragma unroll
                for (int j = 0; j < 4; j++)
                    acc[i][j] = __builtin_amdgcn_mfma_f32_16x16x32_bf16(af[i], bfr[j], acc[i][j], 0, 0, 0);
        }
    }

    const int crow = (lane >> 4) * 4;
    if (mode == 2) {
        if (bn < 1024) {                                 // delta region -> dA, du
#pragma unroll
            for (int j = 0; j < 4; j++) {
                int d = bn + j * 16 + fr;
                float nAd = -expf(A_log[d]);
#pragma unroll
                for (int i = 0; i < 2; i++)
#pragma unroll
                    for (int r = 0; r < 4; r++) {
                        int m = bm + wm + i * 16 + crow + r;
                        float delta = sp_f(acc[i][j][r]);
                        size_t idx = (size_t)m * DI + d;
                        dA_out[idx] = expf(delta * nAd);
                        du_out[idx] = f2bf(delta * bf2f(u_in[idx]));
                    }
            }
        } else {                                         // B/C pack region
#pragma unroll
            for (int j = 0; j < 4; j++) {
                int cc = bn + j * 16 + fr;
#pragma unroll
                for (int i = 0; i < 2; i++)
#pragma unroll
                    for (int r = 0; r < 4; r++) {
                        int m = bm + wm + i * 16 + crow + r;
                        unsigned short v16 = f2bf(acc[i][j][r]);
                        if (cc < 1024 + NS) Bbf[(size_t)m * NS + cc - 1024]      = v16;
                        else                Cbf[(size_t)m * NS + cc - 1024 - NS] = v16;
                    }
            }
        }
    } else {
#pragma unroll
        for (int i = 0; i < 2; i++)
#pragma unroll
            for (int j = 0; j < 4; j++)
#pragma unroll
                for (int r = 0; r < 4; r++) {
                    size_t idx = (size_t)(bm + wm + i * 16 + crow + r) * N + (bn + j * 16 + fr);
                    if (mode == 1) Czb[idx] = f2bf(acc[i][j][r]);
                    else           Cz[idx]  = acc[i][j][r];
                }
    }
}

// ---------------------------------------------------------------------------
// Split-K reduce: out = p0+p1+p2+p3
// ---------------------------------------------------------------------------
__global__ __launch_bounds__(256) void reduce4(
    const float* __restrict__ p, float* __restrict__ out, int n)
{
    int i = (blockIdx.x * 256 + threadIdx.x) * 4;
    if (i >= n) return;
    float4 a = *(const float4*)(p + i);
    float4 b = *(const float4*)(p + n + i);
    float4 c = *(const float4*)(p + 2 * n + i);
    float4 d = *(const float4*)(p + 3 * n + i);
    float4 o;
    o.x = (a.x + b.x) + (c.x + d.x);
    o.y = (a.y + b.y) + (c.y + d.y);
    o.z = (a.z + b.z) + (c.z + d.z);
    o.w = (a.w + b.w) + (c.w + d.w);
    *(float4*)(out + i) = o;
}

// ---------------------------------------------------------------------------
// Conv (causal fwd + anti-causal bwd) + SiLU -> u; fused D*u and F=0.5*silu(z).
// ---------------------------------------------------------------------------
__global__ __launch_bounds__(256) void convk(
    const unsigned short* __restrict__ xzb, const float* __restrict__ cw,
    const float* __restrict__ cb, const float* __restrict__ Dvec,
    unsigned short* __restrict__ uc2b, unsigned short* __restrict__ ygb,
    unsigned short* __restrict__ Fbuf)
{
    int idx = blockIdx.x * 256 + threadIdx.x;
    int b   = idx >> 20;
    int rem = idx & ((LSEQ * DI) - 1);
    int tau = rem >> 10;
    int d   = rem & (DI - 1);

    const unsigned short* xc = xzb + (size_t)b * LSEQ * (2 * DI);
    float w0 = cw[d * 4 + 0], w1 = cw[d * 4 + 1], w2 = cw[d * 4 + 2], w3 = cw[d * 4 + 3];
    float bias = cb[d];
    float accf = bias, accb = bias;
    {
        int t0 = tau - 3, t1 = tau - 2, t2 = tau - 1;
        if (t0 >= 0) accf = fmaf(w0, bf2f(xc[(size_t)t0 * 2048 + d]), accf);
        if (t1 >= 0) accf = fmaf(w1, bf2f(xc[(size_t)t1 * 2048 + d]), accf);
        if (t2 >= 0) accf = fmaf(w2, bf2f(xc[(size_t)t2 * 2048 + d]), accf);
        accf = fmaf(w3, bf2f(xc[(size_t)tau * 2048 + d]), accf);
    }
    {
        int t0 = tau + 3, t1 = tau + 2, t2 = tau + 1;
        if (t0 < LSEQ) accb = fmaf(w0, bf2f(xc[(size_t)t0 * 2048 + d]), accb);
        if (t1 < LSEQ) accb = fmaf(w1, bf2f(xc[(size_t)t1 * 2048 + d]), accb);
        if (t2 < LSEQ) accb = fmaf(w2, bf2f(xc[(size_t)t2 * 2048 + d]), accb);
        accb = fmaf(w3, bf2f(xc[(size_t)tau * 2048 + d]), accb);
    }
    float uf = silu_f(accf), ub = silu_f(accb);
    size_t fi = ((size_t)b * LSEQ + tau) * DI + d;
    size_t bi = ((size_t)(2 + b) * LSEQ + tau) * DI + d;
    uc2b[fi] = f2bf(uf);
    uc2b[bi] = f2bf(ub);
    float Dd = Dvec[d];
    ygb[fi] = f2bf(Dd * uf);
    ygb[bi] = f2bf(Dd * ub);
    float z = bf2f(xc[(size_t)tau * 2048 + DI + d]);
    Fbuf[fi] = f2bf(0.5f * silu_f(z));
}

// ---------------------------------------------------------------------------
// Pass A: local chunk scan from zero; emits yloc (+Du, into ygb),
// g running product (bf16), chunk-end states (bf16), P.
// ---------------------------------------------------------------------------
__global__ __launch_bounds__(256) void passA(
    const float* __restrict__ dAbuf, const unsigned short* __restrict__ dub,
    const unsigned short* __restrict__ Bbf, const unsigned short* __restrict__ Cbf,
    unsigned short* __restrict__ ygb, unsigned short* __restrict__ gbuf,
    unsigned short* __restrict__ sEnd, float* __restrict__ Pbuf)
{
    const int dl   = threadIdx.x >> 2;
    const int nq   = threadIdx.x & 3;
    const int d0   = blockIdx.x * 64;
    const int d    = d0 + dl;
    const int c    = blockIdx.y;
    const int dirb = blockIdx.z;
    const int dir  = dirb >> 1;

    __shared__ float Bsh[TC][NS];
    __shared__ float Csh[TC][NS];
    __shared__ unsigned short gshY[TC][64];
    __shared__ unsigned short gshG[TC][64];

    for (int i = threadIdx.x * 4; i < TC * NS; i += 1024) {
        int tl = i >> 6, n = i & 63;
        int tau = dir ? (LSEQ - 1 - (c * TC + tl)) : (c * TC + tl);
        ushort4 vb = *(const ushort4*)&Bbf[((size_t)dirb * LSEQ + tau) * NS + n];
        ushort4 vc = *(const ushort4*)&Cbf[((size_t)dirb * LSEQ + tau) * NS + n];
        Bsh[tl][n+0] = bf2f(vb.x); Bsh[tl][n+1] = bf2f(vb.y);
        Bsh[tl][n+2] = bf2f(vb.z); Bsh[tl][n+3] = bf2f(vb.w);
        Csh[tl][n+0] = bf2f(vc.x); Csh[tl][n+1] = bf2f(vc.y);
        Csh[tl][n+2] = bf2f(vc.z); Csh[tl][n+3] = bf2f(vc.w);
    }
    __syncthreads();

    float s[16];
#pragma unroll
    for (int i = 0; i < 16; i++) s[i] = 0.f;
    float g_run = 1.f;

    int tau0 = dir ? (LSEQ - 1 - c * TC) : (c * TC);
    long stp = (dir ? -1L : 1L) * (long)DI;
    const float* pDA = dAbuf + ((size_t)dirb * LSEQ + tau0) * DI + d;
    const unsigned short* pDU = dub + ((size_t)dirb * LSEQ + tau0) * DI + d;
    const unsigned short* pY  = ygb + ((size_t)dirb * LSEQ + tau0) * DI + d;

    float dA = *pDA, du = bf2f(*pDU), Du = bf2f(*pY);
    for (int tl = 0; tl < TC; tl++) {
        float dA_c = dA, du_c = du, Du_c = Du;
        if (tl + 1 < TC) {                        // 1-deep register prefetch
            pDA += stp; pDU += stp; pY += stp;
            dA = *pDA; du = bf2f(*pDU); Du = bf2f(*pY);
        }
        g_run *= dA_c;
        float ydot = 0.f;
        const float4* brow = (const float4*)&Bsh[tl][nq * 16];
        const float4* crow = (const float4*)&Csh[tl][nq * 16];
#pragma unroll
        for (int q = 0; q < 4; q++) {
            float4 bv = brow[q];
            float4 cv = crow[q];
            float s0 = fmaf(du_c, bv.x, dA_c * s[4*q+0]); s[4*q+0] = s0; ydot = fmaf(cv.x, s0, ydot);
            float s1 = fmaf(du_c, bv.y, dA_c * s[4*q+1]); s[4*q+1] = s1; ydot = fmaf(cv.y, s1, ydot);
            float s2 = fmaf(du_c, bv.z, dA_c * s[4*q+2]); s[4*q+2] = s2; ydot = fmaf(cv.z, s2, ydot);
            float s3 = fmaf(du_c, bv.w, dA_c * s[4*q+3]); s[4*q+3] = s3; ydot = fmaf(cv.w, s3, ydot);
        }
        ydot += __shfl_xor(ydot, 1);
        ydot += __shfl_xor(ydot, 2);
        if (nq == 0) {
            gshY[tl][dl] = f2bf(Du_c + ydot);
            gshG[tl][dl] = f2bf(g_run);
        }
    }
    __syncthreads();

    size_t base = (((size_t)dirb * NC + c) * DI + d) * NS + nq * 16;
#pragma unroll
    for (int q = 0; q < 4; q++) {
        ushort4 v;
        v.x = f2bf(s[4*q+0]); v.y = f2bf(s[4*q+1]);
        v.z = f2bf(s[4*q+2]); v.w = f2bf(s[4*q+3]);
        *(ushort4*)&sEnd[base + q * 4] = v;
    }
    if (nq == 0) Pbuf[((size_t)dirb * NC + c) * DI + d] = g_run;

    for (int i = threadIdx.x * 4; i < TC * 64; i += 1024) {
        int tl = i >> 6, col = i & 63;
        int tau = dir ? (LSEQ - 1 - (c * TC + tl)) : (c * TC + tl);
        *(ushort4*)&ygb[((size_t)dirb * LSEQ + tau) * DI + d0 + col]  = *(const ushort4*)&gshY[tl][col];
        *(ushort4*)&gbuf[((size_t)dirb * LSEQ + tau) * DI + d0 + col] = *(const ushort4*)&gshG[tl][col];
    }
}

// ---------------------------------------------------------------------------
// Pass B: combine chunk states; sEnd bf16 in, sInitB bf16 out (f32 running).
// ---------------------------------------------------------------------------
__global__ __launch_bounds__(256) void passB(
    const unsigned short* __restrict__ sEnd, const float* __restrict__ Pbuf,
    unsigned short* __restrict__ sInitB)
{
    const int fl   = blockIdx.x * 256 + threadIdx.x;   // d*64 + n
    const int dirb = blockIdx.y;
    const int d    = fl >> 6;
    float run = 0.f;
    for (int c = 0; c < NC; c++) {
        size_t idx = ((size_t)(dirb * NC + c)) * (DI * NS) + fl;
        float tmp = bf2f(sEnd[idx]);
        sInitB[idx] = f2bf(run);
        float P = Pbuf[((size_t)dirb * NC + c) * DI + d];
        run = fmaf(P, run, tmp);
    }
}

// ---------------------------------------------------------------------------
// corrK: per (dirb, chunk, 128-d group): corr = C_chunk[64,64] @ s_init[d,n]^T
// via MFMA (padded LDS: 144-B stride -> 2-way max, free), then
// out = F*(yloc + g*corr) -> ygb in place.
// ---------------------------------------------------------------------------
__global__ __launch_bounds__(256) void corrK(
    const unsigned short* __restrict__ Cbf, const unsigned short* __restrict__ sInitB,
    const unsigned short* __restrict__ gbuf, const unsigned short* __restrict__ Fbuf,
    unsigned short* __restrict__ ygb)
{
    const int tid  = threadIdx.x;
    const int lane = tid & 63, wid = tid >> 6;
    const int d0   = blockIdx.x * 128;
    const int c    = blockIdx.y;
    const int dirb = blockIdx.z;
    const int dir  = dirb >> 1;
    const int b    = dirb & 1;
    const int fr = lane & 15, fk = (lane >> 4) * 8;
    const int wm = (wid >> 1) * 32, wn = (wid & 1) * 64;

    __shared__ short Cs[64 * LDP];
    __shared__ short Ss[128 * LDP];
    __shared__ float corrS[64 * 128];

    for (int i = tid * 4; i < 64 * 64; i += 1024) {
        int tl = i >> 6, n = i & 63;
        int tau = dir ? (LSEQ - 1 - (c * TC + tl)) : (c * TC + tl);
        *(ushort4*)&Cs[tl * LDP + n] = *(const ushort4*)&Cbf[((size_t)dirb * LSEQ + tau) * NS + n];
    }
    for (int i = tid * 4; i < 128 * 64; i += 1024) {
        int r = i >> 6, n = i & 63;
        *(ushort4*)&Ss[r * LDP + n] =
            *(const ushort4*)&sInitB[(((size_t)dirb * NC + c) * DI + d0 + r) * NS + n];
    }
    __syncthreads();

    f32x4 acc[2][4];
#pragma unroll
    for (int i = 0; i < 2; i++)
#pragma unroll
        for (int j = 0; j < 4; j++) acc[i][j] = (f32x4)0.f;

#pragma unroll
    for (int kk = 0; kk < 2; kk++) {
        bf16x8 af[2], bfr[4];
#pragma unroll
        for (int i = 0; i < 2; i++)
            af[i] = *reinterpret_cast<const bf16x8*>(&Cs[(wm + i * 16 + fr) * LDP + kk * 32 + fk]);
#pragma unroll
        for (int j = 0; j < 4; j++)
            bfr[j] = *reinterpret_cast<const bf16x8*>(&Ss[(wn + j * 16 + fr) * LDP + kk * 32 + fk]);
#pragma unroll
        for (int i = 0; i < 2; i++)
#pragma unroll
            for (int j = 0; j < 4; j++)
                acc[i][j] = __builtin_amdgcn_mfma_f32_16x16x32_bf16(af[i], bfr[j], acc[i][j], 0, 0, 0);
    }

    const int crow = (lane >> 4) * 4;
#pragma unroll
    for (int i = 0; i < 2; i++)
#pragma unroll
        for (int j = 0; j < 4; j++)
#pragma unroll
            for (int r = 0; r < 4; r++)
                corrS[(wm + i * 16 + crow + r) * 128 + (wn + j * 16 + fr)] = acc[i][j][r];
    __syncthreads();

    for (int i = tid * 4; i < 64 * 128; i += 1024) {
        int tl = i >> 7, col = i & 127;
        int tau = dir ? (LSEQ - 1 - (c * TC + tl)) : (c * TC + tl);
        size_t gi = ((size_t)dirb * LSEQ + tau) * DI + d0 + col;
        size_t fi = ((size_t)b    * LSEQ + tau) * DI + d0 + col;
        ushort4 g4 = *(const ushort4*)&gbuf[gi];
        ushort4 y4 = *(const ushort4*)&ygb[gi];
        ushort4 F4 = *(const ushort4*)&Fbuf[fi];
        const float* cr = &corrS[tl * 128 + col];
        ushort4 o;
        o.x = f2bf(bf2f(F4.x) * fmaf(bf2f(g4.x), cr[0], bf2f(y4.x)));
        o.y = f2bf(bf2f(F4.y) * fmaf(bf2f(g4.y), cr[1], bf2f(y4.y)));
        o.z = f2bf(bf2f(F4.z) * fmaf(bf2f(g4.z), cr[2], bf2f(y4.z)));
        o.w = f2bf(bf2f(F4.w) * fmaf(bf2f(g4.w), cr[3], bf2f(y4.w)));
        *(ushort4*)&ygb[gi] = o;
    }
}

// ---------------------------------------------------------------------------
extern "C" void kernel_launch(void* const* d_in, const int* in_sizes, int n_in,
                              void* d_out, int out_size, void* d_ws, size_t ws_size,
                              hipStream_t stream)
{
    const float* x      = (const float*)d_in[0];
    const float* W_in   = (const float*)d_in[1];
    const float* conv_w = (const float*)d_in[2];
    const float* conv_b = (const float*)d_in[3];
    const float* W_xprj = (const float*)d_in[4];
    const float* A_log  = (const float*)d_in[5];
    const float* Dvec   = (const float*)d_in[6];
    const float* W_out  = (const float*)d_in[7];
    float* out = (float*)d_out;

    // workspace ~65.3 MB; aliases are dead-before-overwrite (stream order):
    float* ws = (float*)d_ws;
    float*          dAbuf = ws;                                   // [4096][1024] f32, 16.8 MB
    unsigned short* uc2b  = (unsigned short*)(ws + 4194304);      // u, 8.4 MB
    unsigned short* xzb   = uc2b + 4194304;                       // 8.4 MB
    unsigned short* dub   = xzb  + 4194304;                       // du, 8.4 MB
    unsigned short* ygb   = dub  + 4194304;                       // Du->yloc->g, 8.4 MB
    unsigned short* gbuf  = ygb  + 4194304;                       // 8.4 MB
    unsigned short* Fbuf  = gbuf + 4194304;                       // 4.2 MB
    unsigned short* Bbf   = Fbuf + 2097152;                       // 0.5 MB
    unsigned short* Cbf   = Bbf  + 262144;                        // 0.5 MB
    unsigned short* wob   = Cbf  + 262144;                        // 1.0 MB
    float*          Pbuf  = (float*)(wob + 524288);               // 0.26 MB
    // aliases:
    unsigned short* xb     = (unsigned short*)dAbuf;              // dead after gemm1 (dAbuf written by gemm2)
    unsigned short* winb   = xb + 1048576;                        // dead after gemm1
    unsigned short* wxb    = gbuf;                                // dead after gemm2 (gbuf written in passA)
    unsigned short* sEnd   = xzb;                                 // xzb dead after convk
    unsigned short* sInitB = uc2b;                                // u dead after gemm2 epilogue
    float*          gpart  = dAbuf;                               // dAbuf dead after passA (== 4x2048x512 f32)

    // 1) bf16 casts
    castall<<<3712, 256, 0, stream>>>(x, W_in, W_xprj, W_out, xb, winb, wxb, wob);

    // 2) xz = x @ W_in^T -> bf16 (M=2048, N=2048, K=512) — 512 blocks
    gemm128<<<dim3(32, 16), 256, 0, stream>>>(xb, nullptr, winb, (float*)xzb,
        B_ * LSEQ, 2 * DI, DM, DM, 1, 1, nullptr, nullptr, nullptr, nullptr, nullptr, nullptr);

    // 3) conv both dirs + SiLU -> u; fused D*u and F=0.5*silu(z)
    convk<<<(B_ * LSEQ * DI) / 256, 256, 0, stream>>>(xzb, conv_w, conv_b, Dvec, uc2b, ygb, Fbuf);

    // 4) proj GEMM with fused prep epilogue: dA/du + packed B,C — 576 blocks
    gemm128<<<dim3(18, 32), 256, 0, stream>>>(uc2b, nullptr, wxb, nullptr,
        4 * LSEQ, DI + 2 * NS, DI, DI, 1, 2, A_log, uc2b, dAbuf, dub, Bbf, Cbf);

    // 5) pass A: local scans + yloc + g
    passA<<<dim3(16, NC, 4), 256, 0, stream>>>(dAbuf, dub, Bbf, Cbf, ygb, gbuf, sEnd, Pbuf);

    // 6) pass B: chunk-state combine -> bf16 s_init
    passB<<<dim3(256, 4), 256, 0, stream>>>(sEnd, Pbuf, sInitB);

    // 7) corrK: MFMA correction + epilogue -> final g values in ygb
    corrK<<<dim3(8, NC, 4), 256, 0, stream>>>(Cbf, sInitB, gbuf, Fbuf, ygb);

    // 8) out = [gf | gb] @ [W|W]^T via K-concat (K=2048, wrapK=1024), split-K=4 — 512 blocks
    gemm128<<<dim3(8, 16, 4), 256, 0, stream>>>(ygb, ygb + (size_t)2 * LSEQ * DI, wob, gpart,
        B_ * LSEQ, DM, 2 * DI, DI, 4, 0, nullptr, nullptr, nullptr, nullptr, nullptr, nullptr);
    reduce4<<<1024, 256, 0, stream>>>(gpart, out, B_ * LSEQ * DM);
}

// Round 11
// 144.311 us; speedup vs baseline: 3.7586x; 1.0642x over previous
//
#include <hip/hip_runtime.h>
#include <math.h>

#define B_    2
#define LSEQ  1024
#define DM    512
#define DI    1024
#define NS    64
#define TC    64
#define NC    (LSEQ/TC)     // 16
#define LDP   72            // padded stride for corrK tiles only

typedef __bf16 bf16x8 __attribute__((ext_vector_type(8)));
typedef float  f32x4  __attribute__((ext_vector_type(4)));

__device__ __forceinline__ float sp_f(float x)   { return fmaxf(x, 0.f) + log1pf(expf(-fabsf(x))); }
__device__ __forceinline__ float silu_f(float x) { return x / (1.f + expf(-x)); }
__device__ __forceinline__ unsigned short f2bf(float f) {
    unsigned int u = __float_as_uint(f);
    u += 0x7FFF + ((u >> 16) & 1);          // RNE
    return (unsigned short)(u >> 16);
}
__device__ __forceinline__ float bf2f(unsigned short h) {
    return __uint_as_float(((unsigned int)h) << 16);
}
// async global->LDS, 16 B per lane; LDS dest = wave-uniform base + lane*16
__device__ __forceinline__ void gload16(const void* g, void* l) {
    __builtin_amdgcn_global_load_lds(
        (const __attribute__((address_space(1))) unsigned int*)g,
        (__attribute__((address_space(3))) unsigned int*)l, 16, 0, 0);
}

// ---------------------------------------------------------------------------
// All 4 f32->bf16 casts in one launch (3712 blocks exactly).
// ---------------------------------------------------------------------------
__global__ __launch_bounds__(256) void castall(
    const float* __restrict__ x, const float* __restrict__ W_in,
    const float* __restrict__ W_xproj, const float* __restrict__ W_out,
    unsigned short* __restrict__ xb, unsigned short* __restrict__ winb,
    unsigned short* __restrict__ wxb, unsigned short* __restrict__ wob)
{
    int i = (blockIdx.x * 256 + threadIdx.x) * 4;
    const float* s; unsigned short* dst; int off;
    if (i < 1048576)      { s = x;       dst = xb;   off = i; }
    else if (i < 2097152) { s = W_in;    dst = winb; off = i - 1048576; }
    else if (i < 3276800) { s = W_xproj; dst = wxb;  off = i - 2097152; }
    else                  { s = W_out;   dst = wob;  off = i - 3276800; }
    float4 v = *(const float4*)(s + off);
    ushort4 o;
    o.x = f2bf(v.x); o.y = f2bf(v.y); o.z = f2bf(v.z); o.w = f2bf(v.w);
    *(ushort4*)(dst + off) = o;
}

// ---------------------------------------------------------------------------
// bf16 MFMA GEMM: 128x64 tile, BK=64, 4 waves each 32x64.
// R11: 2-phase double-buffered K-loop (STAGE(next) issued BEFORE COMPUTE(cur),
// one __syncthreads per step -> stage HBM latency hides under MFMA), distinct
// static LDS buffers so waitcnt pass can disambiguate; XCD-aware block swizzle
// (grids %8==0); both-sides XOR bank swizzle from R10 (conflicts == 0).
// K-concat: for k0 >= wrapK, A source switches Alo->Ahi; k-index rebased.
// mode 0: f32 C. mode 1: bf16 C. mode 2: fused Mamba prep epilogue
//   (cols<1024: packed u32 (dA bf16 | du bf16<<16); cols>=1024: pack B/C).
// ---------------------------------------------------------------------------
__global__ __launch_bounds__(256) void gemm128(
    const unsigned short* __restrict__ Alo, const unsigned short* __restrict__ Ahi,
    const unsigned short* __restrict__ B, float* __restrict__ C,
    int M, int N, int K, int wrapK, int ks, int mode,
    const float* __restrict__ A_log, const unsigned short* __restrict__ u_in,
    unsigned* __restrict__ ddu_out,
    unsigned short* __restrict__ Bbf, unsigned short* __restrict__ Cbf)
{
    __shared__ short As0[128 * 64];
    __shared__ short Bs0[64 * 64];
    __shared__ short As1[128 * 64];
    __shared__ short Bs1[64 * 64];
    const int tid  = threadIdx.x;
    const int lane = tid & 63, wid = tid >> 6;

    // XCD-aware swizzle: contiguous work chunk per XCD (grid.x*grid.y % 8 == 0)
    const int gx = gridDim.x;
    int id  = blockIdx.y * gx + blockIdx.x;
    int q   = (gx * gridDim.y) >> 3;
    int swz = (id & 7) * q + (id >> 3);
    const int bm = (swz / gx) * 128, bn = (swz % gx) * 64;

    const int wm = wid * 32;
    const int fr = lane & 15;
    const int h  = fr & 7;                 // read-side bank swizzle
    const int tq = lane >> 4;
    const int Kc = K / ks;
    const int k0beg = blockIdx.z * Kc;
    const int k0end = k0beg + Kc;
    float* Cz = C + (size_t)blockIdx.z * M * N;
    unsigned short* Czb = (unsigned short*)C + (size_t)blockIdx.z * M * N;

    f32x4 acc[2][4];
#pragma unroll
    for (int i = 0; i < 2; i++)
#pragma unroll
        for (int j = 0; j < 4; j++) acc[i][j] = (f32x4)0.f;

    auto STAGE = [&](short* Adst, short* Bdst, int kk0) {
        const unsigned short* Asrc = (kk0 < wrapK) ? Alo : Ahi;
        const int ka = (kk0 < wrapK) ? kk0 : kk0 - wrapK;
#pragma unroll
        for (int r = 0; r < 4; r++) {                    // A tile: 16 KB
            int o    = tid * 16 + r * 4096;
            int row  = o >> 7;
            int colb = ((((o >> 4) & 7) ^ (row & 7)) << 4);   // pre-swizzled col
            int wb   = wid * 1024 + r * 4096;
            gload16((const char*)Asrc + ((size_t)(bm + row) * wrapK + ka) * 2 + colb,
                    (char*)Adst + wb);
        }
#pragma unroll
        for (int r = 0; r < 2; r++) {                    // B tile: 8 KB
            int o    = tid * 16 + r * 4096;
            int row  = o >> 7;
            int colb = ((((o >> 4) & 7) ^ (row & 7)) << 4);
            int wb   = wid * 1024 + r * 4096;
            gload16((const char*)B + ((size_t)(bn + row) * wrapK + ka) * 2 + colb,
                    (char*)Bdst + wb);
        }
    };
    auto COMPUTE = [&](const short* Asrc_l, const short* Bsrc_l) {
#pragma unroll
        for (int kk = 0; kk < 2; kk++) {
            const int sc = ((kk * 4 + tq) ^ h) << 3;     // swizzled chunk (shorts)
            bf16x8 af[2], bfr[4];
#pragma unroll
            for (int i = 0; i < 2; i++)
                af[i] = *reinterpret_cast<const bf16x8*>(&Asrc_l[(wm + i * 16 + fr) * 64 + sc]);
#pragma unroll
            for (int j = 0; j < 4; j++)
                bfr[j] = *reinterpret_cast<const bf16x8*>(&Bsrc_l[(j * 16 + fr) * 64 + sc]);
#pragma unroll
            for (int i = 0; i < 2; i++)
#pragma unroll
                for (int j = 0; j < 4; j++)
                    acc[i][j] = __builtin_amdgcn_mfma_f32_16x16x32_bf16(af[i], bfr[j], acc[i][j], 0, 0, 0);
        }
    };

    // 2-phase pipeline, unrolled x2 with distinct buffers
    STAGE(As0, Bs0, k0beg);
    __syncthreads();
    for (int k0 = k0beg; k0 < k0end; k0 += 128) {
        if (k0 + 64 < k0end) STAGE(As1, Bs1, k0 + 64);
        COMPUTE(As0, Bs0);
        __syncthreads();
        if (k0 + 64 < k0end) {
            if (k0 + 128 < k0end) STAGE(As0, Bs0, k0 + 128);
            COMPUTE(As1, Bs1);
            __syncthreads();
        }
    }

    const int crow = (lane >> 4) * 4;
    if (mode == 2) {
        if (bn < 1024) {                                 // delta region -> packed (dA|du)
#pragma unroll
            for (int j = 0; j < 4; j++) {
                int d = bn + j * 16 + fr;
                float nAd = -expf(A_log[d]);
#pragma unroll
                for (int i = 0; i < 2; i++)
#pragma unroll
                    for (int r = 0; r < 4; r++) {
                        int m = bm + wm + i * 16 + crow + r;
                        float delta = sp_f(acc[i][j][r]);
                        size_t idx = (size_t)m * DI + d;
                        float dA = expf(delta * nAd);
                        float du = delta * bf2f(u_in[idx]);
                        ddu_out[idx] = (unsigned)f2bf(dA) | ((unsigned)f2bf(du) << 16);
                    }
            }
        } else {                                         // B/C pack region
#pragma unroll
            for (int j = 0; j < 4; j++) {
                int cc = bn + j * 16 + fr;
#pragma unroll
                for (int i = 0; i < 2; i++)
#pragma unroll
                    for (int r = 0; r < 4; r++) {
                        int m = bm + wm + i * 16 + crow + r;
                        unsigned short v16 = f2bf(acc[i][j][r]);
                        if (cc < 1024 + NS) Bbf[(size_t)m * NS + cc - 1024]      = v16;
                        else                Cbf[(size_t)m * NS + cc - 1024 - NS] = v16;
                    }
            }
        }
    } else {
#pragma unroll
        for (int i = 0; i < 2; i++)
#pragma unroll
            for (int j = 0; j < 4; j++)
#pragma unroll
                for (int r = 0; r < 4; r++) {
                    size_t idx = (size_t)(bm + wm + i * 16 + crow + r) * N + (bn + j * 16 + fr);
                    if (mode == 1) Czb[idx] = f2bf(acc[i][j][r]);
                    else           Cz[idx]  = acc[i][j][r];
                }
    }
}

// ---------------------------------------------------------------------------
// Split-K reduce: out = p0+p1+p2+p3
// ---------------------------------------------------------------------------
__global__ __launch_bounds__(256) void reduce4(
    const float* __restrict__ p, float* __restrict__ out, int n)
{
    int i = (blockIdx.x * 256 + threadIdx.x) * 4;
    if (i >= n) return;
    float4 a = *(const float4*)(p + i);
    float4 b = *(const float4*)(p + n + i);
    float4 c = *(const float4*)(p + 2 * n + i);
    float4 d = *(const float4*)(p + 3 * n + i);
    float4 o;
    o.x = (a.x + b.x) + (c.x + d.x);
    o.y = (a.y + b.y) + (c.y + d.y);
    o.z = (a.z + b.z) + (c.z + d.z);
    o.w = (a.w + b.w) + (c.w + d.w);
    *(float4*)(out + i) = o;
}

// ---------------------------------------------------------------------------
// Conv (causal fwd + anti-causal bwd) + SiLU -> u; fused D*u and F=0.5*silu(z).
// ---------------------------------------------------------------------------
__global__ __launch_bounds__(256) void convk(
    const unsigned short* __restrict__ xzb, const float* __restrict__ cw,
    const float* __restrict__ cb, const float* __restrict__ Dvec,
    unsigned short* __restrict__ uc2b, unsigned short* __restrict__ ygb,
    unsigned short* __restrict__ Fbuf)
{
    int idx = blockIdx.x * 256 + threadIdx.x;
    int b   = idx >> 20;
    int rem = idx & ((LSEQ * DI) - 1);
    int tau = rem >> 10;
    int d   = rem & (DI - 1);

    const unsigned short* xc = xzb + (size_t)b * LSEQ * (2 * DI);
    float w0 = cw[d * 4 + 0], w1 = cw[d * 4 + 1], w2 = cw[d * 4 + 2], w3 = cw[d * 4 + 3];
    float bias = cb[d];
    float accf = bias, accb = bias;
    {
        int t0 = tau - 3, t1 = tau - 2, t2 = tau - 1;
        if (t0 >= 0) accf = fmaf(w0, bf2f(xc[(size_t)t0 * 2048 + d]), accf);
        if (t1 >= 0) accf = fmaf(w1, bf2f(xc[(size_t)t1 * 2048 + d]), accf);
        if (t2 >= 0) accf = fmaf(w2, bf2f(xc[(size_t)t2 * 2048 + d]), accf);
        accf = fmaf(w3, bf2f(xc[(size_t)tau * 2048 + d]), accf);
    }
    {
        int t0 = tau + 3, t1 = tau + 2, t2 = tau + 1;
        if (t0 < LSEQ) accb = fmaf(w0, bf2f(xc[(size_t)t0 * 2048 + d]), accb);
        if (t1 < LSEQ) accb = fmaf(w1, bf2f(xc[(size_t)t1 * 2048 + d]), accb);
        if (t2 < LSEQ) accb = fmaf(w2, bf2f(xc[(size_t)t2 * 2048 + d]), accb);
        accb = fmaf(w3, bf2f(xc[(size_t)tau * 2048 + d]), accb);
    }
    float uf = silu_f(accf), ub = silu_f(accb);
    size_t fi = ((size_t)b * LSEQ + tau) * DI + d;
    size_t bi = ((size_t)(2 + b) * LSEQ + tau) * DI + d;
    uc2b[fi] = f2bf(uf);
    uc2b[bi] = f2bf(ub);
    float Dd = Dvec[d];
    ygb[fi] = f2bf(Dd * uf);
    ygb[bi] = f2bf(Dd * ub);
    float z = bf2f(xc[(size_t)tau * 2048 + DI + d]);
    Fbuf[fi] = f2bf(0.5f * silu_f(z));
}

// ---------------------------------------------------------------------------
// Pass A: local chunk scan from zero; reads PACKED ddu (dA|du u32) + ygb (Du);
// emits yloc (+Du, into ygb), g (bf16), chunk-end states (bf16), P.
// ---------------------------------------------------------------------------
__global__ __launch_bounds__(256) void passA(
    const unsigned* __restrict__ ddu,
    const unsigned short* __restrict__ Bbf, const unsigned short* __restrict__ Cbf,
    unsigned short* __restrict__ ygb, unsigned short* __restrict__ gbuf,
    unsigned short* __restrict__ sEnd, float* __restrict__ Pbuf)
{
    const int dl   = threadIdx.x >> 2;
    const int nq   = threadIdx.x & 3;
    const int d0   = blockIdx.x * 64;
    const int d    = d0 + dl;
    const int c    = blockIdx.y;
    const int dirb = blockIdx.z;
    const int dir  = dirb >> 1;

    __shared__ float Bsh[TC][NS];
    __shared__ float Csh[TC][NS];
    __shared__ unsigned short gshY[TC][64];
    __shared__ unsigned short gshG[TC][64];

    for (int i = threadIdx.x * 4; i < TC * NS; i += 1024) {
        int tl = i >> 6, n = i & 63;
        int tau = dir ? (LSEQ - 1 - (c * TC + tl)) : (c * TC + tl);
        ushort4 vb = *(const ushort4*)&Bbf[((size_t)dirb * LSEQ + tau) * NS + n];
        ushort4 vc = *(const ushort4*)&Cbf[((size_t)dirb * LSEQ + tau) * NS + n];
        Bsh[tl][n+0] = bf2f(vb.x); Bsh[tl][n+1] = bf2f(vb.y);
        Bsh[tl][n+2] = bf2f(vb.z); Bsh[tl][n+3] = bf2f(vb.w);
        Csh[tl][n+0] = bf2f(vc.x); Csh[tl][n+1] = bf2f(vc.y);
        Csh[tl][n+2] = bf2f(vc.z); Csh[tl][n+3] = bf2f(vc.w);
    }
    __syncthreads();

    float s[16];
#pragma unroll
    for (int i = 0; i < 16; i++) s[i] = 0.f;
    float g_run = 1.f;

    int tau0 = dir ? (LSEQ - 1 - c * TC) : (c * TC);
    long stp = (dir ? -1L : 1L) * (long)DI;
    const unsigned* pW = ddu + ((size_t)dirb * LSEQ + tau0) * DI + d;
    const unsigned short* pY = ygb + ((size_t)dirb * LSEQ + tau0) * DI + d;

    unsigned w = *pW;
    float Du = bf2f(*pY);
    for (int tl = 0; tl < TC; tl++) {
        unsigned w_c = w;
        float Du_c = Du;
        if (tl + 1 < TC) {                        // 1-deep register prefetch
            pW += stp; pY += stp;
            w = *pW; Du = bf2f(*pY);
        }
        float dA_c = bf2f((unsigned short)(w_c & 0xffff));
        float du_c = bf2f((unsigned short)(w_c >> 16));
        g_run *= dA_c;
        float ydot = 0.f;
        const float4* brow = (const float4*)&Bsh[tl][nq * 16];
        const float4* crow = (const float4*)&Csh[tl][nq * 16];
#pragma unroll
        for (int q = 0; q < 4; q++) {
            float4 bv = brow[q];
            float4 cv = crow[q];
            float s0 = fmaf(du_c, bv.x, dA_c * s[4*q+0]); s[4*q+0] = s0; ydot = fmaf(cv.x, s0, ydot);
            float s1 = fmaf(du_c, bv.y, dA_c * s[4*q+1]); s[4*q+1] = s1; ydot = fmaf(cv.y, s1, ydot);
            float s2 = fmaf(du_c, bv.z, dA_c * s[4*q+2]); s[4*q+2] = s2; ydot = fmaf(cv.z, s2, ydot);
            float s3 = fmaf(du_c, bv.w, dA_c * s[4*q+3]); s[4*q+3] = s3; ydot = fmaf(cv.w, s3, ydot);
        }
        ydot += __shfl_xor(ydot, 1);
        ydot += __shfl_xor(ydot, 2);
        if (nq == 0) {
            gshY[tl][dl] = f2bf(Du_c + ydot);
            gshG[tl][dl] = f2bf(g_run);
        }
    }
    __syncthreads();

    size_t base = (((size_t)dirb * NC + c) * DI + d) * NS + nq * 16;
#pragma unroll
    for (int q = 0; q < 4; q++) {
        ushort4 v;
        v.x = f2bf(s[4*q+0]); v.y = f2bf(s[4*q+1]);
        v.z = f2bf(s[4*q+2]); v.w = f2bf(s[4*q+3]);
        *(ushort4*)&sEnd[base + q * 4] = v;
    }
    if (nq == 0) Pbuf[((size_t)dirb * NC + c) * DI + d] = g_run;

    for (int i = threadIdx.x * 4; i < TC * 64; i += 1024) {
        int tl = i >> 6, col = i & 63;
        int tau = dir ? (LSEQ - 1 - (c * TC + tl)) : (c * TC + tl);
        *(ushort4*)&ygb[((size_t)dirb * LSEQ + tau) * DI + d0 + col]  = *(const ushort4*)&gshY[tl][col];
        *(ushort4*)&gbuf[((size_t)dirb * LSEQ + tau) * DI + d0 + col] = *(const ushort4*)&gshG[tl][col];
    }
}

// ---------------------------------------------------------------------------
// Pass B: combine chunk states; sEnd bf16 in, sInitB bf16 out (f32 running).
// ---------------------------------------------------------------------------
__global__ __launch_bounds__(256) void passB(
    const unsigned short* __restrict__ sEnd, const float* __restrict__ Pbuf,
    unsigned short* __restrict__ sInitB)
{
    const int fl   = blockIdx.x * 256 + threadIdx.x;   // d*64 + n
    const int dirb = blockIdx.y;
    const int d    = fl >> 6;
    float run = 0.f;
    for (int c = 0; c < NC; c++) {
        size_t idx = ((size_t)(dirb * NC + c)) * (DI * NS) + fl;
        float tmp = bf2f(sEnd[idx]);
        sInitB[idx] = f2bf(run);
        float P = Pbuf[((size_t)dirb * NC + c) * DI + d];
        run = fmaf(P, run, tmp);
    }
}

// ---------------------------------------------------------------------------
// corrK: per (dirb, chunk, 128-d group): corr = C_chunk[64,64] @ s_init[d,n]^T
// via MFMA (padded LDS: 144-B stride, conflict-free), then
// out = F*(yloc + g*corr) -> ygb in place.
// ---------------------------------------------------------------------------
__global__ __launch_bounds__(256) void corrK(
    const unsigned short* __restrict__ Cbf, const unsigned short* __restrict__ sInitB,
    const unsigned short* __restrict__ gbuf, const unsigned short* __restrict__ Fbuf,
    unsigned short* __restrict__ ygb)
{
    const int tid  = threadIdx.x;
    const int lane = tid & 63, wid = tid >> 6;
    const int d0   = blockIdx.x * 128;
    const int c    = blockIdx.y;
    const int dirb = blockIdx.z;
    const int dir  = dirb >> 1;
    const int b    = dirb & 1;
    const int fr = lane & 15, fk = (lane >> 4) * 8;
    const int wm = (wid >> 1) * 32, wn = (wid & 1) * 64;

    __shared__ short Cs[64 * LDP];
    __shared__ short Ss[128 * LDP];
    __shared__ float corrS[64 * 128];

    for (int i = tid * 4; i < 64 * 64; i += 1024) {
        int tl = i >> 6, n = i & 63;
        int tau = dir ? (LSEQ - 1 - (c * TC + tl)) : (c * TC + tl);
        *(ushort4*)&Cs[tl * LDP + n] = *(const ushort4*)&Cbf[((size_t)dirb * LSEQ + tau) * NS + n];
    }
    for (int i = tid * 4; i < 128 * 64; i += 1024) {
        int r = i >> 6, n = i & 63;
        *(ushort4*)&Ss[r * LDP + n] =
            *(const ushort4*)&sInitB[(((size_t)dirb * NC + c) * DI + d0 + r) * NS + n];
    }
    __syncthreads();

    f32x4 acc[2][4];
#pragma unroll
    for (int i = 0; i < 2; i++)
#pragma unroll
        for (int j = 0; j < 4; j++) acc[i][j] = (f32x4)0.f;

#pragma unroll
    for (int kk = 0; kk < 2; kk++) {
        bf16x8 af[2], bfr[4];
#pragma unroll
        for (int i = 0; i < 2; i++)
            af[i] = *reinterpret_cast<const bf16x8*>(&Cs[(wm + i * 16 + fr) * LDP + kk * 32 + fk]);
#pragma unroll
        for (int j = 0; j < 4; j++)
            bfr[j] = *reinterpret_cast<const bf16x8*>(&Ss[(wn + j * 16 + fr) * LDP + kk * 32 + fk]);
#pragma unroll
        for (int i = 0; i < 2; i++)
#pragma unroll
            for (int j = 0; j < 4; j++)
                acc[i][j] = __builtin_amdgcn_mfma_f32_16x16x32_bf16(af[i], bfr[j], acc[i][j], 0, 0, 0);
    }

    const int crow = (lane >> 4) * 4;
#pragma unroll
    for (int i = 0; i < 2; i++)
#pragma unroll
        for (int j = 0; j < 4; j++)
#pragma unroll
            for (int r = 0; r < 4; r++)
                corrS[(wm + i * 16 + crow + r) * 128 + (wn + j * 16 + fr)] = acc[i][j][r];
    __syncthreads();

    for (int i = tid * 4; i < 64 * 128; i += 1024) {
        int tl = i >> 7, col = i & 127;
        int tau = dir ? (LSEQ - 1 - (c * TC + tl)) : (c * TC + tl);
        size_t gi = ((size_t)dirb * LSEQ + tau) * DI + d0 + col;
        size_t fi = ((size_t)b    * LSEQ + tau) * DI + d0 + col;
        ushort4 g4 = *(const ushort4*)&gbuf[gi];
        ushort4 y4 = *(const ushort4*)&ygb[gi];
        ushort4 F4 = *(const ushort4*)&Fbuf[fi];
        const float* cr = &corrS[tl * 128 + col];
        ushort4 o;
        o.x = f2bf(bf2f(F4.x) * fmaf(bf2f(g4.x), cr[0], bf2f(y4.x)));
        o.y = f2bf(bf2f(F4.y) * fmaf(bf2f(g4.y), cr[1], bf2f(y4.y)));
        o.z = f2bf(bf2f(F4.z) * fmaf(bf2f(g4.z), cr[2], bf2f(y4.z)));
        o.w = f2bf(bf2f(F4.w) * fmaf(bf2f(g4.w), cr[3], bf2f(y4.w)));
        *(ushort4*)&ygb[gi] = o;
    }
}

// ---------------------------------------------------------------------------
extern "C" void kernel_launch(void* const* d_in, const int* in_sizes, int n_in,
                              void* d_out, int out_size, void* d_ws, size_t ws_size,
                              hipStream_t stream)
{
    const float* x      = (const float*)d_in[0];
    const float* W_in   = (const float*)d_in[1];
    const float* conv_w = (const float*)d_in[2];
    const float* conv_b = (const float*)d_in[3];
    const float* W_xprj = (const float*)d_in[4];
    const float* A_log  = (const float*)d_in[5];
    const float* Dvec   = (const float*)d_in[6];
    const float* W_out  = (const float*)d_in[7];
    float* out = (float*)d_out;

    // workspace ~56.5 MB; aliases are dead-before-overwrite (stream order):
    float* ws = (float*)d_ws;
    unsigned*       ddu   = (unsigned*)ws;                        // [4096][1024] u32 (dA|du), 16.8 MB
    unsigned short* uc2b  = (unsigned short*)(ws + 4194304);      // u, 8.4 MB
    unsigned short* xzb   = uc2b + 4194304;                       // 8.4 MB
    unsigned short* ygb   = xzb  + 4194304;                       // Du->yloc->g, 8.4 MB
    unsigned short* gbuf  = ygb  + 4194304;                       // 8.4 MB
    unsigned short* Fbuf  = gbuf + 4194304;                       // 4.2 MB
    unsigned short* Bbf   = Fbuf + 2097152;                       // 0.5 MB
    unsigned short* Cbf   = Bbf  + 262144;                        // 0.5 MB
    unsigned short* wob   = Cbf  + 262144;                        // 1.0 MB
    float*          Pbuf  = (float*)(wob + 524288);               // 0.26 MB
    // aliases:
    unsigned short* xb     = (unsigned short*)ddu;                // dead after gemm1 (ddu written by gemm2)
    unsigned short* winb   = xb + 1048576;                        // dead after gemm1
    unsigned short* wxb    = gbuf;                                // dead after gemm2 (gbuf written in passA)
    unsigned short* sEnd   = xzb;                                 // xzb dead after convk
    unsigned short* sInitB = uc2b;                                // u dead after gemm2 epilogue
    float*          gpart  = (float*)ddu;                         // ddu dead after passA (4x2048x512 f32 = 16.8 MB)

    // 1) bf16 casts
    castall<<<3712, 256, 0, stream>>>(x, W_in, W_xprj, W_out, xb, winb, wxb, wob);

    // 2) xz = x @ W_in^T -> bf16 (M=2048, N=2048, K=512) — 512 blocks
    gemm128<<<dim3(32, 16), 256, 0, stream>>>(xb, nullptr, winb, (float*)xzb,
        B_ * LSEQ, 2 * DI, DM, DM, 1, 1, nullptr, nullptr, nullptr, nullptr, nullptr);

    // 3) conv both dirs + SiLU -> u; fused D*u and F=0.5*silu(z)
    convk<<<(B_ * LSEQ * DI) / 256, 256, 0, stream>>>(xzb, conv_w, conv_b, Dvec, uc2b, ygb, Fbuf);

    // 4) proj GEMM with fused prep epilogue: packed ddu + B,C — 576 blocks
    gemm128<<<dim3(18, 32), 256, 0, stream>>>(uc2b, nullptr, wxb, nullptr,
        4 * LSEQ, DI + 2 * NS, DI, DI, 1, 2, A_log, uc2b, ddu, Bbf, Cbf);

    // 5) pass A: local scans + yloc + g
    passA<<<dim3(16, NC, 4), 256, 0, stream>>>(ddu, Bbf, Cbf, ygb, gbuf, sEnd, Pbuf);

    // 6) pass B: chunk-state combine -> bf16 s_init
    passB<<<dim3(256, 4), 256, 0, stream>>>(sEnd, Pbuf, sInitB);

    // 7) corrK: MFMA correction + epilogue -> final g values in ygb
    corrK<<<dim3(8, NC, 4), 256, 0, stream>>>(Cbf, sInitB, gbuf, Fbuf, ygb);

    // 8) out = [gf | gb] @ [W|W]^T via K-concat (K=2048, wrapK=1024), split-K=4 — 512 blocks
    gemm128<<<dim3(8, 16, 4), 256, 0, stream>>>(ygb, ygb + (size_t)2 * LSEQ * DI, wob, gpart,
        B_ * LSEQ, DM, 2 * DI, DI, 4, 0, nullptr, nullptr, nullptr, nullptr, nullptr);
    reduce4<<<1024, 256, 0, stream>>>(gpart, out, B_ * LSEQ * DM);
}